// Round 9
// baseline (416.613 us; speedup 1.0000x reference)
//
#include <hip/hip_runtime.h>
#include <hip/hip_bf16.h>
#include <math.h>

#define D_ 1024
#define H_ 8
#define QLR_ 384
#define KVLR_ 256
#define NOPE_ 128
#define ROPE_ 64
#define VD_ 128
#define E_ 8
#define INTER_ 512
#define B_ 2
#define T_ 2048
#define QKD_ 192
#define NTOK (B_*T_)
#define LSTR 4608
#define MAXMB 72

typedef __attribute__((ext_vector_type(8))) short short8;
typedef __attribute__((ext_vector_type(4))) float f32x4;
typedef __attribute__((ext_vector_type(4))) unsigned short us4;

__device__ __forceinline__ unsigned short f2bf(float f) {
  union { float f; unsigned u; } v; v.f = f;
  return (unsigned short)((v.u + 0x7FFFu + ((v.u >> 16) & 1u)) >> 16);
}
__device__ __forceinline__ float bf2f(unsigned short h) {
  union { unsigned u; float f; } v; v.u = ((unsigned)h) << 16;
  return v.f;
}

#define GLD16(SRC, DST) __builtin_amdgcn_global_load_lds( \
    (__attribute__((address_space(1))) void*)(SRC), \
    (__attribute__((address_space(3))) void*)(DST), 16, 0, 0)

#define DPPF(v, ctrl) __int_as_float(__builtin_amdgcn_update_dpp(0, __float_as_int(v), ctrl, 0xF, 0xF, true))
__device__ __forceinline__ float dppmax16(float v) {
  v = fmaxf(v, DPPF(v, 0xB1));
  v = fmaxf(v, DPPF(v, 0x4E));
  v = fmaxf(v, DPPF(v, 0x124));
  v = fmaxf(v, DPPF(v, 0x128));
  return v;
}
__device__ __forceinline__ float dppsum16(float v) {
  v += DPPF(v, 0xB1);
  v += DPPF(v, 0x4E);
  v += DPPF(v, 0x124);
  v += DPPF(v, 0x128);
  return v;
}

// ---------------- transpose fp32 [R][C] -> bf16 [C][R] (batched) ----------------
__global__ __launch_bounds__(256) void transpose_f32_bf16(
    const float* __restrict__ in, unsigned short* __restrict__ out,
    int R, int C, size_t inBS, size_t outBS) {
  __shared__ float tile[32][33];
  const float* inp = in + (size_t)blockIdx.z * inBS;
  unsigned short* outp = out + (size_t)blockIdx.z * outBS;
  int c0 = blockIdx.x * 32, r0 = blockIdx.y * 32;
  int tx = threadIdx.x & 31, ty = threadIdx.x >> 5;
  #pragma unroll
  for (int i = 0; i < 4; ++i) {
    int rr = ty + i * 8;
    tile[rr][tx] = inp[(size_t)(r0 + rr) * C + c0 + tx];
  }
  __syncthreads();
  #pragma unroll
  for (int i = 0; i < 4; ++i) {
    int rr = ty + i * 8;
    outp[(size_t)(c0 + rr) * R + r0 + tx] = f2bf(tile[tx][rr]);
  }
}

// ---------------- interleaved pair transpose for w1/w3 fusion ----------------
__global__ __launch_bounds__(256) void transpose_pair(
    const float* __restrict__ in1, const float* __restrict__ in3,
    unsigned short* __restrict__ out, int K, int C1, size_t inBS, size_t outBS) {
  __shared__ float tile[32][33];
  int z = blockIdx.z; int bat = z >> 1; int f = (z & 1) * 16;
  const float* src = ((z & 1) ? in3 : in1) + (size_t)bat * inBS;
  unsigned short* o = out + (size_t)bat * outBS;
  int c0 = blockIdx.x * 32, r0 = blockIdx.y * 32;
  int tx = threadIdx.x & 31, ty = threadIdx.x >> 5;
  #pragma unroll
  for (int i = 0; i < 4; ++i) {
    int rr = ty + i * 8;
    tile[rr][tx] = src[(size_t)(r0 + rr) * C1 + c0 + tx];
  }
  __syncthreads();
  #pragma unroll
  for (int i = 0; i < 4; ++i) {
    int cc = ty + i * 8;
    int c = c0 + cc;
    int n = ((c >> 4) << 5) + (c & 15) + f;
    o[(size_t)n * K + r0 + tx] = f2bf(tile[tx][cc]);
  }
}

// ---------------- RMS norm -> bf16 ----------------
template<typename TI>
__global__ __launch_bounds__(256) void rms_to_bf16(
    const TI* __restrict__ src, int stride, int off, const float* __restrict__ w,
    unsigned short* __restrict__ out, int Dd, int outStride) {
  int row = blockIdx.x;
  const TI* xr = src + (size_t)row * stride + off;
  float ss = 0.f;
  for (int i = threadIdx.x; i < Dd; i += 256) {
    float v;
    if constexpr (sizeof(TI) == 2) v = bf2f((unsigned short)xr[i]); else v = (float)xr[i];
    ss += v * v;
  }
  for (int o = 1; o < 64; o <<= 1) ss += __shfl_xor(ss, o);
  __shared__ float red[4];
  if ((threadIdx.x & 63) == 0) red[threadIdx.x >> 6] = ss;
  __syncthreads();
  float tot = red[0] + red[1] + red[2] + red[3];
  float inv = 1.f / sqrtf(tot / Dd + 1e-6f);
  for (int i = threadIdx.x; i < Dd; i += 256) {
    float v;
    if constexpr (sizeof(TI) == 2) v = bf2f((unsigned short)xr[i]); else v = (float)xr[i];
    out[(size_t)row * outStride + i] = f2bf(v * inv * w[i]);
  }
}

// ---------------- fused: q_norm + kv_norm + rope_k from lat ----------------
__global__ __launch_bounds__(256) void lat_post(
    const unsigned short* __restrict__ lat, const float* __restrict__ qw,
    const float* __restrict__ kw, const float* __restrict__ fc, const float* __restrict__ fs,
    unsigned short* __restrict__ qn, unsigned short* __restrict__ kvn,
    unsigned short* __restrict__ kr) {
  int row = blockIdx.x, tid = threadIdx.x;
  int lane = tid & 63, wv = tid >> 6;
  const unsigned short* lr = lat + (size_t)row * 768;
  float s1 = 0.f, s2 = 0.f;
  for (int i = tid; i < QLR_; i += 256) { float v = bf2f(lr[i]); s1 += v * v; }
  { float v = bf2f(lr[QLR_ + tid]); s2 = v * v; }
  for (int o = 1; o < 64; o <<= 1) { s1 += __shfl_xor(s1, o); s2 += __shfl_xor(s2, o); }
  __shared__ float red[8];
  if (lane == 0) { red[wv] = s1; red[4 + wv] = s2; }
  __syncthreads();
  float inv1 = 1.f / sqrtf((red[0] + red[1] + red[2] + red[3]) / QLR_ + 1e-6f);
  float inv2 = 1.f / sqrtf((red[4] + red[5] + red[6] + red[7]) / KVLR_ + 1e-6f);
  for (int i = tid; i < QLR_; i += 256)
    qn[(size_t)row * QLR_ + i] = f2bf(bf2f(lr[i]) * inv1 * qw[i]);
  kvn[(size_t)row * KVLR_ + tid] = f2bf(bf2f(lr[QLR_ + tid]) * inv2 * kw[tid]);
  if (tid < 32) {
    int t = row & (T_ - 1);
    float c = fc[t * 32 + tid], s = fs[t * 32 + tid];
    float x0 = bf2f(lr[640 + 2 * tid]), x1 = bf2f(lr[640 + 2 * tid + 1]);
    kr[(size_t)row * ROPE_ + 2 * tid]     = f2bf(x0 * c - x1 * s);
    kr[(size_t)row * ROPE_ + 2 * tid + 1] = f2bf(x0 * s + x1 * c);
  }
}

// ---------------- bf16 MFMA GEMM: C[M,N] = A[M,K] @ Bt[N,K]^T ----------------
// MODE 0: bf16 out. 1: f32 out = acc + addv. 2: f32 out += acc.
// 4: silu-pair -> bf16 [M][N/2]. 5: kv_up special (nope->kvb, V->vt transposed)
template<int MODE>
__global__ __launch_bounds__(256) void gemm_bf16(
    const unsigned short* __restrict__ A, const unsigned short* __restrict__ Bt,
    void* __restrict__ Cv, int M, int N, int K,
    const float* __restrict__ addv, unsigned short* __restrict__ vtg) {
  __shared__ __align__(16) unsigned short As[128 * 32];
  __shared__ __align__(16) unsigned short Bs[128 * 32];
  const int tid = threadIdx.x;
  const int lane = tid & 63, wave = tid >> 6;
  const int wm = wave >> 1, wn = wave & 1;
  const int bm = blockIdx.y * 128, bn = blockIdx.x * 128;
  const int r = lane & 15, g = lane >> 4;

  f32x4 acc[4][4];
  #pragma unroll
  for (int i = 0; i < 4; ++i)
    #pragma unroll
    for (int j = 0; j < 4; ++j) acc[i][j] = (f32x4)0.f;

  const int rl0 = wave * 16 + (lane >> 2);
  const int rl1 = rl0 + 64;
  const int kc = (lane & 3) * 8;
  char* AsB = (char*)As; char* BsB = (char*)Bs;

  for (int k0 = 0; k0 < K; k0 += 32) {
    GLD16(A + (size_t)(bm + rl0) * K + k0 + kc, AsB + wave * 1024);
    GLD16(A + (size_t)(bm + rl1) * K + k0 + kc, AsB + (wave + 4) * 1024);
    GLD16(Bt + (size_t)(bn + rl0) * K + k0 + kc, BsB + wave * 1024);
    GLD16(Bt + (size_t)(bn + rl1) * K + k0 + kc, BsB + (wave + 4) * 1024);
    __syncthreads();
    short8 af[4], bfr[4];
    #pragma unroll
    for (int mi = 0; mi < 4; ++mi)
      af[mi] = *(const short8*)(As + (wm * 64 + mi * 16 + r) * 32 + g * 8);
    #pragma unroll
    for (int nj = 0; nj < 4; ++nj)
      bfr[nj] = *(const short8*)(Bs + (wn * 64 + nj * 16 + r) * 32 + g * 8);
    #pragma unroll
    for (int mi = 0; mi < 4; ++mi)
      #pragma unroll
      for (int nj = 0; nj < 4; ++nj)
        acc[mi][nj] = __builtin_amdgcn_mfma_f32_16x16x32_bf16(af[mi], bfr[nj], acc[mi][nj], 0, 0, 0);
    __syncthreads();
  }

  if (MODE == 5) {
    unsigned short* C = (unsigned short*)Cv;
    const int colbase = bn + wn * 64;
    const int b = bm >> 11;
    const int hh = colbase >> 8;
    if ((colbase & 255) < 128) {
      #pragma unroll
      for (int mi = 0; mi < 4; ++mi)
        #pragma unroll
        for (int reg = 0; reg < 4; ++reg) {
          int mrow = bm + wm * 64 + mi * 16 + g * 4 + reg;
          size_t bas = (size_t)mrow * N + colbase + r;
          #pragma unroll
          for (int nj = 0; nj < 4; ++nj) C[bas + nj * 16] = f2bf(acc[mi][nj][reg]);
        }
    } else {
      const int tl0 = (bm & 2047) + wm * 64 + g * 4;
      const int d0 = (colbase & 255) - 128 + r;
      #pragma unroll
      for (int mi = 0; mi < 4; ++mi)
        #pragma unroll
        for (int nj = 0; nj < 4; ++nj) {
          int d = d0 + nj * 16;
          us4 pk;
          #pragma unroll
          for (int reg = 0; reg < 4; ++reg) pk[reg] = f2bf(acc[mi][nj][reg]);
          *(us4*)(vtg + ((size_t)((b * 8 + hh) * 128 + d)) * 2048 + tl0 + mi * 16) = pk;
        }
    }
    return;
  }

  const int orow0 = wm * 64 + g * 4;
  const int ocol0 = bn + wn * 64 + r;
  #pragma unroll
  for (int mi = 0; mi < 4; ++mi) {
    #pragma unroll
    for (int reg = 0; reg < 4; ++reg) {
      int mrow = bm + orow0 + mi * 16 + reg;
      if (MODE == 4) {
        unsigned short* C = (unsigned short*)Cv;
        size_t bas2 = (size_t)mrow * (N >> 1) + ((bn + wn * 64) >> 1) + r;
        #pragma unroll
        for (int p = 0; p < 2; ++p) {
          float a = acc[mi][2 * p][reg], b3 = acc[mi][2 * p + 1][reg];
          C[bas2 + p * 16] = f2bf((a / (1.f + __expf(-a))) * b3);
        }
      } else {
        size_t bas = (size_t)mrow * N + ocol0;
        if (MODE == 0) {
          unsigned short* C = (unsigned short*)Cv;
          #pragma unroll
          for (int nj = 0; nj < 4; ++nj) C[bas + nj * 16] = f2bf(acc[mi][nj][reg]);
        } else if (MODE == 1) {
          float* C = (float*)Cv;
          #pragma unroll
          for (int nj = 0; nj < 4; ++nj) C[bas + nj * 16] = acc[mi][nj][reg] + addv[bas + nj * 16];
        } else {
          float* C = (float*)Cv;
          #pragma unroll
          for (int nj = 0; nj < 4; ++nj) C[bas + nj * 16] += acc[mi][nj][reg];
        }
      }
    }
  }
}

// ---------------- expert w13 gather GEMM + fused silu -> ehm[slot][512] ----------------
__global__ __launch_bounds__(256) void gemm_moe13(
    const unsigned short* __restrict__ A, const unsigned short* __restrict__ W,
    unsigned short* __restrict__ Cb,
    const int* __restrict__ lists, const int* __restrict__ map, const int* __restrict__ sbase) {
  int mb = map[blockIdx.y];
  if (mb < 0) return;
  const int e = mb >> 16, ib = mb & 0xFFFF;
  __shared__ __align__(16) unsigned short As[128 * 32];
  __shared__ __align__(16) unsigned short Bs[128 * 32];
  const int tid = threadIdx.x, lane = tid & 63, wave = tid >> 6;
  const int wm = wave >> 1, wn = wave & 1;
  const int bn = blockIdx.x * 128;
  const int r = lane & 15, g = lane >> 4;

  f32x4 acc[4][4];
  #pragma unroll
  for (int i = 0; i < 4; ++i)
    #pragma unroll
    for (int j = 0; j < 4; ++j) acc[i][j] = (f32x4)0.f;

  const int rl0 = wave * 16 + (lane >> 2), rl1 = rl0 + 64;
  const int kc = (lane & 3) * 8;
  int t0 = lists[e * LSTR + ib * 128 + rl0]; if (t0 < 0) t0 = 0;
  int t1 = lists[e * LSTR + ib * 128 + rl1]; if (t1 < 0) t1 = 0;
  const unsigned short* Wb = W + (size_t)e * 1024 * 1024;
  char* AsB = (char*)As; char* BsB = (char*)Bs;

  for (int k0 = 0; k0 < 1024; k0 += 32) {
    GLD16(A + (size_t)t0 * 1024 + k0 + kc, AsB + wave * 1024);
    GLD16(A + (size_t)t1 * 1024 + k0 + kc, AsB + (wave + 4) * 1024);
    GLD16(Wb + (size_t)(bn + rl0) * 1024 + k0 + kc, BsB + wave * 1024);
    GLD16(Wb + (size_t)(bn + rl1) * 1024 + k0 + kc, BsB + (wave + 4) * 1024);
    __syncthreads();
    short8 af[4], bfr[4];
    #pragma unroll
    for (int mi = 0; mi < 4; ++mi)
      af[mi] = *(const short8*)(As + (wm * 64 + mi * 16 + r) * 32 + g * 8);
    #pragma unroll
    for (int nj = 0; nj < 4; ++nj)
      bfr[nj] = *(const short8*)(Bs + (wn * 64 + nj * 16 + r) * 32 + g * 8);
    #pragma unroll
    for (int mi = 0; mi < 4; ++mi)
      #pragma unroll
      for (int nj = 0; nj < 4; ++nj)
        acc[mi][nj] = __builtin_amdgcn_mfma_f32_16x16x32_bf16(af[mi], bfr[nj], acc[mi][nj], 0, 0, 0);
    __syncthreads();
  }
  const int sb = sbase[e] + ib * 128;
  const int hc = ((bn + wn * 64) >> 1) + r;
  #pragma unroll
  for (int mi = 0; mi < 4; ++mi)
    #pragma unroll
    for (int reg = 0; reg < 4; ++reg) {
      int srow = sb + wm * 64 + mi * 16 + g * 4 + reg;
      #pragma unroll
      for (int p = 0; p < 2; ++p) {
        float a = acc[mi][2 * p][reg], b3 = acc[mi][2 * p + 1][reg];
        Cb[(size_t)srow * 512 + hc + p * 16] = f2bf((a / (1.f + __expf(-a))) * b3);
      }
    }
}

// ---------------- expert w2 GEMM + weighted atomic scatter ----------------
__global__ __launch_bounds__(256) void gemm_moe2(
    const unsigned short* __restrict__ Am, const unsigned short* __restrict__ W,
    float* __restrict__ out,
    const int* __restrict__ lists, const int* __restrict__ map, const int* __restrict__ sbase,
    const float* __restrict__ cw) {
  int mb = map[blockIdx.y];
  if (mb < 0) return;
  const int e = mb >> 16, ib = mb & 0xFFFF;
  __shared__ __align__(16) unsigned short As[128 * 32];
  __shared__ __align__(16) unsigned short Bs[128 * 32];
  const int tid = threadIdx.x, lane = tid & 63, wave = tid >> 6;
  const int wm = wave >> 1, wn = wave & 1;
  const int bn = blockIdx.x * 128;
  const int r = lane & 15, g = lane >> 4;

  f32x4 acc[4][4];
  #pragma unroll
  for (int i = 0; i < 4; ++i)
    #pragma unroll
    for (int j = 0; j < 4; ++j) acc[i][j] = (f32x4)0.f;

  const int rl0 = wave * 16 + (lane >> 2), rl1 = rl0 + 64;
  const int kc = (lane & 3) * 8;
  const int sb = sbase[e] + ib * 128;
  const unsigned short* Wb = W + (size_t)e * 512 * 1024;
  char* AsB = (char*)As; char* BsB = (char*)Bs;

  for (int k0 = 0; k0 < 512; k0 += 32) {
    GLD16(Am + (size_t)(sb + rl0) * 512 + k0 + kc, AsB + wave * 1024);
    GLD16(Am + (size_t)(sb + rl1) * 512 + k0 + kc, AsB + (wave + 4) * 1024);
    GLD16(Wb + (size_t)(bn + rl0) * 512 + k0 + kc, BsB + wave * 1024);
    GLD16(Wb + (size_t)(bn + rl1) * 512 + k0 + kc, BsB + (wave + 4) * 1024);
    __syncthreads();
    short8 af[4], bfr[4];
    #pragma unroll
    for (int mi = 0; mi < 4; ++mi)
      af[mi] = *(const short8*)(As + (wm * 64 + mi * 16 + r) * 32 + g * 8);
    #pragma unroll
    for (int nj = 0; nj < 4; ++nj)
      bfr[nj] = *(const short8*)(Bs + (wn * 64 + nj * 16 + r) * 32 + g * 8);
    #pragma unroll
    for (int mi = 0; mi < 4; ++mi)
      #pragma unroll
      for (int nj = 0; nj < 4; ++nj)
        acc[mi][nj] = __builtin_amdgcn_mfma_f32_16x16x32_bf16(af[mi], bfr[nj], acc[mi][nj], 0, 0, 0);
    __syncthreads();
  }
  const int ocol0 = bn + wn * 64 + r;
  #pragma unroll
  for (int mi = 0; mi < 4; ++mi)
    #pragma unroll
    for (int reg = 0; reg < 4; ++reg) {
      int orow = wm * 64 + mi * 16 + g * 4 + reg;
      int tok = lists[e * LSTR + ib * 128 + orow];
      if (tok >= 0) {
        float wt = cw[(size_t)tok * E_ + e];
        #pragma unroll
        for (int nj = 0; nj < 4; ++nj)
          atomicAdd(out + (size_t)tok * 1024 + ocol0 + nj * 16, acc[mi][nj][reg] * wt);
      }
    }
}

// ---------------- MFMA flash attention, split-K x2, Q-in-regs, counted-wait barriers ----------------
#define AQ 64
#define AK 32
#define VP 40
__global__ __launch_bounds__(256) void attn_mfma(
    const unsigned short* __restrict__ q,   // [NTOK][H][192] (rope NOT applied)
    const unsigned short* __restrict__ kv,  // [NTOK][H][256] (nope half valid)
    const unsigned short* __restrict__ kr,  // [NTOK][64]
    const unsigned short* __restrict__ vt,  // [16][128][2048]
    const float* __restrict__ fcos, const float* __restrict__ fsin,
    unsigned short* __restrict__ po,        // [16*32*2][64*128] bf16 unnormalized O
    float* __restrict__ pml) {              // [16*32*2][64*2] (m, l)
  __shared__ __align__(16) unsigned short Ks[AK * 192];    // row-major pitch 384B, XOR-swizzled
  __shared__ __align__(16) unsigned short Vl[128 * VP];
  __shared__ __align__(16) unsigned short Ps[4 * 16 * VP];
  const int tid = threadIdx.x, lane = tid & 63, wave = tid >> 6;
  const int r = lane & 15, g = lane >> 4;
  const int bh = blockIdx.y, b = bh >> 3, h = bh & 7;
  const int qt = gridDim.x - 1 - blockIdx.x;   // LPT
  const int q0 = qt * AQ;
  const int half = blockIdx.z;
  const int hnt = qt + 1;                      // tiles per half
  const int kb = half * hnt, ke = kb + hnt;
  const size_t bT = (size_t)b * T_;
  const unsigned short* vbase = vt + (size_t)bh * 128 * T_;
  char* KsB = (char*)Ks;

  // ---- Q into registers with fused RoPE ----
  short8 qf[6];
  const int qrow = q0 + wave * 16 + r;         // sequence position
  {
    const unsigned short* qb = q + ((bT + qrow) * H_ + h) * 192;
    #pragma unroll
    for (int kk = 0; kk < 6; ++kk) qf[kk] = *(const short8*)(qb + kk * 32 + g * 8);
    #pragma unroll
    for (int kk = 4; kk < 6; ++kk) {
      int i0 = (kk - 4) * 16 + g * 4;
      #pragma unroll
      for (int p = 0; p < 4; ++p) {
        float cc = fcos[qrow * 32 + i0 + p], sn = fsin[qrow * 32 + i0 + p];
        float x0 = bf2f((unsigned short)qf[kk][2 * p]), x1 = bf2f((unsigned short)qf[kk][2 * p + 1]);
        qf[kk][2 * p]     = (short)f2bf(x0 * cc - x1 * sn);
        qf[kk][2 * p + 1] = (short)f2bf(x0 * sn + x1 * cc);
      }
    }
  }

  float m_i[4], l_i[4];
  f32x4 o[8];
  #pragma unroll
  for (int i = 0; i < 4; ++i) { m_i[i] = -1e30f; l_i[i] = 0.f; }
  #pragma unroll
  for (int cb = 0; cb < 8; ++cb) o[cb] = (f32x4)0.f;

  const float scale2 = 0.07216878364870322f * 1.44269504088896f; // 1/sqrt(192)*log2e

  // prefetch tile kb
  short8 kreg[3], vreg[2];
  int krow[3], kcol[3];
  #pragma unroll
  for (int it = 0; it < 3; ++it) {
    int c = tid + it * 256;
    krow[it] = c / 24; kcol[it] = c % 24;
    kreg[it] = (kcol[it] < 16)
      ? *(const short8*)(kv + ((bT + kb * AK + krow[it]) * H_ + h) * 256 + kcol[it] * 8)
      : *(const short8*)(kr + (bT + kb * AK + krow[it]) * 64 + (kcol[it] - 16) * 8);
  }
  #pragma unroll
  for (int it = 0; it < 2; ++it) {
    int x = tid + it * 256;
    vreg[it] = *(const short8*)(vbase + (size_t)(x >> 2) * T_ + kb * AK + (x & 3) * 8);
  }

  for (int kt = kb; kt < ke; ++kt) {
    // barrier A: all waves finished READING prev tile's Ks/Vl. Raw barrier — no vmcnt
    // drain, so the K/V register-prefetch loads stay in flight across it (T4).
    __builtin_amdgcn_s_barrier();
    __builtin_amdgcn_sched_barrier(0);
    #pragma unroll
    for (int it = 0; it < 3; ++it)
      *(short8*)(KsB + ((krow[it] * 384 + kcol[it] * 16) ^ ((krow[it] & 7) << 4))) = kreg[it];
    #pragma unroll
    for (int it = 0; it < 2; ++it) {
      int x = tid + it * 256;
      *(short8*)(Vl + (x >> 2) * VP + (x & 3) * 8) = vreg[it];
    }
    // barrier B: stores visible to all waves; only LDS counter drained.
    asm volatile("s_waitcnt lgkmcnt(0)" ::: "memory");
    __builtin_amdgcn_s_barrier();
    __builtin_amdgcn_sched_barrier(0);

    if (kt + 1 < ke) {
      int k1 = (kt + 1) * AK;
      #pragma unroll
      for (int it = 0; it < 3; ++it)
        kreg[it] = (kcol[it] < 16)
          ? *(const short8*)(kv + ((bT + k1 + krow[it]) * H_ + h) * 256 + kcol[it] * 8)
          : *(const short8*)(kr + (bT + k1 + krow[it]) * 64 + (kcol[it] - 16) * 8);
      #pragma unroll
      for (int it = 0; it < 2; ++it) {
        int x = tid + it * 256;
        vreg[it] = *(const short8*)(vbase + (size_t)(x >> 2) * T_ + k1 + (x & 3) * 8);
      }
    }

    const int k0 = kt * AK;
    f32x4 sf0 = (f32x4)0.f, sf1 = (f32x4)0.f;
    {
      int ksw = (r & 7) << 4;
      __builtin_amdgcn_s_setprio(1);
      #pragma unroll
      for (int kk = 0; kk < 6; ++kk) {
        short8 b0 = *(const short8*)(KsB + ((r * 384 + kk * 64 + g * 16) ^ ksw));
        short8 b1 = *(const short8*)(KsB + (((16 + r) * 384 + kk * 64 + g * 16) ^ ksw));
        sf0 = __builtin_amdgcn_mfma_f32_16x16x32_bf16(qf[kk], b0, sf0, 0, 0, 0);
        sf1 = __builtin_amdgcn_mfma_f32_16x16x32_bf16(qf[kk], b1, sf1, 0, 0, 0);
      }
      __builtin_amdgcn_s_setprio(0);
    }

    float fac[4];
    bool needs = false;
    const bool bnd = (k0 + AK > q0);   // masks needed only on diagonal tiles (<=2/block)
    #pragma unroll
    for (int reg = 0; reg < 4; ++reg) {
      float s0 = sf0[reg] * scale2;   // log2 domain
      float s1 = sf1[reg] * scale2;
      if (bnd) {
        int qp = q0 + wave * 16 + g * 4 + reg;
        if (k0 + r > qp) s0 = -1e30f;
        if (k0 + 16 + r > qp) s1 = -1e30f;
      }
      float mt = dppmax16(fmaxf(s0, s1));
      float fc = 1.f, mn = m_i[reg];
      if (mt > mn + 8.f) {            // defer-max
        mn = mt; fc = exp2f(m_i[reg] - mn); m_i[reg] = mn; needs = true;
      }
      float e0 = exp2f(s0 - mn), e1 = exp2f(s1 - mn);
      float rs = dppsum16(e0 + e1);
      l_i[reg] = l_i[reg] * fc + rs;
      fac[reg] = fc;
      __hip_bfloat162 pk = __float22bfloat162_rn(float2{e0, e1});
      unsigned u = *(unsigned*)&pk;
      int prow = g * 4 + reg;
      Ps[wave * 16 * VP + prow * VP + r] = (unsigned short)u;
      Ps[wave * 16 * VP + prow * VP + 16 + r] = (unsigned short)(u >> 16);
    }
    if (__any(needs)) {
      #pragma unroll
      for (int cb = 0; cb < 8; ++cb)
        #pragma unroll
        for (int reg = 0; reg < 4; ++reg) o[cb][reg] *= fac[reg];
    }
    short8 pa = *(const short8*)(Ps + wave * 16 * VP + r * VP + g * 8);
    __builtin_amdgcn_s_setprio(1);
    #pragma unroll
    for (int cb = 0; cb < 8; ++cb) {
      short8 vb = *(const short8*)(Vl + (cb * 16 + r) * VP + g * 8);
      o[cb] = __builtin_amdgcn_mfma_f32_16x16x32_bf16(pa, vb, o[cb], 0, 0, 0);
    }
    __builtin_amdgcn_s_setprio(0);
  }

  // ---- write partial (unnormalized O bf16, m/l fp32) ----
  const int slab = (bh * 32 + qt) * 2 + half;
  unsigned short* pob = po + (size_t)slab * 8192;
  float* pmlb = pml + (size_t)slab * 128;
  #pragma unroll
  for (int reg = 0; reg < 4; ++reg) {
    int row = wave * 16 + g * 4 + reg;
    if (r == 0) { pmlb[row * 2] = m_i[reg]; pmlb[row * 2 + 1] = l_i[reg]; }
    #pragma unroll
    for (int cb = 0; cb < 8; ++cb)
      pob[row * 128 + cb * 16 + r] = f2bf(o[cb][reg]);
  }
}

// ---------------- split-K combine: merge 2 halves -> y bf16 ----------------
__global__ __launch_bounds__(256) void attn_combine(
    const unsigned short* __restrict__ po, const float* __restrict__ pml,
    unsigned short* __restrict__ y) {
  const int qt = blockIdx.x, bh = blockIdx.y, b = bh >> 3, h = bh & 7;
  const int s0 = (bh * 32 + qt) * 2, s1 = s0 + 1;
  const int row = threadIdx.x >> 2;
  const int qp = threadIdx.x & 3;
  float m0 = pml[(size_t)s0 * 128 + row * 2], l0 = pml[(size_t)s0 * 128 + row * 2 + 1];
  float m1 = pml[(size_t)s1 * 128 + row * 2], l1 = pml[(size_t)s1 * 128 + row * 2 + 1];
  float m = fmaxf(m0, m1);
  float e0 = exp2f(m0 - m), e1 = exp2f(m1 - m);
  float inv = 1.f / (l0 * e0 + l1 * e1);
  e0 *= inv; e1 *= inv;
  const unsigned short* o0 = po + (size_t)s0 * 8192 + row * 128 + qp * 32;
  const unsigned short* o1 = po + (size_t)s1 * 8192 + row * 128 + qp * 32;
  unsigned short* yb = y + ((size_t)(b * T_ + qt * 64 + row)) * 1024 + h * 128 + qp * 32;
  #pragma unroll
  for (int v = 0; v < 4; ++v) {
    short8 a = *(const short8*)(o0 + v * 8);
    short8 c = *(const short8*)(o1 + v * 8);
    short8 w;
    #pragma unroll
    for (int j = 0; j < 8; ++j)
      w[j] = (short)f2bf(bf2f((unsigned short)a[j]) * e0 + bf2f((unsigned short)c[j]) * e1);
    *(short8*)(yb + v * 8) = w;
  }
}

// ---------------- fused rms2 + gate (logits, softmax, top2) ----------------
__global__ __launch_bounds__(256) void rms2_gate(
    const float* __restrict__ xo, const float* __restrict__ rw, const float* __restrict__ gw,
    unsigned short* __restrict__ h2b, float* __restrict__ cw) {
  int row = blockIdx.x, tid = threadIdx.x;
  int lane = tid & 63, wv = tid >> 6;
  const float* xr = xo + (size_t)row * D_;
  float v[4]; float ss = 0.f;
  #pragma unroll
  for (int j = 0; j < 4; ++j) { v[j] = xr[tid + j * 256]; ss += v[j] * v[j]; }
  for (int o = 1; o < 64; o <<= 1) ss += __shfl_xor(ss, o);
  __shared__ float red[4];
  if (lane == 0) red[wv] = ss;
  __syncthreads();
  float inv = 1.f / sqrtf((red[0] + red[1] + red[2] + red[3]) / D_ + 1e-6f);
  float a[E_] = {0, 0, 0, 0, 0, 0, 0, 0};
  #pragma unroll
  for (int j = 0; j < 4; ++j) {
    int i = tid + j * 256;
    float hv = v[j] * inv * rw[i];
    h2b[(size_t)row * D_ + i] = f2bf(hv);
    const float* wr = gw + (size_t)i * E_;
    #pragma unroll
    for (int e = 0; e < E_; ++e) a[e] += hv * wr[e];
  }
  #pragma unroll
  for (int e = 0; e < E_; ++e) {
    float t = a[e];
    for (int o = 1; o < 64; o <<= 1) t += __shfl_xor(t, o);
    a[e] = t;
  }
  __shared__ float ga[4][E_];
  if (lane == 0)
    #pragma unroll
    for (int e = 0; e < E_; ++e) ga[wv][e] = a[e];
  __syncthreads();
  if (tid == 0) {
    float lg[E_];
    #pragma unroll
    for (int e = 0; e < E_; ++e) lg[e] = ga[0][e] + ga[1][e] + ga[2][e] + ga[3][e];
    float mx = lg[0];
    #pragma unroll
    for (int e = 1; e < E_; ++e) mx = fmaxf(mx, lg[e]);
    float sum = 0.f; float p[E_];
    #pragma unroll
    for (int e = 0; e < E_; ++e) { p[e] = __expf(lg[e] - mx); sum += p[e]; }
    float is = 1.f / sum;
    int i1 = 0; float b1 = p[0];
    #pragma unroll
    for (int e = 1; e < E_; ++e) if (p[e] > b1) { b1 = p[e]; i1 = e; }
    int i2 = -1; float b2 = -1.f;
    #pragma unroll
    for (int e = 0; e < E_; ++e) if (e != i1 && p[e] > b2) { b2 = p[e]; i2 = e; }
    #pragma unroll
    for (int e = 0; e < E_; ++e)
      cw[(size_t)row * E_ + e] = (e == i1) ? b1 * is : (e == i2 ? b2 * is : 0.f);
  }
}

// ---------------- MoE token compaction (ballot-based, deterministic) ----------------
__global__ __launch_bounds__(256) void moe_build(const float* __restrict__ cw,
                                                 int* __restrict__ lists, int* __restrict__ counts) {
  int e = blockIdx.x, tid = threadIdx.x;
  int lane = tid & 63, wv = tid >> 6;
  __shared__ int wsum[4];
  __shared__ int base;
  if (tid == 0) base = 0;
  __syncthreads();
  for (int c0 = 0; c0 < NTOK; c0 += 256) {
    int tok = c0 + tid;
    bool f = cw[(size_t)tok * E_ + e] > 0.f;
    unsigned long long m = __ballot(f);
    int pos = __popcll(m & ((1ull << lane) - 1ull));
    if (lane == 0) wsum[wv] = __popcll(m);
    __syncthreads();
    int woff = base;
    #pragma unroll
    for (int w = 0; w < 4; ++w) if (w < wv) woff += wsum[w];
    if (f) lists[e * LSTR + woff + pos] = tok;
    __syncthreads();
    if (tid == 0) base += wsum[0] + wsum[1] + wsum[2] + wsum[3];
    __syncthreads();
  }
  int cnt = base;
  int padded = (cnt + 127) & ~127;
  for (int i2 = cnt + tid; i2 < padded; i2 += 256) lists[e * LSTR + i2] = -1;
  if (tid == 0) { counts[e] = cnt; counts[8 + e] = padded >> 7; }
}

__global__ void moe_finalize(const int* __restrict__ counts, int* __restrict__ map,
                             int* __restrict__ sbase) {
  if (threadIdx.x == 0 && blockIdx.x == 0) {
    int cum = 0;
    for (int e = 0; e < E_; ++e) {
      sbase[e] = cum * 128;
      int nb = counts[8 + e];
      for (int i = 0; i < nb; ++i) map[cum + i] = (e << 16) | i;
      cum += nb;
    }
    for (; cum < MAXMB; ++cum) map[cum] = -1;
  }
}

extern "C" void kernel_launch(void* const* d_in, const int* in_sizes, int n_in,
                              void* d_out, int out_size, void* d_ws, size_t ws_size,
                              hipStream_t stream) {
  const float* x        = (const float*)d_in[0];
  const float* fcos     = (const float*)d_in[1];
  const float* fsin     = (const float*)d_in[2];
  const float* rmsn1_w  = (const float*)d_in[3];
  const float* rmsn2_w  = (const float*)d_in[4];
  const float* latent_w = (const float*)d_in[5];
  const float* q_norm_w = (const float*)d_in[6];
  const float* q_up_w   = (const float*)d_in[7];
  const float* kv_norm_w= (const float*)d_in[8];
  const float* kv_up_w  = (const float*)d_in[9];
  const float* c_proj_w = (const float*)d_in[10];
  const float* gate_w   = (const float*)d_in[11];
  const float* sh_w1    = (const float*)d_in[12];
  const float* sh_w2    = (const float*)d_in[13];
  const float* sh_w3    = (const float*)d_in[14];
  const float* e_w1     = (const float*)d_in[15];
  const float* e_w2     = (const float*)d_in[16];
  const float* e_w3     = (const float*)d_in[17];
  float* out = (float*)d_out;

  char* base = (char*)d_ws;
  size_t off = 0;
  auto take = [&](size_t bytes) { char* p = base + off; off += (bytes + 255) & ~(size_t)255; return p; };
  unsigned short* Wlat  = (unsigned short*)take((size_t)768 * 1024 * 2);
  unsigned short* Wqup  = (unsigned short*)take((size_t)1536 * 384 * 2);
  unsigned short* Wkv   = (unsigned short*)take((size_t)2048 * 256 * 2);
  unsigned short* Wcp   = (unsigned short*)take((size_t)1024 * 1024 * 2);
  unsigned short* Wsh13 = (unsigned short*)take((size_t)2048 * 1024 * 2);
  unsigned short* Wsh2  = (unsigned short*)take((size_t)1024 * 1024 * 2);
  unsigned short* Wew13 = (unsigned short*)take((size_t)8 * 1024 * 1024 * 2);
  unsigned short* Wew2  = (unsigned short*)take((size_t)8 * 1024 * 512 * 2);
  float* cw             = (float*)take((size_t)NTOK * E_ * 4);
  int* lists            = (int*)take((size_t)E_ * LSTR * 4);
  int* counts           = (int*)take(64 * 4);
  int* map              = (int*)take(MAXMB * 4);
  int* sbase            = (int*)take(E_ * 4);
  unsigned short* Vtg   = (unsigned short*)take((size_t)16 * 128 * T_ * 2);
  unsigned short* kr    = (unsigned short*)take((size_t)NTOK * 64 * 2);
  float* pml            = (float*)take((size_t)1024 * 128 * 4);

  size_t actStart = off;
  size_t aoff = actStart;
  auto takeA = [&](size_t bytes) { char* p = base + aoff; aoff += (bytes + 255) & ~(size_t)255; return p; };
  unsigned short* h_bf = (unsigned short*)takeA((size_t)NTOK * 1024 * 2);
  unsigned short* lat  = (unsigned short*)takeA((size_t)NTOK * 768 * 2);
  unsigned short* qn   = (unsigned short*)takeA((size_t)NTOK * 384 * 2);
  unsigned short* kvn  = (unsigned short*)takeA((size_t)NTOK * 256 * 2);
  unsigned short* qq   = (unsigned short*)takeA((size_t)NTOK * 1536 * 2);
  unsigned short* kvb  = (unsigned short*)takeA((size_t)NTOK * 2048 * 2);
  unsigned short* y    = (unsigned short*)takeA((size_t)NTOK * 1024 * 2);

  // split-K partial O (16 MB bf16) aliases h_bf/lat/qn (dead during attention)
  unsigned short* po   = (unsigned short*)(base + actStart);

  size_t coff = actStart;
  auto takeC = [&](size_t bytes) { char* p = base + coff; coff += (bytes + 255) & ~(size_t)255; return p; };
  unsigned short* h2b  = (unsigned short*)takeC((size_t)NTOK * 1024 * 2);
  unsigned short* t1m  = (unsigned short*)takeC((size_t)NTOK * 1024 * 2);
  unsigned short* ehm  = (unsigned short*)takeC((size_t)9216 * 512 * 2);

  dim3 blk(256);

  // --- weight conversion ---
  transpose_f32_bf16<<<dim3(22, 32, 1), blk, 0, stream>>>(latent_w, Wlat, 1024, 704, 0, 0);
  transpose_f32_bf16<<<dim3(48, 12, 1), blk, 0, stream>>>(q_up_w, Wqup, 384, 1536, 0, 0);
  transpose_f32_bf16<<<dim3(64, 8, 1), blk, 0, stream>>>(kv_up_w, Wkv, 256, 2048, 0, 0);
  transpose_f32_bf16<<<dim3(32, 32, 1), blk, 0, stream>>>(c_proj_w, Wcp, 1024, 1024, 0, 0);
  transpose_f32_bf16<<<dim3(32, 32, 1), blk, 0, stream>>>(sh_w2, Wsh2, 1024, 1024, 0, 0);
  transpose_pair<<<dim3(32, 32, 2), blk, 0, stream>>>(sh_w1, sh_w3, Wsh13, 1024, 1024, 0, 0);
  transpose_pair<<<dim3(16, 32, 16), blk, 0, stream>>>(e_w1, e_w3, Wew13, 1024, 512,
      (size_t)1024 * 512, (size_t)1024 * 1024);
  transpose_f32_bf16<<<dim3(32, 16, 8), blk, 0, stream>>>(e_w2, Wew2, 512, 1024,
      (size_t)512 * 1024, (size_t)1024 * 512);

  rms_to_bf16<float><<<NTOK, blk, 0, stream>>>(x, D_, 0, rmsn1_w, h_bf, D_, D_);
  gemm_bf16<0><<<dim3(6, 32), blk, 0, stream>>>(h_bf, Wlat, lat, NTOK, 768, 1024, nullptr, nullptr);
  lat_post<<<NTOK, blk, 0, stream>>>(lat, q_norm_w, kv_norm_w, fcos, fsin, qn, kvn, kr);
  gemm_bf16<0><<<dim3(12, 32), blk, 0, stream>>>(qn, Wqup, qq, NTOK, 1536, 384, nullptr, nullptr);
  gemm_bf16<5><<<dim3(16, 32), blk, 0, stream>>>(kvn, Wkv, kvb, NTOK, 2048, 256, nullptr, Vtg);
  attn_mfma<<<dim3(T_ / AQ, B_ * H_, 2), blk, 0, stream>>>(qq, kvb, kr, Vtg, fcos, fsin, po, pml);
  attn_combine<<<dim3(T_ / AQ, B_ * H_), blk, 0, stream>>>(po, pml, y);
  gemm_bf16<1><<<dim3(8, 32), blk, 0, stream>>>(y, Wcp, out, NTOK, 1024, 1024, x, nullptr);
  rms2_gate<<<NTOK, blk, 0, stream>>>(out, rmsn2_w, gate_w, h2b, cw);
  moe_build<<<E_, blk, 0, stream>>>(cw, lists, counts);
  moe_finalize<<<1, 64, 0, stream>>>(counts, map, sbase);
  // shared expert (silu fused into w13 GEMM epilogue)
  gemm_bf16<4><<<dim3(16, 32), blk, 0, stream>>>(h2b, Wsh13, t1m, NTOK, 2048, 1024, nullptr, nullptr);
  gemm_bf16<2><<<dim3(8, 32), blk, 0, stream>>>(t1m, Wsh2, out, NTOK, 1024, 1024, nullptr, nullptr);
  // sparse experts (silu fused)
  gemm_moe13<<<dim3(8, MAXMB), blk, 0, stream>>>(h2b, Wew13, ehm, lists, map, sbase);
  gemm_moe2<<<dim3(8, MAXMB), blk, 0, stream>>>(ehm, Wew2, out, lists, map, sbase, cw);
}

// Round 10
// 415.134 us; speedup vs baseline: 1.0036x; 1.0036x over previous
//
#include <hip/hip_runtime.h>
#include <hip/hip_bf16.h>
#include <math.h>

#define D_ 1024
#define H_ 8
#define QLR_ 384
#define KVLR_ 256
#define NOPE_ 128
#define ROPE_ 64
#define VD_ 128
#define E_ 8
#define INTER_ 512
#define B_ 2
#define T_ 2048
#define QKD_ 192
#define NTOK (B_*T_)
#define LSTR 4608
#define MAXMB 72

typedef __attribute__((ext_vector_type(8))) short short8;
typedef __attribute__((ext_vector_type(4))) float f32x4;
typedef __attribute__((ext_vector_type(4))) unsigned short us4;

__device__ __forceinline__ unsigned short f2bf(float f) {
  union { float f; unsigned u; } v; v.f = f;
  return (unsigned short)((v.u + 0x7FFFu + ((v.u >> 16) & 1u)) >> 16);
}
__device__ __forceinline__ float bf2f(unsigned short h) {
  union { unsigned u; float f; } v; v.u = ((unsigned)h) << 16;
  return v.f;
}

#define GLD16(SRC, DST) __builtin_amdgcn_global_load_lds( \
    (__attribute__((address_space(1))) void*)(SRC), \
    (__attribute__((address_space(3))) void*)(DST), 16, 0, 0)

#define DPPF(v, ctrl) __int_as_float(__builtin_amdgcn_update_dpp(0, __float_as_int(v), ctrl, 0xF, 0xF, true))
__device__ __forceinline__ float dppmax16(float v) {
  v = fmaxf(v, DPPF(v, 0xB1));
  v = fmaxf(v, DPPF(v, 0x4E));
  v = fmaxf(v, DPPF(v, 0x124));
  v = fmaxf(v, DPPF(v, 0x128));
  return v;
}
__device__ __forceinline__ float dppsum16(float v) {
  v += DPPF(v, 0xB1);
  v += DPPF(v, 0x4E);
  v += DPPF(v, 0x124);
  v += DPPF(v, 0x128);
  return v;
}

// ---------------- transpose fp32 [R][C] -> bf16 [C][R] (batched) ----------------
__global__ __launch_bounds__(256) void transpose_f32_bf16(
    const float* __restrict__ in, unsigned short* __restrict__ out,
    int R, int C, size_t inBS, size_t outBS) {
  __shared__ float tile[32][33];
  const float* inp = in + (size_t)blockIdx.z * inBS;
  unsigned short* outp = out + (size_t)blockIdx.z * outBS;
  int c0 = blockIdx.x * 32, r0 = blockIdx.y * 32;
  int tx = threadIdx.x & 31, ty = threadIdx.x >> 5;
  #pragma unroll
  for (int i = 0; i < 4; ++i) {
    int rr = ty + i * 8;
    tile[rr][tx] = inp[(size_t)(r0 + rr) * C + c0 + tx];
  }
  __syncthreads();
  #pragma unroll
  for (int i = 0; i < 4; ++i) {
    int rr = ty + i * 8;
    outp[(size_t)(c0 + rr) * R + r0 + tx] = f2bf(tile[tx][rr]);
  }
}

// ---------------- interleaved pair transpose for w1/w3 fusion ----------------
__global__ __launch_bounds__(256) void transpose_pair(
    const float* __restrict__ in1, const float* __restrict__ in3,
    unsigned short* __restrict__ out, int K, int C1, size_t inBS, size_t outBS) {
  __shared__ float tile[32][33];
  int z = blockIdx.z; int bat = z >> 1; int f = (z & 1) * 16;
  const float* src = ((z & 1) ? in3 : in1) + (size_t)bat * inBS;
  unsigned short* o = out + (size_t)bat * outBS;
  int c0 = blockIdx.x * 32, r0 = blockIdx.y * 32;
  int tx = threadIdx.x & 31, ty = threadIdx.x >> 5;
  #pragma unroll
  for (int i = 0; i < 4; ++i) {
    int rr = ty + i * 8;
    tile[rr][tx] = src[(size_t)(r0 + rr) * C1 + c0 + tx];
  }
  __syncthreads();
  #pragma unroll
  for (int i = 0; i < 4; ++i) {
    int cc = ty + i * 8;
    int c = c0 + cc;
    int n = ((c >> 4) << 5) + (c & 15) + f;
    o[(size_t)n * K + r0 + tx] = f2bf(tile[tx][cc]);
  }
}

// ---------------- RMS norm -> bf16 ----------------
template<typename TI>
__global__ __launch_bounds__(256) void rms_to_bf16(
    const TI* __restrict__ src, int stride, int off, const float* __restrict__ w,
    unsigned short* __restrict__ out, int Dd, int outStride) {
  int row = blockIdx.x;
  const TI* xr = src + (size_t)row * stride + off;
  float ss = 0.f;
  for (int i = threadIdx.x; i < Dd; i += 256) {
    float v;
    if constexpr (sizeof(TI) == 2) v = bf2f((unsigned short)xr[i]); else v = (float)xr[i];
    ss += v * v;
  }
  for (int o = 1; o < 64; o <<= 1) ss += __shfl_xor(ss, o);
  __shared__ float red[4];
  if ((threadIdx.x & 63) == 0) red[threadIdx.x >> 6] = ss;
  __syncthreads();
  float tot = red[0] + red[1] + red[2] + red[3];
  float inv = 1.f / sqrtf(tot / Dd + 1e-6f);
  for (int i = threadIdx.x; i < Dd; i += 256) {
    float v;
    if constexpr (sizeof(TI) == 2) v = bf2f((unsigned short)xr[i]); else v = (float)xr[i];
    out[(size_t)row * outStride + i] = f2bf(v * inv * w[i]);
  }
}

// ---------------- fused: q_norm + kv_norm + rope_k from lat ----------------
__global__ __launch_bounds__(256) void lat_post(
    const unsigned short* __restrict__ lat, const float* __restrict__ qw,
    const float* __restrict__ kw, const float* __restrict__ fc, const float* __restrict__ fs,
    unsigned short* __restrict__ qn, unsigned short* __restrict__ kvn,
    unsigned short* __restrict__ kr) {
  int row = blockIdx.x, tid = threadIdx.x;
  int lane = tid & 63, wv = tid >> 6;
  const unsigned short* lr = lat + (size_t)row * 768;
  float s1 = 0.f, s2 = 0.f;
  for (int i = tid; i < QLR_; i += 256) { float v = bf2f(lr[i]); s1 += v * v; }
  { float v = bf2f(lr[QLR_ + tid]); s2 = v * v; }
  for (int o = 1; o < 64; o <<= 1) { s1 += __shfl_xor(s1, o); s2 += __shfl_xor(s2, o); }
  __shared__ float red[8];
  if (lane == 0) { red[wv] = s1; red[4 + wv] = s2; }
  __syncthreads();
  float inv1 = 1.f / sqrtf((red[0] + red[1] + red[2] + red[3]) / QLR_ + 1e-6f);
  float inv2 = 1.f / sqrtf((red[4] + red[5] + red[6] + red[7]) / KVLR_ + 1e-6f);
  for (int i = tid; i < QLR_; i += 256)
    qn[(size_t)row * QLR_ + i] = f2bf(bf2f(lr[i]) * inv1 * qw[i]);
  kvn[(size_t)row * KVLR_ + tid] = f2bf(bf2f(lr[QLR_ + tid]) * inv2 * kw[tid]);
  if (tid < 32) {
    int t = row & (T_ - 1);
    float c = fc[t * 32 + tid], s = fs[t * 32 + tid];
    float x0 = bf2f(lr[640 + 2 * tid]), x1 = bf2f(lr[640 + 2 * tid + 1]);
    kr[(size_t)row * ROPE_ + 2 * tid]     = f2bf(x0 * c - x1 * s);
    kr[(size_t)row * ROPE_ + 2 * tid + 1] = f2bf(x0 * s + x1 * c);
  }
}

// ---------------- bf16 MFMA GEMM: C[M,N] = A[M,K] @ Bt[N,K]^T ----------------
// MODE 0: bf16 out. 1: f32 out = acc + addv. 2: f32 out += acc.
// 4: silu-pair -> bf16 [M][N/2]. 5: kv_up special (nope->kvb, V->vt tile-contiguous)
template<int MODE>
__global__ __launch_bounds__(256) void gemm_bf16(
    const unsigned short* __restrict__ A, const unsigned short* __restrict__ Bt,
    void* __restrict__ Cv, int M, int N, int K,
    const float* __restrict__ addv, unsigned short* __restrict__ vtg) {
  __shared__ __align__(16) unsigned short As[128 * 32];
  __shared__ __align__(16) unsigned short Bs[128 * 32];
  const int tid = threadIdx.x;
  const int lane = tid & 63, wave = tid >> 6;
  const int wm = wave >> 1, wn = wave & 1;
  const int bm = blockIdx.y * 128, bn = blockIdx.x * 128;
  const int r = lane & 15, g = lane >> 4;

  f32x4 acc[4][4];
  #pragma unroll
  for (int i = 0; i < 4; ++i)
    #pragma unroll
    for (int j = 0; j < 4; ++j) acc[i][j] = (f32x4)0.f;

  const int rl0 = wave * 16 + (lane >> 2);
  const int rl1 = rl0 + 64;
  const int kc = (lane & 3) * 8;
  char* AsB = (char*)As; char* BsB = (char*)Bs;

  for (int k0 = 0; k0 < K; k0 += 32) {
    GLD16(A + (size_t)(bm + rl0) * K + k0 + kc, AsB + wave * 1024);
    GLD16(A + (size_t)(bm + rl1) * K + k0 + kc, AsB + (wave + 4) * 1024);
    GLD16(Bt + (size_t)(bn + rl0) * K + k0 + kc, BsB + wave * 1024);
    GLD16(Bt + (size_t)(bn + rl1) * K + k0 + kc, BsB + (wave + 4) * 1024);
    __syncthreads();
    short8 af[4], bfr[4];
    #pragma unroll
    for (int mi = 0; mi < 4; ++mi)
      af[mi] = *(const short8*)(As + (wm * 64 + mi * 16 + r) * 32 + g * 8);
    #pragma unroll
    for (int nj = 0; nj < 4; ++nj)
      bfr[nj] = *(const short8*)(Bs + (wn * 64 + nj * 16 + r) * 32 + g * 8);
    #pragma unroll
    for (int mi = 0; mi < 4; ++mi)
      #pragma unroll
      for (int nj = 0; nj < 4; ++nj)
        acc[mi][nj] = __builtin_amdgcn_mfma_f32_16x16x32_bf16(af[mi], bfr[nj], acc[mi][nj], 0, 0, 0);
    __syncthreads();
  }

  if (MODE == 5) {
    unsigned short* C = (unsigned short*)Cv;
    const int colbase = bn + wn * 64;
    const int b = bm >> 11;
    const int hh = colbase >> 8;
    if ((colbase & 255) < 128) {
      #pragma unroll
      for (int mi = 0; mi < 4; ++mi)
        #pragma unroll
        for (int reg = 0; reg < 4; ++reg) {
          int mrow = bm + wm * 64 + mi * 16 + g * 4 + reg;
          size_t bas = (size_t)mrow * N + colbase + r;
          #pragma unroll
          for (int nj = 0; nj < 4; ++nj) C[bas + nj * 16] = f2bf(acc[mi][nj][reg]);
        }
    } else {
      const int tl0 = (bm & 2047) + wm * 64 + g * 4;
      const int d0 = (colbase & 255) - 128 + r;
      const size_t bhbase = (size_t)(b * 8 + hh) * 64;
      #pragma unroll
      for (int mi = 0; mi < 4; ++mi) {
        int t = tl0 + mi * 16;
        size_t tb = (bhbase + (t >> 5)) * 4096 + (t & 31);
        #pragma unroll
        for (int nj = 0; nj < 4; ++nj) {
          int d = d0 + nj * 16;
          us4 pk;
          #pragma unroll
          for (int reg = 0; reg < 4; ++reg) pk[reg] = f2bf(acc[mi][nj][reg]);
          *(us4*)(vtg + tb + (size_t)d * 32) = pk;
        }
      }
    }
    return;
  }

  const int orow0 = wm * 64 + g * 4;
  const int ocol0 = bn + wn * 64 + r;
  #pragma unroll
  for (int mi = 0; mi < 4; ++mi) {
    #pragma unroll
    for (int reg = 0; reg < 4; ++reg) {
      int mrow = bm + orow0 + mi * 16 + reg;
      if (MODE == 4) {
        unsigned short* C = (unsigned short*)Cv;
        size_t bas2 = (size_t)mrow * (N >> 1) + ((bn + wn * 64) >> 1) + r;
        #pragma unroll
        for (int p = 0; p < 2; ++p) {
          float a = acc[mi][2 * p][reg], b3 = acc[mi][2 * p + 1][reg];
          C[bas2 + p * 16] = f2bf((a / (1.f + __expf(-a))) * b3);
        }
      } else {
        size_t bas = (size_t)mrow * N + ocol0;
        if (MODE == 0) {
          unsigned short* C = (unsigned short*)Cv;
          #pragma unroll
          for (int nj = 0; nj < 4; ++nj) C[bas + nj * 16] = f2bf(acc[mi][nj][reg]);
        } else if (MODE == 1) {
          float* C = (float*)Cv;
          #pragma unroll
          for (int nj = 0; nj < 4; ++nj) C[bas + nj * 16] = acc[mi][nj][reg] + addv[bas + nj * 16];
        } else {
          float* C = (float*)Cv;
          #pragma unroll
          for (int nj = 0; nj < 4; ++nj) C[bas + nj * 16] += acc[mi][nj][reg];
        }
      }
    }
  }
}

// ---------------- expert w13 gather GEMM + fused silu -> ehm[slot][512] ----------------
__global__ __launch_bounds__(256) void gemm_moe13(
    const unsigned short* __restrict__ A, const unsigned short* __restrict__ W,
    unsigned short* __restrict__ Cb,
    const int* __restrict__ lists, const int* __restrict__ map, const int* __restrict__ sbase) {
  int mb = map[blockIdx.y];
  if (mb < 0) return;
  const int e = mb >> 16, ib = mb & 0xFFFF;
  __shared__ __align__(16) unsigned short As[128 * 32];
  __shared__ __align__(16) unsigned short Bs[128 * 32];
  const int tid = threadIdx.x, lane = tid & 63, wave = tid >> 6;
  const int wm = wave >> 1, wn = wave & 1;
  const int bn = blockIdx.x * 128;
  const int r = lane & 15, g = lane >> 4;

  f32x4 acc[4][4];
  #pragma unroll
  for (int i = 0; i < 4; ++i)
    #pragma unroll
    for (int j = 0; j < 4; ++j) acc[i][j] = (f32x4)0.f;

  const int rl0 = wave * 16 + (lane >> 2), rl1 = rl0 + 64;
  const int kc = (lane & 3) * 8;
  int t0 = lists[e * LSTR + ib * 128 + rl0]; if (t0 < 0) t0 = 0;
  int t1 = lists[e * LSTR + ib * 128 + rl1]; if (t1 < 0) t1 = 0;
  const unsigned short* Wb = W + (size_t)e * 1024 * 1024;
  char* AsB = (char*)As; char* BsB = (char*)Bs;

  for (int k0 = 0; k0 < 1024; k0 += 32) {
    GLD16(A + (size_t)t0 * 1024 + k0 + kc, AsB + wave * 1024);
    GLD16(A + (size_t)t1 * 1024 + k0 + kc, AsB + (wave + 4) * 1024);
    GLD16(Wb + (size_t)(bn + rl0) * 1024 + k0 + kc, BsB + wave * 1024);
    GLD16(Wb + (size_t)(bn + rl1) * 1024 + k0 + kc, BsB + (wave + 4) * 1024);
    __syncthreads();
    short8 af[4], bfr[4];
    #pragma unroll
    for (int mi = 0; mi < 4; ++mi)
      af[mi] = *(const short8*)(As + (wm * 64 + mi * 16 + r) * 32 + g * 8);
    #pragma unroll
    for (int nj = 0; nj < 4; ++nj)
      bfr[nj] = *(const short8*)(Bs + (wn * 64 + nj * 16 + r) * 32 + g * 8);
    #pragma unroll
    for (int mi = 0; mi < 4; ++mi)
      #pragma unroll
      for (int nj = 0; nj < 4; ++nj)
        acc[mi][nj] = __builtin_amdgcn_mfma_f32_16x16x32_bf16(af[mi], bfr[nj], acc[mi][nj], 0, 0, 0);
    __syncthreads();
  }
  const int sb = sbase[e] + ib * 128;
  const int hc = ((bn + wn * 64) >> 1) + r;
  #pragma unroll
  for (int mi = 0; mi < 4; ++mi)
    #pragma unroll
    for (int reg = 0; reg < 4; ++reg) {
      int srow = sb + wm * 64 + mi * 16 + g * 4 + reg;
      #pragma unroll
      for (int p = 0; p < 2; ++p) {
        float a = acc[mi][2 * p][reg], b3 = acc[mi][2 * p + 1][reg];
        Cb[(size_t)srow * 512 + hc + p * 16] = f2bf((a / (1.f + __expf(-a))) * b3);
      }
    }
}

// ---------------- expert w2 GEMM + weighted atomic scatter ----------------
__global__ __launch_bounds__(256) void gemm_moe2(
    const unsigned short* __restrict__ Am, const unsigned short* __restrict__ W,
    float* __restrict__ out,
    const int* __restrict__ lists, const int* __restrict__ map, const int* __restrict__ sbase,
    const float* __restrict__ cw) {
  int mb = map[blockIdx.y];
  if (mb < 0) return;
  const int e = mb >> 16, ib = mb & 0xFFFF;
  __shared__ __align__(16) unsigned short As[128 * 32];
  __shared__ __align__(16) unsigned short Bs[128 * 32];
  const int tid = threadIdx.x, lane = tid & 63, wave = tid >> 6;
  const int wm = wave >> 1, wn = wave & 1;
  const int bn = blockIdx.x * 128;
  const int r = lane & 15, g = lane >> 4;

  f32x4 acc[4][4];
  #pragma unroll
  for (int i = 0; i < 4; ++i)
    #pragma unroll
    for (int j = 0; j < 4; ++j) acc[i][j] = (f32x4)0.f;

  const int rl0 = wave * 16 + (lane >> 2), rl1 = rl0 + 64;
  const int kc = (lane & 3) * 8;
  const int sb = sbase[e] + ib * 128;
  const unsigned short* Wb = W + (size_t)e * 512 * 1024;
  char* AsB = (char*)As; char* BsB = (char*)Bs;

  for (int k0 = 0; k0 < 512; k0 += 32) {
    GLD16(Am + (size_t)(sb + rl0) * 512 + k0 + kc, AsB + wave * 1024);
    GLD16(Am + (size_t)(sb + rl1) * 512 + k0 + kc, AsB + (wave + 4) * 1024);
    GLD16(Wb + (size_t)(bn + rl0) * 512 + k0 + kc, BsB + wave * 1024);
    GLD16(Wb + (size_t)(bn + rl1) * 512 + k0 + kc, BsB + (wave + 4) * 1024);
    __syncthreads();
    short8 af[4], bfr[4];
    #pragma unroll
    for (int mi = 0; mi < 4; ++mi)
      af[mi] = *(const short8*)(As + (wm * 64 + mi * 16 + r) * 32 + g * 8);
    #pragma unroll
    for (int nj = 0; nj < 4; ++nj)
      bfr[nj] = *(const short8*)(Bs + (wn * 64 + nj * 16 + r) * 32 + g * 8);
    #pragma unroll
    for (int mi = 0; mi < 4; ++mi)
      #pragma unroll
      for (int nj = 0; nj < 4; ++nj)
        acc[mi][nj] = __builtin_amdgcn_mfma_f32_16x16x32_bf16(af[mi], bfr[nj], acc[mi][nj], 0, 0, 0);
    __syncthreads();
  }
  const int ocol0 = bn + wn * 64 + r;
  #pragma unroll
  for (int mi = 0; mi < 4; ++mi)
    #pragma unroll
    for (int reg = 0; reg < 4; ++reg) {
      int orow = wm * 64 + mi * 16 + g * 4 + reg;
      int tok = lists[e * LSTR + ib * 128 + orow];
      if (tok >= 0) {
        float wt = cw[(size_t)tok * E_ + e];
        #pragma unroll
        for (int nj = 0; nj < 4; ++nj)
          atomicAdd(out + (size_t)tok * 1024 + ocol0 + nj * 16, acc[mi][nj][reg] * wt);
      }
    }
}

// ---------------- MFMA flash attention, split-K x2, Q-in-regs, tile-contiguous V ----------------
#define AQ 64
#define AK 32
#define VP 40
__global__ __launch_bounds__(256) void attn_mfma(
    const unsigned short* __restrict__ q,   // [NTOK][H][192] (rope NOT applied)
    const unsigned short* __restrict__ kv,  // [NTOK][H][256] (nope half valid)
    const unsigned short* __restrict__ kr,  // [NTOK][64]
    const unsigned short* __restrict__ vt,  // [16][64][128][32] tile-contiguous
    const float* __restrict__ fcos, const float* __restrict__ fsin,
    unsigned short* __restrict__ po,        // [16*32*2][64*128] bf16 unnormalized O
    float* __restrict__ pml) {              // [16*32*2][64*2] (m, l)
  __shared__ __align__(16) unsigned short Ks[AK * 192];    // row-major pitch 384B, XOR-swizzled
  __shared__ __align__(16) unsigned short Vl[128 * VP];
  __shared__ __align__(16) unsigned short Ps[4 * 16 * VP];
  const int tid = threadIdx.x, lane = tid & 63, wave = tid >> 6;
  const int r = lane & 15, g = lane >> 4;
  const int bh = blockIdx.y, b = bh >> 3, h = bh & 7;
  const int qt = gridDim.x - 1 - blockIdx.x;   // LPT
  const int q0 = qt * AQ;
  const int half = blockIdx.z;
  const int hnt = qt + 1;                      // tiles per half
  const int kb = half * hnt, ke = kb + hnt;
  const size_t bT = (size_t)b * T_;
  const unsigned short* vbase = vt + (size_t)bh * 64 * 4096;
  char* KsB = (char*)Ks;

  // ---- Q into registers with fused RoPE ----
  short8 qf[6];
  const int qrow = q0 + wave * 16 + r;         // sequence position
  {
    const unsigned short* qb = q + ((bT + qrow) * H_ + h) * 192;
    #pragma unroll
    for (int kk = 0; kk < 6; ++kk) qf[kk] = *(const short8*)(qb + kk * 32 + g * 8);
    #pragma unroll
    for (int kk = 4; kk < 6; ++kk) {
      int i0 = (kk - 4) * 16 + g * 4;
      #pragma unroll
      for (int p = 0; p < 4; ++p) {
        float cc = fcos[qrow * 32 + i0 + p], sn = fsin[qrow * 32 + i0 + p];
        float x0 = bf2f((unsigned short)qf[kk][2 * p]), x1 = bf2f((unsigned short)qf[kk][2 * p + 1]);
        qf[kk][2 * p]     = (short)f2bf(x0 * cc - x1 * sn);
        qf[kk][2 * p + 1] = (short)f2bf(x0 * sn + x1 * cc);
      }
    }
  }

  float m_i[4], l_i[4];
  f32x4 o[8];
  #pragma unroll
  for (int i = 0; i < 4; ++i) { m_i[i] = -1e30f; l_i[i] = 0.f; }
  #pragma unroll
  for (int cb = 0; cb < 8; ++cb) o[cb] = (f32x4)0.f;

  const float scale2 = 0.07216878364870322f * 1.44269504088896f; // 1/sqrt(192)*log2e

  // prefetch tile kb (V now tile-contiguous: 8KB dense block per key-tile)
  short8 kreg[3], vreg[2];
  int krow[3], kcol[3];
  #pragma unroll
  for (int it = 0; it < 3; ++it) {
    int c = tid + it * 256;
    krow[it] = c / 24; kcol[it] = c % 24;
    kreg[it] = (kcol[it] < 16)
      ? *(const short8*)(kv + ((bT + kb * AK + krow[it]) * H_ + h) * 256 + kcol[it] * 8)
      : *(const short8*)(kr + (bT + kb * AK + krow[it]) * 64 + (kcol[it] - 16) * 8);
  }
  #pragma unroll
  for (int it = 0; it < 2; ++it) {
    int x = tid + it * 256;
    vreg[it] = *(const short8*)(vbase + (size_t)kb * 4096 + x * 8);
  }

  for (int kt = kb; kt < ke; ++kt) {
    // barrier A: all waves finished READING prev tile's Ks/Vl. Raw barrier — no vmcnt
    // drain, so the K/V register-prefetch loads stay in flight across it (T4).
    __builtin_amdgcn_s_barrier();
    __builtin_amdgcn_sched_barrier(0);
    #pragma unroll
    for (int it = 0; it < 3; ++it)
      *(short8*)(KsB + ((krow[it] * 384 + kcol[it] * 16) ^ ((krow[it] & 7) << 4))) = kreg[it];
    #pragma unroll
    for (int it = 0; it < 2; ++it) {
      int x = tid + it * 256;
      *(short8*)(Vl + (x >> 2) * VP + (x & 3) * 8) = vreg[it];
    }
    // barrier B: stores visible to all waves; only LDS counter drained.
    asm volatile("s_waitcnt lgkmcnt(0)" ::: "memory");
    __builtin_amdgcn_s_barrier();
    __builtin_amdgcn_sched_barrier(0);

    if (kt + 1 < ke) {
      int k1 = (kt + 1) * AK;
      #pragma unroll
      for (int it = 0; it < 3; ++it)
        kreg[it] = (kcol[it] < 16)
          ? *(const short8*)(kv + ((bT + k1 + krow[it]) * H_ + h) * 256 + kcol[it] * 8)
          : *(const short8*)(kr + (bT + k1 + krow[it]) * 64 + (kcol[it] - 16) * 8);
      #pragma unroll
      for (int it = 0; it < 2; ++it) {
        int x = tid + it * 256;
        vreg[it] = *(const short8*)(vbase + (size_t)(kt + 1) * 4096 + x * 8);
      }
    }

    const int k0 = kt * AK;
    f32x4 sf0 = (f32x4)0.f, sf1 = (f32x4)0.f;
    {
      int ksw = (r & 7) << 4;
      __builtin_amdgcn_s_setprio(1);
      #pragma unroll
      for (int kk = 0; kk < 6; ++kk) {
        short8 b0 = *(const short8*)(KsB + ((r * 384 + kk * 64 + g * 16) ^ ksw));
        short8 b1 = *(const short8*)(KsB + (((16 + r) * 384 + kk * 64 + g * 16) ^ ksw));
        sf0 = __builtin_amdgcn_mfma_f32_16x16x32_bf16(qf[kk], b0, sf0, 0, 0, 0);
        sf1 = __builtin_amdgcn_mfma_f32_16x16x32_bf16(qf[kk], b1, sf1, 0, 0, 0);
      }
      __builtin_amdgcn_s_setprio(0);
    }

    float fac[4];
    bool needs = false;
    const bool bnd = (k0 + AK > q0);   // masks needed only on diagonal tiles (<=2/block)
    #pragma unroll
    for (int reg = 0; reg < 4; ++reg) {
      float s0 = sf0[reg] * scale2;   // log2 domain
      float s1 = sf1[reg] * scale2;
      if (bnd) {
        int qp = q0 + wave * 16 + g * 4 + reg;
        if (k0 + r > qp) s0 = -1e30f;
        if (k0 + 16 + r > qp) s1 = -1e30f;
      }
      float mt = dppmax16(fmaxf(s0, s1));
      float fc = 1.f, mn = m_i[reg];
      if (mt > mn + 8.f) {            // defer-max
        mn = mt; fc = exp2f(m_i[reg] - mn); m_i[reg] = mn; needs = true;
      }
      float e0 = exp2f(s0 - mn), e1 = exp2f(s1 - mn);
      float rs = dppsum16(e0 + e1);
      l_i[reg] = l_i[reg] * fc + rs;
      fac[reg] = fc;
      __hip_bfloat162 pk = __float22bfloat162_rn(float2{e0, e1});
      unsigned u = *(unsigned*)&pk;
      int prow = g * 4 + reg;
      Ps[wave * 16 * VP + prow * VP + r] = (unsigned short)u;
      Ps[wave * 16 * VP + prow * VP + 16 + r] = (unsigned short)(u >> 16);
    }
    if (__any(needs)) {
      #pragma unroll
      for (int cb = 0; cb < 8; ++cb)
        #pragma unroll
        for (int reg = 0; reg < 4; ++reg) o[cb][reg] *= fac[reg];
    }
    short8 pa = *(const short8*)(Ps + wave * 16 * VP + r * VP + g * 8);
    __builtin_amdgcn_s_setprio(1);
    #pragma unroll
    for (int cb = 0; cb < 8; ++cb) {
      short8 vb = *(const short8*)(Vl + (cb * 16 + r) * VP + g * 8);
      o[cb] = __builtin_amdgcn_mfma_f32_16x16x32_bf16(pa, vb, o[cb], 0, 0, 0);
    }
    __builtin_amdgcn_s_setprio(0);
  }

  // ---- write partial (unnormalized O bf16, m/l fp32) ----
  const int slab = (bh * 32 + qt) * 2 + half;
  unsigned short* pob = po + (size_t)slab * 8192;
  float* pmlb = pml + (size_t)slab * 128;
  #pragma unroll
  for (int reg = 0; reg < 4; ++reg) {
    int row = wave * 16 + g * 4 + reg;
    if (r == 0) { pmlb[row * 2] = m_i[reg]; pmlb[row * 2 + 1] = l_i[reg]; }
    #pragma unroll
    for (int cb = 0; cb < 8; ++cb)
      pob[row * 128 + cb * 16 + r] = f2bf(o[cb][reg]);
  }
}

// ---------------- split-K combine: merge 2 halves -> y bf16 ----------------
__global__ __launch_bounds__(256) void attn_combine(
    const unsigned short* __restrict__ po, const float* __restrict__ pml,
    unsigned short* __restrict__ y) {
  const int qt = blockIdx.x, bh = blockIdx.y, b = bh >> 3, h = bh & 7;
  const int s0 = (bh * 32 + qt) * 2, s1 = s0 + 1;
  const int row = threadIdx.x >> 2;
  const int qp = threadIdx.x & 3;
  float m0 = pml[(size_t)s0 * 128 + row * 2], l0 = pml[(size_t)s0 * 128 + row * 2 + 1];
  float m1 = pml[(size_t)s1 * 128 + row * 2], l1 = pml[(size_t)s1 * 128 + row * 2 + 1];
  float m = fmaxf(m0, m1);
  float e0 = exp2f(m0 - m), e1 = exp2f(m1 - m);
  float inv = 1.f / (l0 * e0 + l1 * e1);
  e0 *= inv; e1 *= inv;
  const unsigned short* o0 = po + (size_t)s0 * 8192 + row * 128 + qp * 32;
  const unsigned short* o1 = po + (size_t)s1 * 8192 + row * 128 + qp * 32;
  unsigned short* yb = y + ((size_t)(b * T_ + qt * 64 + row)) * 1024 + h * 128 + qp * 32;
  #pragma unroll
  for (int v = 0; v < 4; ++v) {
    short8 a = *(const short8*)(o0 + v * 8);
    short8 c = *(const short8*)(o1 + v * 8);
    short8 w;
    #pragma unroll
    for (int j = 0; j < 8; ++j)
      w[j] = (short)f2bf(bf2f((unsigned short)a[j]) * e0 + bf2f((unsigned short)c[j]) * e1);
    *(short8*)(yb + v * 8) = w;
  }
}

// ---------------- fused rms2 + gate (logits, softmax, top2) ----------------
__global__ __launch_bounds__(256) void rms2_gate(
    const float* __restrict__ xo, const float* __restrict__ rw, const float* __restrict__ gw,
    unsigned short* __restrict__ h2b, float* __restrict__ cw) {
  int row = blockIdx.x, tid = threadIdx.x;
  int lane = tid & 63, wv = tid >> 6;
  const float* xr = xo + (size_t)row * D_;
  float v[4]; float ss = 0.f;
  #pragma unroll
  for (int j = 0; j < 4; ++j) { v[j] = xr[tid + j * 256]; ss += v[j] * v[j]; }
  for (int o = 1; o < 64; o <<= 1) ss += __shfl_xor(ss, o);
  __shared__ float red[4];
  if (lane == 0) red[wv] = ss;
  __syncthreads();
  float inv = 1.f / sqrtf((red[0] + red[1] + red[2] + red[3]) / D_ + 1e-6f);
  float a[E_] = {0, 0, 0, 0, 0, 0, 0, 0};
  #pragma unroll
  for (int j = 0; j < 4; ++j) {
    int i = tid + j * 256;
    float hv = v[j] * inv * rw[i];
    h2b[(size_t)row * D_ + i] = f2bf(hv);
    const float* wr = gw + (size_t)i * E_;
    #pragma unroll
    for (int e = 0; e < E_; ++e) a[e] += hv * wr[e];
  }
  #pragma unroll
  for (int e = 0; e < E_; ++e) {
    float t = a[e];
    for (int o = 1; o < 64; o <<= 1) t += __shfl_xor(t, o);
    a[e] = t;
  }
  __shared__ float ga[4][E_];
  if (lane == 0)
    #pragma unroll
    for (int e = 0; e < E_; ++e) ga[wv][e] = a[e];
  __syncthreads();
  if (tid == 0) {
    float lg[E_];
    #pragma unroll
    for (int e = 0; e < E_; ++e) lg[e] = ga[0][e] + ga[1][e] + ga[2][e] + ga[3][e];
    float mx = lg[0];
    #pragma unroll
    for (int e = 1; e < E_; ++e) mx = fmaxf(mx, lg[e]);
    float sum = 0.f; float p[E_];
    #pragma unroll
    for (int e = 0; e < E_; ++e) { p[e] = __expf(lg[e] - mx); sum += p[e]; }
    float is = 1.f / sum;
    int i1 = 0; float b1 = p[0];
    #pragma unroll
    for (int e = 1; e < E_; ++e) if (p[e] > b1) { b1 = p[e]; i1 = e; }
    int i2 = -1; float b2 = -1.f;
    #pragma unroll
    for (int e = 0; e < E_; ++e) if (e != i1 && p[e] > b2) { b2 = p[e]; i2 = e; }
    #pragma unroll
    for (int e = 0; e < E_; ++e)
      cw[(size_t)row * E_ + e] = (e == i1) ? b1 * is : (e == i2 ? b2 * is : 0.f);
  }
}

// ---------------- MoE token compaction (ballot-based, deterministic) ----------------
__global__ __launch_bounds__(256) void moe_build(const float* __restrict__ cw,
                                                 int* __restrict__ lists, int* __restrict__ counts) {
  int e = blockIdx.x, tid = threadIdx.x;
  int lane = tid & 63, wv = tid >> 6;
  __shared__ int wsum[4];
  __shared__ int base;
  if (tid == 0) base = 0;
  __syncthreads();
  for (int c0 = 0; c0 < NTOK; c0 += 256) {
    int tok = c0 + tid;
    bool f = cw[(size_t)tok * E_ + e] > 0.f;
    unsigned long long m = __ballot(f);
    int pos = __popcll(m & ((1ull << lane) - 1ull));
    if (lane == 0) wsum[wv] = __popcll(m);
    __syncthreads();
    int woff = base;
    #pragma unroll
    for (int w = 0; w < 4; ++w) if (w < wv) woff += wsum[w];
    if (f) lists[e * LSTR + woff + pos] = tok;
    __syncthreads();
    if (tid == 0) base += wsum[0] + wsum[1] + wsum[2] + wsum[3];
    __syncthreads();
  }
  int cnt = base;
  int padded = (cnt + 127) & ~127;
  for (int i2 = cnt + tid; i2 < padded; i2 += 256) lists[e * LSTR + i2] = -1;
  if (tid == 0) { counts[e] = cnt; counts[8 + e] = padded >> 7; }
}

__global__ void moe_finalize(const int* __restrict__ counts, int* __restrict__ map,
                             int* __restrict__ sbase) {
  if (threadIdx.x == 0 && blockIdx.x == 0) {
    int cum = 0;
    for (int e = 0; e < E_; ++e) {
      sbase[e] = cum * 128;
      int nb = counts[8 + e];
      for (int i = 0; i < nb; ++i) map[cum + i] = (e << 16) | i;
      cum += nb;
    }
    for (; cum < MAXMB; ++cum) map[cum] = -1;
  }
}

extern "C" void kernel_launch(void* const* d_in, const int* in_sizes, int n_in,
                              void* d_out, int out_size, void* d_ws, size_t ws_size,
                              hipStream_t stream) {
  const float* x        = (const float*)d_in[0];
  const float* fcos     = (const float*)d_in[1];
  const float* fsin     = (const float*)d_in[2];
  const float* rmsn1_w  = (const float*)d_in[3];
  const float* rmsn2_w  = (const float*)d_in[4];
  const float* latent_w = (const float*)d_in[5];
  const float* q_norm_w = (const float*)d_in[6];
  const float* q_up_w   = (const float*)d_in[7];
  const float* kv_norm_w= (const float*)d_in[8];
  const float* kv_up_w  = (const float*)d_in[9];
  const float* c_proj_w = (const float*)d_in[10];
  const float* gate_w   = (const float*)d_in[11];
  const float* sh_w1    = (const float*)d_in[12];
  const float* sh_w2    = (const float*)d_in[13];
  const float* sh_w3    = (const float*)d_in[14];
  const float* e_w1     = (const float*)d_in[15];
  const float* e_w2     = (const float*)d_in[16];
  const float* e_w3     = (const float*)d_in[17];
  float* out = (float*)d_out;

  char* base = (char*)d_ws;
  size_t off = 0;
  auto take = [&](size_t bytes) { char* p = base + off; off += (bytes + 255) & ~(size_t)255; return p; };
  unsigned short* Wlat  = (unsigned short*)take((size_t)768 * 1024 * 2);
  unsigned short* Wqup  = (unsigned short*)take((size_t)1536 * 384 * 2);
  unsigned short* Wkv   = (unsigned short*)take((size_t)2048 * 256 * 2);
  unsigned short* Wcp   = (unsigned short*)take((size_t)1024 * 1024 * 2);
  unsigned short* Wsh13 = (unsigned short*)take((size_t)2048 * 1024 * 2);
  unsigned short* Wsh2  = (unsigned short*)take((size_t)1024 * 1024 * 2);
  unsigned short* Wew13 = (unsigned short*)take((size_t)8 * 1024 * 1024 * 2);
  unsigned short* Wew2  = (unsigned short*)take((size_t)8 * 1024 * 512 * 2);
  float* cw             = (float*)take((size_t)NTOK * E_ * 4);
  int* lists            = (int*)take((size_t)E_ * LSTR * 4);
  int* counts           = (int*)take(64 * 4);
  int* map              = (int*)take(MAXMB * 4);
  int* sbase            = (int*)take(E_ * 4);
  unsigned short* Vtg   = (unsigned short*)take((size_t)16 * 64 * 4096 * 2);
  unsigned short* kr    = (unsigned short*)take((size_t)NTOK * 64 * 2);
  float* pml            = (float*)take((size_t)1024 * 128 * 4);

  size_t actStart = off;
  size_t aoff = actStart;
  auto takeA = [&](size_t bytes) { char* p = base + aoff; aoff += (bytes + 255) & ~(size_t)255; return p; };
  unsigned short* h_bf = (unsigned short*)takeA((size_t)NTOK * 1024 * 2);
  unsigned short* lat  = (unsigned short*)takeA((size_t)NTOK * 768 * 2);
  unsigned short* qn   = (unsigned short*)takeA((size_t)NTOK * 384 * 2);
  unsigned short* kvn  = (unsigned short*)takeA((size_t)NTOK * 256 * 2);
  unsigned short* qq   = (unsigned short*)takeA((size_t)NTOK * 1536 * 2);
  unsigned short* kvb  = (unsigned short*)takeA((size_t)NTOK * 2048 * 2);
  unsigned short* y    = (unsigned short*)takeA((size_t)NTOK * 1024 * 2);

  // split-K partial O (16 MB bf16) aliases h_bf/lat/qn (dead during attention)
  unsigned short* po   = (unsigned short*)(base + actStart);

  size_t coff = actStart;
  auto takeC = [&](size_t bytes) { char* p = base + coff; coff += (bytes + 255) & ~(size_t)255; return p; };
  unsigned short* h2b  = (unsigned short*)takeC((size_t)NTOK * 1024 * 2);
  unsigned short* t1m  = (unsigned short*)takeC((size_t)NTOK * 1024 * 2);
  unsigned short* ehm  = (unsigned short*)takeC((size_t)9216 * 512 * 2);

  dim3 blk(256);

  // --- weight conversion ---
  transpose_f32_bf16<<<dim3(22, 32, 1), blk, 0, stream>>>(latent_w, Wlat, 1024, 704, 0, 0);
  transpose_f32_bf16<<<dim3(48, 12, 1), blk, 0, stream>>>(q_up_w, Wqup, 384, 1536, 0, 0);
  transpose_f32_bf16<<<dim3(64, 8, 1), blk, 0, stream>>>(kv_up_w, Wkv, 256, 2048, 0, 0);
  transpose_f32_bf16<<<dim3(32, 32, 1), blk, 0, stream>>>(c_proj_w, Wcp, 1024, 1024, 0, 0);
  transpose_f32_bf16<<<dim3(32, 32, 1), blk, 0, stream>>>(sh_w2, Wsh2, 1024, 1024, 0, 0);
  transpose_pair<<<dim3(32, 32, 2), blk, 0, stream>>>(sh_w1, sh_w3, Wsh13, 1024, 1024, 0, 0);
  transpose_pair<<<dim3(16, 32, 16), blk, 0, stream>>>(e_w1, e_w3, Wew13, 1024, 512,
      (size_t)1024 * 512, (size_t)1024 * 1024);
  transpose_f32_bf16<<<dim3(32, 16, 8), blk, 0, stream>>>(e_w2, Wew2, 512, 1024,
      (size_t)512 * 1024, (size_t)1024 * 512);

  rms_to_bf16<float><<<NTOK, blk, 0, stream>>>(x, D_, 0, rmsn1_w, h_bf, D_, D_);
  gemm_bf16<0><<<dim3(6, 32), blk, 0, stream>>>(h_bf, Wlat, lat, NTOK, 768, 1024, nullptr, nullptr);
  lat_post<<<NTOK, blk, 0, stream>>>(lat, q_norm_w, kv_norm_w, fcos, fsin, qn, kvn, kr);
  gemm_bf16<0><<<dim3(12, 32), blk, 0, stream>>>(qn, Wqup, qq, NTOK, 1536, 384, nullptr, nullptr);
  gemm_bf16<5><<<dim3(16, 32), blk, 0, stream>>>(kvn, Wkv, kvb, NTOK, 2048, 256, nullptr, Vtg);
  attn_mfma<<<dim3(T_ / AQ, B_ * H_, 2), blk, 0, stream>>>(qq, kvb, kr, Vtg, fcos, fsin, po, pml);
  attn_combine<<<dim3(T_ / AQ, B_ * H_), blk, 0, stream>>>(po, pml, y);
  gemm_bf16<1><<<dim3(8, 32), blk, 0, stream>>>(y, Wcp, out, NTOK, 1024, 1024, x, nullptr);
  rms2_gate<<<NTOK, blk, 0, stream>>>(out, rmsn2_w, gate_w, h2b, cw);
  moe_build<<<E_, blk, 0, stream>>>(cw, lists, counts);
  moe_finalize<<<1, 64, 0, stream>>>(counts, map, sbase);
  // shared expert (silu fused into w13 GEMM epilogue)
  gemm_bf16<4><<<dim3(16, 32), blk, 0, stream>>>(h2b, Wsh13, t1m, NTOK, 2048, 1024, nullptr, nullptr);
  gemm_bf16<2><<<dim3(8, 32), blk, 0, stream>>>(t1m, Wsh2, out, NTOK, 1024, 1024, nullptr, nullptr);
  // sparse experts (silu fused)
  gemm_moe13<<<dim3(8, MAXMB), blk, 0, stream>>>(h2b, Wew13, ehm, lists, map, sbase);
  gemm_moe2<<<dim3(8, MAXMB), blk, 0, stream>>>(ehm, Wew2, out, lists, map, sbase, cw);
}

// Round 11
// 397.818 us; speedup vs baseline: 1.0472x; 1.0435x over previous
//
#include <hip/hip_runtime.h>
#include <hip/hip_bf16.h>
#include <math.h>

#define D_ 1024
#define H_ 8
#define QLR_ 384
#define KVLR_ 256
#define NOPE_ 128
#define ROPE_ 64
#define VD_ 128
#define E_ 8
#define INTER_ 512
#define B_ 2
#define T_ 2048
#define QKD_ 192
#define NTOK (B_*T_)
#define LSTR 4608
#define MAXMB 72

typedef __attribute__((ext_vector_type(8))) short short8;
typedef __attribute__((ext_vector_type(4))) float f32x4;
typedef __attribute__((ext_vector_type(4))) unsigned short us4;

__device__ __forceinline__ unsigned short f2bf(float f) {
  union { float f; unsigned u; } v; v.f = f;
  return (unsigned short)((v.u + 0x7FFFu + ((v.u >> 16) & 1u)) >> 16);
}
__device__ __forceinline__ float bf2f(unsigned short h) {
  union { unsigned u; float f; } v; v.u = ((unsigned)h) << 16;
  return v.f;
}

#define GLD16(SRC, DST) __builtin_amdgcn_global_load_lds( \
    (__attribute__((address_space(1))) void*)(SRC), \
    (__attribute__((address_space(3))) void*)(DST), 16, 0, 0)

#define DPPF(v, ctrl) __int_as_float(__builtin_amdgcn_update_dpp(0, __float_as_int(v), ctrl, 0xF, 0xF, true))
__device__ __forceinline__ float dppmax16(float v) {
  v = fmaxf(v, DPPF(v, 0xB1));
  v = fmaxf(v, DPPF(v, 0x4E));
  v = fmaxf(v, DPPF(v, 0x124));
  v = fmaxf(v, DPPF(v, 0x128));
  return v;
}
__device__ __forceinline__ float dppsum16(float v) {
  v += DPPF(v, 0xB1);
  v += DPPF(v, 0x4E);
  v += DPPF(v, 0x124);
  v += DPPF(v, 0x128);
  return v;
}

// ---------------- transpose fp32 [R][C] -> bf16 [C][R] (batched) ----------------
__global__ __launch_bounds__(256) void transpose_f32_bf16(
    const float* __restrict__ in, unsigned short* __restrict__ out,
    int R, int C, size_t inBS, size_t outBS) {
  __shared__ float tile[32][33];
  const float* inp = in + (size_t)blockIdx.z * inBS;
  unsigned short* outp = out + (size_t)blockIdx.z * outBS;
  int c0 = blockIdx.x * 32, r0 = blockIdx.y * 32;
  int tx = threadIdx.x & 31, ty = threadIdx.x >> 5;
  #pragma unroll
  for (int i = 0; i < 4; ++i) {
    int rr = ty + i * 8;
    tile[rr][tx] = inp[(size_t)(r0 + rr) * C + c0 + tx];
  }
  __syncthreads();
  #pragma unroll
  for (int i = 0; i < 4; ++i) {
    int rr = ty + i * 8;
    outp[(size_t)(c0 + rr) * R + r0 + tx] = f2bf(tile[tx][rr]);
  }
}

// ---------------- interleaved pair transpose for w1/w3 fusion ----------------
__global__ __launch_bounds__(256) void transpose_pair(
    const float* __restrict__ in1, const float* __restrict__ in3,
    unsigned short* __restrict__ out, int K, int C1, size_t inBS, size_t outBS) {
  __shared__ float tile[32][33];
  int z = blockIdx.z; int bat = z >> 1; int f = (z & 1) * 16;
  const float* src = ((z & 1) ? in3 : in1) + (size_t)bat * inBS;
  unsigned short* o = out + (size_t)bat * outBS;
  int c0 = blockIdx.x * 32, r0 = blockIdx.y * 32;
  int tx = threadIdx.x & 31, ty = threadIdx.x >> 5;
  #pragma unroll
  for (int i = 0; i < 4; ++i) {
    int rr = ty + i * 8;
    tile[rr][tx] = src[(size_t)(r0 + rr) * C1 + c0 + tx];
  }
  __syncthreads();
  #pragma unroll
  for (int i = 0; i < 4; ++i) {
    int cc = ty + i * 8;
    int c = c0 + cc;
    int n = ((c >> 4) << 5) + (c & 15) + f;
    o[(size_t)n * K + r0 + tx] = f2bf(tile[tx][cc]);
  }
}

// ---------------- RMS norm -> bf16 ----------------
template<typename TI>
__global__ __launch_bounds__(256) void rms_to_bf16(
    const TI* __restrict__ src, int stride, int off, const float* __restrict__ w,
    unsigned short* __restrict__ out, int Dd, int outStride) {
  int row = blockIdx.x;
  const TI* xr = src + (size_t)row * stride + off;
  float ss = 0.f;
  for (int i = threadIdx.x; i < Dd; i += 256) {
    float v;
    if constexpr (sizeof(TI) == 2) v = bf2f((unsigned short)xr[i]); else v = (float)xr[i];
    ss += v * v;
  }
  for (int o = 1; o < 64; o <<= 1) ss += __shfl_xor(ss, o);
  __shared__ float red[4];
  if ((threadIdx.x & 63) == 0) red[threadIdx.x >> 6] = ss;
  __syncthreads();
  float tot = red[0] + red[1] + red[2] + red[3];
  float inv = 1.f / sqrtf(tot / Dd + 1e-6f);
  for (int i = threadIdx.x; i < Dd; i += 256) {
    float v;
    if constexpr (sizeof(TI) == 2) v = bf2f((unsigned short)xr[i]); else v = (float)xr[i];
    out[(size_t)row * outStride + i] = f2bf(v * inv * w[i]);
  }
}

// ---------------- fused: q_norm + kv_norm + rope_k from lat ----------------
__global__ __launch_bounds__(256) void lat_post(
    const unsigned short* __restrict__ lat, const float* __restrict__ qw,
    const float* __restrict__ kw, const float* __restrict__ fc, const float* __restrict__ fs,
    unsigned short* __restrict__ qn, unsigned short* __restrict__ kvn,
    unsigned short* __restrict__ kr) {
  int row = blockIdx.x, tid = threadIdx.x;
  int lane = tid & 63, wv = tid >> 6;
  const unsigned short* lr = lat + (size_t)row * 768;
  float s1 = 0.f, s2 = 0.f;
  for (int i = tid; i < QLR_; i += 256) { float v = bf2f(lr[i]); s1 += v * v; }
  { float v = bf2f(lr[QLR_ + tid]); s2 = v * v; }
  for (int o = 1; o < 64; o <<= 1) { s1 += __shfl_xor(s1, o); s2 += __shfl_xor(s2, o); }
  __shared__ float red[8];
  if (lane == 0) { red[wv] = s1; red[4 + wv] = s2; }
  __syncthreads();
  float inv1 = 1.f / sqrtf((red[0] + red[1] + red[2] + red[3]) / QLR_ + 1e-6f);
  float inv2 = 1.f / sqrtf((red[4] + red[5] + red[6] + red[7]) / KVLR_ + 1e-6f);
  for (int i = tid; i < QLR_; i += 256)
    qn[(size_t)row * QLR_ + i] = f2bf(bf2f(lr[i]) * inv1 * qw[i]);
  kvn[(size_t)row * KVLR_ + tid] = f2bf(bf2f(lr[QLR_ + tid]) * inv2 * kw[tid]);
  if (tid < 32) {
    int t = row & (T_ - 1);
    float c = fc[t * 32 + tid], s = fs[t * 32 + tid];
    float x0 = bf2f(lr[640 + 2 * tid]), x1 = bf2f(lr[640 + 2 * tid + 1]);
    kr[(size_t)row * ROPE_ + 2 * tid]     = f2bf(x0 * c - x1 * s);
    kr[(size_t)row * ROPE_ + 2 * tid + 1] = f2bf(x0 * s + x1 * c);
  }
}

// ---------------- bf16 MFMA GEMM: C[M,N] = A[M,K] @ Bt[N,K]^T ----------------
// MODE 0: bf16 out. 1: f32 out = acc + addv.
template<int MODE>
__global__ __launch_bounds__(256) void gemm_bf16(
    const unsigned short* __restrict__ A, const unsigned short* __restrict__ Bt,
    void* __restrict__ Cv, int M, int N, int K,
    const float* __restrict__ addv) {
  __shared__ __align__(16) unsigned short As[128 * 32];
  __shared__ __align__(16) unsigned short Bs[128 * 32];
  const int tid = threadIdx.x;
  const int lane = tid & 63, wave = tid >> 6;
  const int wm = wave >> 1, wn = wave & 1;
  const int bm = blockIdx.y * 128, bn = blockIdx.x * 128;
  const int r = lane & 15, g = lane >> 4;

  f32x4 acc[4][4];
  #pragma unroll
  for (int i = 0; i < 4; ++i)
    #pragma unroll
    for (int j = 0; j < 4; ++j) acc[i][j] = (f32x4)0.f;

  const int rl0 = wave * 16 + (lane >> 2);
  const int rl1 = rl0 + 64;
  const int kc = (lane & 3) * 8;
  char* AsB = (char*)As; char* BsB = (char*)Bs;

  for (int k0 = 0; k0 < K; k0 += 32) {
    GLD16(A + (size_t)(bm + rl0) * K + k0 + kc, AsB + wave * 1024);
    GLD16(A + (size_t)(bm + rl1) * K + k0 + kc, AsB + (wave + 4) * 1024);
    GLD16(Bt + (size_t)(bn + rl0) * K + k0 + kc, BsB + wave * 1024);
    GLD16(Bt + (size_t)(bn + rl1) * K + k0 + kc, BsB + (wave + 4) * 1024);
    __syncthreads();
    short8 af[4], bfr[4];
    #pragma unroll
    for (int mi = 0; mi < 4; ++mi)
      af[mi] = *(const short8*)(As + (wm * 64 + mi * 16 + r) * 32 + g * 8);
    #pragma unroll
    for (int nj = 0; nj < 4; ++nj)
      bfr[nj] = *(const short8*)(Bs + (wn * 64 + nj * 16 + r) * 32 + g * 8);
    #pragma unroll
    for (int mi = 0; mi < 4; ++mi)
      #pragma unroll
      for (int nj = 0; nj < 4; ++nj)
        acc[mi][nj] = __builtin_amdgcn_mfma_f32_16x16x32_bf16(af[mi], bfr[nj], acc[mi][nj], 0, 0, 0);
    __syncthreads();
  }

  const int orow0 = wm * 64 + g * 4;
  const int ocol0 = bn + wn * 64 + r;
  #pragma unroll
  for (int mi = 0; mi < 4; ++mi) {
    #pragma unroll
    for (int reg = 0; reg < 4; ++reg) {
      int mrow = bm + orow0 + mi * 16 + reg;
      size_t bas = (size_t)mrow * N + ocol0;
      if (MODE == 0) {
        unsigned short* C = (unsigned short*)Cv;
        #pragma unroll
        for (int nj = 0; nj < 4; ++nj) C[bas + nj * 16] = f2bf(acc[mi][nj][reg]);
      } else {
        float* C = (float*)Cv;
        #pragma unroll
        for (int nj = 0; nj < 4; ++nj) C[bas + nj * 16] = acc[mi][nj][reg] + addv[bas + nj * 16];
      }
    }
  }
}

// ---------------- merged q_up + kv_up GEMM (one dispatch, 896 blocks) ----------------
__global__ __launch_bounds__(256) void gemm_qkv(
    const unsigned short* __restrict__ qn, const unsigned short* __restrict__ Wqup,
    const unsigned short* __restrict__ kvn, const unsigned short* __restrict__ Wkv,
    unsigned short* __restrict__ qq, unsigned short* __restrict__ kvb,
    unsigned short* __restrict__ vtg) {
  __shared__ __align__(16) unsigned short As[128 * 32];
  __shared__ __align__(16) unsigned short Bs[128 * 32];
  const int tid = threadIdx.x;
  const int lane = tid & 63, wave = tid >> 6;
  const int wm = wave >> 1, wn = wave & 1;
  const bool isQ = blockIdx.x < 12;
  const int bx = isQ ? blockIdx.x : blockIdx.x - 12;
  const unsigned short* A  = isQ ? qn : kvn;
  const unsigned short* Bt = isQ ? Wqup : Wkv;
  const int N = isQ ? 1536 : 2048;
  const int K = isQ ? QLR_ : KVLR_;
  const int bm = blockIdx.y * 128, bn = bx * 128;
  const int r = lane & 15, g = lane >> 4;

  f32x4 acc[4][4];
  #pragma unroll
  for (int i = 0; i < 4; ++i)
    #pragma unroll
    for (int j = 0; j < 4; ++j) acc[i][j] = (f32x4)0.f;

  const int rl0 = wave * 16 + (lane >> 2);
  const int rl1 = rl0 + 64;
  const int kc = (lane & 3) * 8;
  char* AsB = (char*)As; char* BsB = (char*)Bs;

  for (int k0 = 0; k0 < K; k0 += 32) {
    GLD16(A + (size_t)(bm + rl0) * K + k0 + kc, AsB + wave * 1024);
    GLD16(A + (size_t)(bm + rl1) * K + k0 + kc, AsB + (wave + 4) * 1024);
    GLD16(Bt + (size_t)(bn + rl0) * K + k0 + kc, BsB + wave * 1024);
    GLD16(Bt + (size_t)(bn + rl1) * K + k0 + kc, BsB + (wave + 4) * 1024);
    __syncthreads();
    short8 af[4], bfr[4];
    #pragma unroll
    for (int mi = 0; mi < 4; ++mi)
      af[mi] = *(const short8*)(As + (wm * 64 + mi * 16 + r) * 32 + g * 8);
    #pragma unroll
    for (int nj = 0; nj < 4; ++nj)
      bfr[nj] = *(const short8*)(Bs + (wn * 64 + nj * 16 + r) * 32 + g * 8);
    #pragma unroll
    for (int mi = 0; mi < 4; ++mi)
      #pragma unroll
      for (int nj = 0; nj < 4; ++nj)
        acc[mi][nj] = __builtin_amdgcn_mfma_f32_16x16x32_bf16(af[mi], bfr[nj], acc[mi][nj], 0, 0, 0);
    __syncthreads();
  }

  if (isQ) {
    const int orow0 = wm * 64 + g * 4;
    const int ocol0 = bn + wn * 64 + r;
    #pragma unroll
    for (int mi = 0; mi < 4; ++mi)
      #pragma unroll
      for (int reg = 0; reg < 4; ++reg) {
        int mrow = bm + orow0 + mi * 16 + reg;
        size_t bas = (size_t)mrow * 1536 + ocol0;
        #pragma unroll
        for (int nj = 0; nj < 4; ++nj) qq[bas + nj * 16] = f2bf(acc[mi][nj][reg]);
      }
  } else {
    const int colbase = bn + wn * 64;
    const int b = bm >> 11;
    const int hh = colbase >> 8;
    if ((colbase & 255) < 128) {
      #pragma unroll
      for (int mi = 0; mi < 4; ++mi)
        #pragma unroll
        for (int reg = 0; reg < 4; ++reg) {
          int mrow = bm + wm * 64 + mi * 16 + g * 4 + reg;
          size_t bas = (size_t)mrow * 2048 + colbase + r;
          #pragma unroll
          for (int nj = 0; nj < 4; ++nj) kvb[bas + nj * 16] = f2bf(acc[mi][nj][reg]);
        }
    } else {
      const int tl0 = (bm & 2047) + wm * 64 + g * 4;
      const int d0 = (colbase & 255) - 128 + r;
      const size_t bhbase = (size_t)(b * 8 + hh) * 64;
      #pragma unroll
      for (int mi = 0; mi < 4; ++mi) {
        int t = tl0 + mi * 16;
        size_t tb = (bhbase + (t >> 5)) * 4096 + (t & 31);
        #pragma unroll
        for (int nj = 0; nj < 4; ++nj) {
          int d = d0 + nj * 16;
          us4 pk;
          #pragma unroll
          for (int reg = 0; reg < 4; ++reg) pk[reg] = f2bf(acc[mi][nj][reg]);
          *(us4*)(vtg + tb + (size_t)d * 32) = pk;
        }
      }
    }
  }
}

// ---------------- merged sh13 + moe13 GEMM (silu fused, 1088 blocks) ----------------
__global__ __launch_bounds__(256) void gemm_ffn13(
    const unsigned short* __restrict__ h2b, const unsigned short* __restrict__ Wsh13,
    unsigned short* __restrict__ t1m,
    const unsigned short* __restrict__ Wew13, unsigned short* __restrict__ ehm,
    const int* __restrict__ lists, const int* __restrict__ map, const int* __restrict__ sbase) {
  __shared__ __align__(16) unsigned short As[128 * 32];
  __shared__ __align__(16) unsigned short Bs[128 * 32];
  const int i = blockIdx.x;
  const bool isSh = i < 512;
  const int tid = threadIdx.x, lane = tid & 63, wave = tid >> 6;
  const int wm = wave >> 1, wn = wave & 1;
  const int r = lane & 15, g = lane >> 4;
  const int rl0 = wave * 16 + (lane >> 2), rl1 = rl0 + 64;
  const int kc = (lane & 3) * 8;

  int bn, e = 0, ib = 0, bm = 0;
  const unsigned short* Bt;
  int ar0, ar1;
  const unsigned short* A;
  if (isSh) {
    bn = (i & 15) * 128; bm = (i >> 4) * 128;
    Bt = Wsh13; A = h2b;
    ar0 = bm + rl0; ar1 = bm + rl1;
  } else {
    int j = i - 512;
    bn = (j & 7) * 128;
    int mb = map[j >> 3];
    if (mb < 0) return;
    e = mb >> 16; ib = mb & 0xFFFF;
    Bt = Wew13 + (size_t)e * 1024 * 1024; A = h2b;
    ar0 = lists[e * LSTR + ib * 128 + rl0]; if (ar0 < 0) ar0 = 0;
    ar1 = lists[e * LSTR + ib * 128 + rl1]; if (ar1 < 0) ar1 = 0;
  }

  f32x4 acc[4][4];
  #pragma unroll
  for (int a = 0; a < 4; ++a)
    #pragma unroll
    for (int bj = 0; bj < 4; ++bj) acc[a][bj] = (f32x4)0.f;
  char* AsB = (char*)As; char* BsB = (char*)Bs;

  for (int k0 = 0; k0 < 1024; k0 += 32) {
    GLD16(A + (size_t)ar0 * 1024 + k0 + kc, AsB + wave * 1024);
    GLD16(A + (size_t)ar1 * 1024 + k0 + kc, AsB + (wave + 4) * 1024);
    GLD16(Bt + (size_t)(bn + rl0) * 1024 + k0 + kc, BsB + wave * 1024);
    GLD16(Bt + (size_t)(bn + rl1) * 1024 + k0 + kc, BsB + (wave + 4) * 1024);
    __syncthreads();
    short8 af[4], bfr[4];
    #pragma unroll
    for (int mi = 0; mi < 4; ++mi)
      af[mi] = *(const short8*)(As + (wm * 64 + mi * 16 + r) * 32 + g * 8);
    #pragma unroll
    for (int nj = 0; nj < 4; ++nj)
      bfr[nj] = *(const short8*)(Bs + (wn * 64 + nj * 16 + r) * 32 + g * 8);
    #pragma unroll
    for (int mi = 0; mi < 4; ++mi)
      #pragma unroll
      for (int nj = 0; nj < 4; ++nj)
        acc[mi][nj] = __builtin_amdgcn_mfma_f32_16x16x32_bf16(af[mi], bfr[nj], acc[mi][nj], 0, 0, 0);
    __syncthreads();
  }

  if (isSh) {
    const int hc = ((bn + wn * 64) >> 1) + r;
    #pragma unroll
    for (int mi = 0; mi < 4; ++mi)
      #pragma unroll
      for (int reg = 0; reg < 4; ++reg) {
        int mrow = bm + wm * 64 + mi * 16 + g * 4 + reg;
        #pragma unroll
        for (int p = 0; p < 2; ++p) {
          float a = acc[mi][2 * p][reg], b3 = acc[mi][2 * p + 1][reg];
          t1m[(size_t)mrow * 1024 + hc + p * 16] = f2bf((a / (1.f + __expf(-a))) * b3);
        }
      }
  } else {
    const int sb = sbase[e] + ib * 128;
    const int hc = ((bn + wn * 64) >> 1) + r;
    #pragma unroll
    for (int mi = 0; mi < 4; ++mi)
      #pragma unroll
      for (int reg = 0; reg < 4; ++reg) {
        int srow = sb + wm * 64 + mi * 16 + g * 4 + reg;
        #pragma unroll
        for (int p = 0; p < 2; ++p) {
          float a = acc[mi][2 * p][reg], b3 = acc[mi][2 * p + 1][reg];
          ehm[(size_t)srow * 512 + hc + p * 16] = f2bf((a / (1.f + __expf(-a))) * b3);
        }
      }
  }
}

// ---------------- merged sh2 + moe2 GEMM (atomic accumulate, 832 blocks) ----------------
__global__ __launch_bounds__(256) void gemm_ffn2(
    const unsigned short* __restrict__ t1m, const unsigned short* __restrict__ Wsh2,
    const unsigned short* __restrict__ ehm, const unsigned short* __restrict__ Wew2,
    float* __restrict__ out,
    const int* __restrict__ lists, const int* __restrict__ map, const int* __restrict__ sbase,
    const float* __restrict__ cw) {
  __shared__ __align__(16) unsigned short As[128 * 32];
  __shared__ __align__(16) unsigned short Bs[128 * 32];
  const int i = blockIdx.x;
  const bool isSh = i < 256;
  const int tid = threadIdx.x, lane = tid & 63, wave = tid >> 6;
  const int wm = wave >> 1, wn = wave & 1;
  const int r = lane & 15, g = lane >> 4;
  const int rl0 = wave * 16 + (lane >> 2), rl1 = rl0 + 64;
  const int kc = (lane & 3) * 8;

  int bn, e = 0, ib = 0, bm = 0, K, sb = 0;
  const unsigned short* A;
  const unsigned short* Bt;
  if (isSh) {
    bn = (i & 7) * 128; bm = (i >> 3) * 128;
    A = t1m; Bt = Wsh2; K = 1024;
  } else {
    int j = i - 256;
    bn = (j & 7) * 128;
    int mb = map[j >> 3];
    if (mb < 0) return;
    e = mb >> 16; ib = mb & 0xFFFF;
    sb = sbase[e] + ib * 128;
    A = ehm; Bt = Wew2 + (size_t)e * 512 * 1024; K = 512;
    bm = sb;
  }

  f32x4 acc[4][4];
  #pragma unroll
  for (int a = 0; a < 4; ++a)
    #pragma unroll
    for (int bj = 0; bj < 4; ++bj) acc[a][bj] = (f32x4)0.f;
  char* AsB = (char*)As; char* BsB = (char*)Bs;

  for (int k0 = 0; k0 < K; k0 += 32) {
    GLD16(A + (size_t)(bm + rl0) * K + k0 + kc, AsB + wave * 1024);
    GLD16(A + (size_t)(bm + rl1) * K + k0 + kc, AsB + (wave + 4) * 1024);
    GLD16(Bt + (size_t)(bn + rl0) * K + k0 + kc, BsB + wave * 1024);
    GLD16(Bt + (size_t)(bn + rl1) * K + k0 + kc, BsB + (wave + 4) * 1024);
    __syncthreads();
    short8 af[4], bfr[4];
    #pragma unroll
    for (int mi = 0; mi < 4; ++mi)
      af[mi] = *(const short8*)(As + (wm * 64 + mi * 16 + r) * 32 + g * 8);
    #pragma unroll
    for (int nj = 0; nj < 4; ++nj)
      bfr[nj] = *(const short8*)(Bs + (wn * 64 + nj * 16 + r) * 32 + g * 8);
    #pragma unroll
    for (int mi = 0; mi < 4; ++mi)
      #pragma unroll
      for (int nj = 0; nj < 4; ++nj)
        acc[mi][nj] = __builtin_amdgcn_mfma_f32_16x16x32_bf16(af[mi], bfr[nj], acc[mi][nj], 0, 0, 0);
    __syncthreads();
  }

  const int ocol0 = bn + wn * 64 + r;
  if (isSh) {
    #pragma unroll
    for (int mi = 0; mi < 4; ++mi)
      #pragma unroll
      for (int reg = 0; reg < 4; ++reg) {
        int mrow = bm + wm * 64 + mi * 16 + g * 4 + reg;
        #pragma unroll
        for (int nj = 0; nj < 4; ++nj)
          atomicAdd(out + (size_t)mrow * 1024 + ocol0 + nj * 16, acc[mi][nj][reg]);
      }
  } else {
    #pragma unroll
    for (int mi = 0; mi < 4; ++mi)
      #pragma unroll
      for (int reg = 0; reg < 4; ++reg) {
        int orow = wm * 64 + mi * 16 + g * 4 + reg;
        int tok = lists[e * LSTR + ib * 128 + orow];
        if (tok >= 0) {
          float wt = cw[(size_t)tok * E_ + e];
          #pragma unroll
          for (int nj = 0; nj < 4; ++nj)
            atomicAdd(out + (size_t)tok * 1024 + ocol0 + nj * 16, acc[mi][nj][reg] * wt);
        }
      }
  }
}

// ---------------- MFMA flash attention, split-K x2, Q-in-regs, tile-contiguous V ----------------
#define AQ 64
#define AK 32
#define VP 40
__global__ __launch_bounds__(256) void attn_mfma(
    const unsigned short* __restrict__ q,   // [NTOK][H][192] (rope NOT applied)
    const unsigned short* __restrict__ kv,  // [NTOK][H][256] (nope half valid)
    const unsigned short* __restrict__ kr,  // [NTOK][64]
    const unsigned short* __restrict__ vt,  // [16][64][128][32] tile-contiguous
    const float* __restrict__ fcos, const float* __restrict__ fsin,
    unsigned short* __restrict__ po,        // [16*32*2][64*128] bf16 unnormalized O
    float* __restrict__ pml) {              // [16*32*2][64*2] (m, l)
  __shared__ __align__(16) unsigned short Ks[AK * 192];    // row-major pitch 384B, XOR-swizzled
  __shared__ __align__(16) unsigned short Vl[128 * VP];
  __shared__ __align__(16) unsigned short Ps[4 * 16 * VP];
  const int tid = threadIdx.x, lane = tid & 63, wave = tid >> 6;
  const int r = lane & 15, g = lane >> 4;
  const int bh = blockIdx.y, b = bh >> 3, h = bh & 7;
  const int qt = gridDim.x - 1 - blockIdx.x;   // LPT
  const int q0 = qt * AQ;
  const int half = blockIdx.z;
  const int hnt = qt + 1;                      // tiles per half
  const int kb = half * hnt, ke = kb + hnt;
  const size_t bT = (size_t)b * T_;
  const unsigned short* vbase = vt + (size_t)bh * 64 * 4096;
  char* KsB = (char*)Ks;

  // ---- Q into registers with fused RoPE ----
  short8 qf[6];
  const int qrow = q0 + wave * 16 + r;         // sequence position
  {
    const unsigned short* qb = q + ((bT + qrow) * H_ + h) * 192;
    #pragma unroll
    for (int kk = 0; kk < 6; ++kk) qf[kk] = *(const short8*)(qb + kk * 32 + g * 8);
    #pragma unroll
    for (int kk = 4; kk < 6; ++kk) {
      int i0 = (kk - 4) * 16 + g * 4;
      #pragma unroll
      for (int p = 0; p < 4; ++p) {
        float cc = fcos[qrow * 32 + i0 + p], sn = fsin[qrow * 32 + i0 + p];
        float x0 = bf2f((unsigned short)qf[kk][2 * p]), x1 = bf2f((unsigned short)qf[kk][2 * p + 1]);
        qf[kk][2 * p]     = (short)f2bf(x0 * cc - x1 * sn);
        qf[kk][2 * p + 1] = (short)f2bf(x0 * sn + x1 * cc);
      }
    }
  }

  float m_i[4], l_i[4];
  f32x4 o[8];
  #pragma unroll
  for (int i = 0; i < 4; ++i) { m_i[i] = -1e30f; l_i[i] = 0.f; }
  #pragma unroll
  for (int cb = 0; cb < 8; ++cb) o[cb] = (f32x4)0.f;

  const float scale2 = 0.07216878364870322f * 1.44269504088896f; // 1/sqrt(192)*log2e

  // prefetch tile kb (V tile-contiguous: 8KB dense block per key-tile)
  short8 kreg[3], vreg[2];
  int krow[3], kcol[3];
  #pragma unroll
  for (int it = 0; it < 3; ++it) {
    int c = tid + it * 256;
    krow[it] = c / 24; kcol[it] = c % 24;
    kreg[it] = (kcol[it] < 16)
      ? *(const short8*)(kv + ((bT + kb * AK + krow[it]) * H_ + h) * 256 + kcol[it] * 8)
      : *(const short8*)(kr + (bT + kb * AK + krow[it]) * 64 + (kcol[it] - 16) * 8);
  }
  #pragma unroll
  for (int it = 0; it < 2; ++it) {
    int x = tid + it * 256;
    vreg[it] = *(const short8*)(vbase + (size_t)kb * 4096 + x * 8);
  }

  for (int kt = kb; kt < ke; ++kt) {
    __builtin_amdgcn_s_barrier();
    __builtin_amdgcn_sched_barrier(0);
    #pragma unroll
    for (int it = 0; it < 3; ++it)
      *(short8*)(KsB + ((krow[it] * 384 + kcol[it] * 16) ^ ((krow[it] & 7) << 4))) = kreg[it];
    #pragma unroll
    for (int it = 0; it < 2; ++it) {
      int x = tid + it * 256;
      *(short8*)(Vl + (x >> 2) * VP + (x & 3) * 8) = vreg[it];
    }
    asm volatile("s_waitcnt lgkmcnt(0)" ::: "memory");
    __builtin_amdgcn_s_barrier();
    __builtin_amdgcn_sched_barrier(0);

    if (kt + 1 < ke) {
      int k1 = (kt + 1) * AK;
      #pragma unroll
      for (int it = 0; it < 3; ++it)
        kreg[it] = (kcol[it] < 16)
          ? *(const short8*)(kv + ((bT + k1 + krow[it]) * H_ + h) * 256 + kcol[it] * 8)
          : *(const short8*)(kr + (bT + k1 + krow[it]) * 64 + (kcol[it] - 16) * 8);
      #pragma unroll
      for (int it = 0; it < 2; ++it) {
        int x = tid + it * 256;
        vreg[it] = *(const short8*)(vbase + (size_t)(kt + 1) * 4096 + x * 8);
      }
    }

    const int k0 = kt * AK;
    f32x4 sf0 = (f32x4)0.f, sf1 = (f32x4)0.f;
    {
      int ksw = (r & 7) << 4;
      __builtin_amdgcn_s_setprio(1);
      #pragma unroll
      for (int kk = 0; kk < 6; ++kk) {
        short8 b0 = *(const short8*)(KsB + ((r * 384 + kk * 64 + g * 16) ^ ksw));
        short8 b1 = *(const short8*)(KsB + (((16 + r) * 384 + kk * 64 + g * 16) ^ ksw));
        sf0 = __builtin_amdgcn_mfma_f32_16x16x32_bf16(qf[kk], b0, sf0, 0, 0, 0);
        sf1 = __builtin_amdgcn_mfma_f32_16x16x32_bf16(qf[kk], b1, sf1, 0, 0, 0);
      }
      __builtin_amdgcn_s_setprio(0);
    }

    float fac[4];
    bool needs = false;
    const bool bnd = (k0 + AK > q0);
    #pragma unroll
    for (int reg = 0; reg < 4; ++reg) {
      float s0 = sf0[reg] * scale2;
      float s1 = sf1[reg] * scale2;
      if (bnd) {
        int qp = q0 + wave * 16 + g * 4 + reg;
        if (k0 + r > qp) s0 = -1e30f;
        if (k0 + 16 + r > qp) s1 = -1e30f;
      }
      float mt = dppmax16(fmaxf(s0, s1));
      float fc = 1.f, mn = m_i[reg];
      if (mt > mn + 8.f) {
        mn = mt; fc = exp2f(m_i[reg] - mn); m_i[reg] = mn; needs = true;
      }
      float e0 = exp2f(s0 - mn), e1 = exp2f(s1 - mn);
      float rs = dppsum16(e0 + e1);
      l_i[reg] = l_i[reg] * fc + rs;
      fac[reg] = fc;
      __hip_bfloat162 pk = __float22bfloat162_rn(float2{e0, e1});
      unsigned u = *(unsigned*)&pk;
      int prow = g * 4 + reg;
      Ps[wave * 16 * VP + prow * VP + r] = (unsigned short)u;
      Ps[wave * 16 * VP + prow * VP + 16 + r] = (unsigned short)(u >> 16);
    }
    if (__any(needs)) {
      #pragma unroll
      for (int cb = 0; cb < 8; ++cb)
        #pragma unroll
        for (int reg = 0; reg < 4; ++reg) o[cb][reg] *= fac[reg];
    }
    short8 pa = *(const short8*)(Ps + wave * 16 * VP + r * VP + g * 8);
    __builtin_amdgcn_s_setprio(1);
    #pragma unroll
    for (int cb = 0; cb < 8; ++cb) {
      short8 vb = *(const short8*)(Vl + (cb * 16 + r) * VP + g * 8);
      o[cb] = __builtin_amdgcn_mfma_f32_16x16x32_bf16(pa, vb, o[cb], 0, 0, 0);
    }
    __builtin_amdgcn_s_setprio(0);
  }

  const int slab = (bh * 32 + qt) * 2 + half;
  unsigned short* pob = po + (size_t)slab * 8192;
  float* pmlb = pml + (size_t)slab * 128;
  #pragma unroll
  for (int reg = 0; reg < 4; ++reg) {
    int row = wave * 16 + g * 4 + reg;
    if (r == 0) { pmlb[row * 2] = m_i[reg]; pmlb[row * 2 + 1] = l_i[reg]; }
    #pragma unroll
    for (int cb = 0; cb < 8; ++cb)
      pob[row * 128 + cb * 16 + r] = f2bf(o[cb][reg]);
  }
}

// ---------------- split-K combine: merge 2 halves -> y bf16 ----------------
__global__ __launch_bounds__(256) void attn_combine(
    const unsigned short* __restrict__ po, const float* __restrict__ pml,
    unsigned short* __restrict__ y) {
  const int qt = blockIdx.x, bh = blockIdx.y, b = bh >> 3, h = bh & 7;
  const int s0 = (bh * 32 + qt) * 2, s1 = s0 + 1;
  const int row = threadIdx.x >> 2;
  const int qp = threadIdx.x & 3;
  float m0 = pml[(size_t)s0 * 128 + row * 2], l0 = pml[(size_t)s0 * 128 + row * 2 + 1];
  float m1 = pml[(size_t)s1 * 128 + row * 2], l1 = pml[(size_t)s1 * 128 + row * 2 + 1];
  float m = fmaxf(m0, m1);
  float e0 = exp2f(m0 - m), e1 = exp2f(m1 - m);
  float inv = 1.f / (l0 * e0 + l1 * e1);
  e0 *= inv; e1 *= inv;
  const unsigned short* o0 = po + (size_t)s0 * 8192 + row * 128 + qp * 32;
  const unsigned short* o1 = po + (size_t)s1 * 8192 + row * 128 + qp * 32;
  unsigned short* yb = y + ((size_t)(b * T_ + qt * 64 + row)) * 1024 + h * 128 + qp * 32;
  #pragma unroll
  for (int v = 0; v < 4; ++v) {
    short8 a = *(const short8*)(o0 + v * 8);
    short8 c = *(const short8*)(o1 + v * 8);
    short8 w;
    #pragma unroll
    for (int j = 0; j < 8; ++j)
      w[j] = (short)f2bf(bf2f((unsigned short)a[j]) * e0 + bf2f((unsigned short)c[j]) * e1);
    *(short8*)(yb + v * 8) = w;
  }
}

// ---------------- fused rms2 + gate (logits, softmax, top2) ----------------
__global__ __launch_bounds__(256) void rms2_gate(
    const float* __restrict__ xo, const float* __restrict__ rw, const float* __restrict__ gw,
    unsigned short* __restrict__ h2b, float* __restrict__ cw) {
  int row = blockIdx.x, tid = threadIdx.x;
  int lane = tid & 63, wv = tid >> 6;
  const float* xr = xo + (size_t)row * D_;
  float v[4]; float ss = 0.f;
  #pragma unroll
  for (int j = 0; j < 4; ++j) { v[j] = xr[tid + j * 256]; ss += v[j] * v[j]; }
  for (int o = 1; o < 64; o <<= 1) ss += __shfl_xor(ss, o);
  __shared__ float red[4];
  if (lane == 0) red[wv] = ss;
  __syncthreads();
  float inv = 1.f / sqrtf((red[0] + red[1] + red[2] + red[3]) / D_ + 1e-6f);
  float a[E_] = {0, 0, 0, 0, 0, 0, 0, 0};
  #pragma unroll
  for (int j = 0; j < 4; ++j) {
    int i = tid + j * 256;
    float hv = v[j] * inv * rw[i];
    h2b[(size_t)row * D_ + i] = f2bf(hv);
    const float* wr = gw + (size_t)i * E_;
    #pragma unroll
    for (int e = 0; e < E_; ++e) a[e] += hv * wr[e];
  }
  #pragma unroll
  for (int e = 0; e < E_; ++e) {
    float t = a[e];
    for (int o = 1; o < 64; o <<= 1) t += __shfl_xor(t, o);
    a[e] = t;
  }
  __shared__ float ga[4][E_];
  if (lane == 0)
    #pragma unroll
    for (int e = 0; e < E_; ++e) ga[wv][e] = a[e];
  __syncthreads();
  if (tid == 0) {
    float lg[E_];
    #pragma unroll
    for (int e = 0; e < E_; ++e) lg[e] = ga[0][e] + ga[1][e] + ga[2][e] + ga[3][e];
    float mx = lg[0];
    #pragma unroll
    for (int e = 1; e < E_; ++e) mx = fmaxf(mx, lg[e]);
    float sum = 0.f; float p[E_];
    #pragma unroll
    for (int e = 0; e < E_; ++e) { p[e] = __expf(lg[e] - mx); sum += p[e]; }
    float is = 1.f / sum;
    int i1 = 0; float b1 = p[0];
    #pragma unroll
    for (int e = 1; e < E_; ++e) if (p[e] > b1) { b1 = p[e]; i1 = e; }
    int i2 = -1; float b2 = -1.f;
    #pragma unroll
    for (int e = 0; e < E_; ++e) if (e != i1 && p[e] > b2) { b2 = p[e]; i2 = e; }
    #pragma unroll
    for (int e = 0; e < E_; ++e)
      cw[(size_t)row * E_ + e] = (e == i1) ? b1 * is : (e == i2 ? b2 * is : 0.f);
  }
}

// ---------------- MoE token compaction (ballot-based, deterministic) ----------------
__global__ __launch_bounds__(256) void moe_build(const float* __restrict__ cw,
                                                 int* __restrict__ lists, int* __restrict__ counts) {
  int e = blockIdx.x, tid = threadIdx.x;
  int lane = tid & 63, wv = tid >> 6;
  __shared__ int wsum[4];
  __shared__ int base;
  if (tid == 0) base = 0;
  __syncthreads();
  for (int c0 = 0; c0 < NTOK; c0 += 256) {
    int tok = c0 + tid;
    bool f = cw[(size_t)tok * E_ + e] > 0.f;
    unsigned long long m = __ballot(f);
    int pos = __popcll(m & ((1ull << lane) - 1ull));
    if (lane == 0) wsum[wv] = __popcll(m);
    __syncthreads();
    int woff = base;
    #pragma unroll
    for (int w = 0; w < 4; ++w) if (w < wv) woff += wsum[w];
    if (f) lists[e * LSTR + woff + pos] = tok;
    __syncthreads();
    if (tid == 0) base += wsum[0] + wsum[1] + wsum[2] + wsum[3];
    __syncthreads();
  }
  int cnt = base;
  int padded = (cnt + 127) & ~127;
  for (int i2 = cnt + tid; i2 < padded; i2 += 256) lists[e * LSTR + i2] = -1;
  if (tid == 0) { counts[e] = cnt; counts[8 + e] = padded >> 7; }
}

__global__ void moe_finalize(const int* __restrict__ counts, int* __restrict__ map,
                             int* __restrict__ sbase) {
  if (threadIdx.x == 0 && blockIdx.x == 0) {
    int cum = 0;
    for (int e = 0; e < E_; ++e) {
      sbase[e] = cum * 128;
      int nb = counts[8 + e];
      for (int i = 0; i < nb; ++i) map[cum + i] = (e << 16) | i;
      cum += nb;
    }
    for (; cum < MAXMB; ++cum) map[cum] = -1;
  }
}

extern "C" void kernel_launch(void* const* d_in, const int* in_sizes, int n_in,
                              void* d_out, int out_size, void* d_ws, size_t ws_size,
                              hipStream_t stream) {
  const float* x        = (const float*)d_in[0];
  const float* fcos     = (const float*)d_in[1];
  const float* fsin     = (const float*)d_in[2];
  const float* rmsn1_w  = (const float*)d_in[3];
  const float* rmsn2_w  = (const float*)d_in[4];
  const float* latent_w = (const float*)d_in[5];
  const float* q_norm_w = (const float*)d_in[6];
  const float* q_up_w   = (const float*)d_in[7];
  const float* kv_norm_w= (const float*)d_in[8];
  const float* kv_up_w  = (const float*)d_in[9];
  const float* c_proj_w = (const float*)d_in[10];
  const float* gate_w   = (const float*)d_in[11];
  const float* sh_w1    = (const float*)d_in[12];
  const float* sh_w2    = (const float*)d_in[13];
  const float* sh_w3    = (const float*)d_in[14];
  const float* e_w1     = (const float*)d_in[15];
  const float* e_w2     = (const float*)d_in[16];
  const float* e_w3     = (const float*)d_in[17];
  float* out = (float*)d_out;

  char* base = (char*)d_ws;
  size_t off = 0;
  auto take = [&](size_t bytes) { char* p = base + off; off += (bytes + 255) & ~(size_t)255; return p; };
  unsigned short* Wlat  = (unsigned short*)take((size_t)768 * 1024 * 2);
  unsigned short* Wqup  = (unsigned short*)take((size_t)1536 * 384 * 2);
  unsigned short* Wkv   = (unsigned short*)take((size_t)2048 * 256 * 2);
  unsigned short* Wcp   = (unsigned short*)take((size_t)1024 * 1024 * 2);
  unsigned short* Wsh13 = (unsigned short*)take((size_t)2048 * 1024 * 2);
  unsigned short* Wsh2  = (unsigned short*)take((size_t)1024 * 1024 * 2);
  unsigned short* Wew13 = (unsigned short*)take((size_t)8 * 1024 * 1024 * 2);
  unsigned short* Wew2  = (unsigned short*)take((size_t)8 * 1024 * 512 * 2);
  float* cw             = (float*)take((size_t)NTOK * E_ * 4);
  int* lists            = (int*)take((size_t)E_ * LSTR * 4);
  int* counts           = (int*)take(64 * 4);
  int* map              = (int*)take(MAXMB * 4);
  int* sbase            = (int*)take(E_ * 4);
  unsigned short* Vtg   = (unsigned short*)take((size_t)16 * 64 * 4096 * 2);
  unsigned short* kr    = (unsigned short*)take((size_t)NTOK * 64 * 2);
  float* pml            = (float*)take((size_t)1024 * 128 * 4);

  size_t actStart = off;
  size_t aoff = actStart;
  auto takeA = [&](size_t bytes) { char* p = base + aoff; aoff += (bytes + 255) & ~(size_t)255; return p; };
  unsigned short* h_bf = (unsigned short*)takeA((size_t)NTOK * 1024 * 2);
  unsigned short* lat  = (unsigned short*)takeA((size_t)NTOK * 768 * 2);
  unsigned short* qn   = (unsigned short*)takeA((size_t)NTOK * 384 * 2);
  unsigned short* kvn  = (unsigned short*)takeA((size_t)NTOK * 256 * 2);
  unsigned short* qq   = (unsigned short*)takeA((size_t)NTOK * 1536 * 2);
  unsigned short* kvb  = (unsigned short*)takeA((size_t)NTOK * 2048 * 2);
  unsigned short* y    = (unsigned short*)takeA((size_t)NTOK * 1024 * 2);

  // split-K partial O (16 MB bf16) aliases h_bf/lat/qn (dead during attention)
  unsigned short* po   = (unsigned short*)(base + actStart);

  size_t coff = actStart;
  auto takeC = [&](size_t bytes) { char* p = base + coff; coff += (bytes + 255) & ~(size_t)255; return p; };
  unsigned short* h2b  = (unsigned short*)takeC((size_t)NTOK * 1024 * 2);
  unsigned short* t1m  = (unsigned short*)takeC((size_t)NTOK * 1024 * 2);
  unsigned short* ehm  = (unsigned short*)takeC((size_t)9216 * 512 * 2);

  dim3 blk(256);

  // --- weight conversion ---
  transpose_f32_bf16<<<dim3(22, 32, 1), blk, 0, stream>>>(latent_w, Wlat, 1024, 704, 0, 0);
  transpose_f32_bf16<<<dim3(48, 12, 1), blk, 0, stream>>>(q_up_w, Wqup, 384, 1536, 0, 0);
  transpose_f32_bf16<<<dim3(64, 8, 1), blk, 0, stream>>>(kv_up_w, Wkv, 256, 2048, 0, 0);
  transpose_f32_bf16<<<dim3(32, 32, 1), blk, 0, stream>>>(c_proj_w, Wcp, 1024, 1024, 0, 0);
  transpose_f32_bf16<<<dim3(32, 32, 1), blk, 0, stream>>>(sh_w2, Wsh2, 1024, 1024, 0, 0);
  transpose_pair<<<dim3(32, 32, 2), blk, 0, stream>>>(sh_w1, sh_w3, Wsh13, 1024, 1024, 0, 0);
  transpose_pair<<<dim3(16, 32, 16), blk, 0, stream>>>(e_w1, e_w3, Wew13, 1024, 512,
      (size_t)1024 * 512, (size_t)1024 * 1024);
  transpose_f32_bf16<<<dim3(32, 16, 8), blk, 0, stream>>>(e_w2, Wew2, 512, 1024,
      (size_t)512 * 1024, (size_t)1024 * 512);

  rms_to_bf16<float><<<NTOK, blk, 0, stream>>>(x, D_, 0, rmsn1_w, h_bf, D_, D_);
  gemm_bf16<0><<<dim3(6, 32), blk, 0, stream>>>(h_bf, Wlat, lat, NTOK, 768, 1024, nullptr);
  lat_post<<<NTOK, blk, 0, stream>>>(lat, q_norm_w, kv_norm_w, fcos, fsin, qn, kvn, kr);
  // merged q_up + kv_up (896 blocks)
  gemm_qkv<<<dim3(28, 32), blk, 0, stream>>>(qn, Wqup, kvn, Wkv, qq, kvb, Vtg);
  attn_mfma<<<dim3(T_ / AQ, B_ * H_, 2), blk, 0, stream>>>(qq, kvb, kr, Vtg, fcos, fsin, po, pml);
  attn_combine<<<dim3(T_ / AQ, B_ * H_), blk, 0, stream>>>(po, pml, y);
  gemm_bf16<1><<<dim3(8, 32), blk, 0, stream>>>(y, Wcp, out, NTOK, 1024, 1024, x);
  rms2_gate<<<NTOK, blk, 0, stream>>>(out, rmsn2_w, gate_w, h2b, cw);
  moe_build<<<E_, blk, 0, stream>>>(cw, lists, counts);
  moe_finalize<<<1, 64, 0, stream>>>(counts, map, sbase);
  // merged sh13 + moe13 (1088 blocks), then merged sh2 + moe2 (832 blocks, atomic)
  gemm_ffn13<<<dim3(1088), blk, 0, stream>>>(h2b, Wsh13, t1m, Wew13, ehm, lists, map, sbase);
  gemm_ffn2<<<dim3(832), blk, 0, stream>>>(t1m, Wsh2, ehm, Wew2, out, lists, map, sbase, cw);
}

// Round 12
// 388.819 us; speedup vs baseline: 1.0715x; 1.0231x over previous
//
#include <hip/hip_runtime.h>
#include <hip/hip_bf16.h>
#include <math.h>

#define D_ 1024
#define H_ 8
#define QLR_ 384
#define KVLR_ 256
#define NOPE_ 128
#define ROPE_ 64
#define VD_ 128
#define E_ 8
#define INTER_ 512
#define B_ 2
#define T_ 2048
#define QKD_ 192
#define NTOK (B_*T_)
#define LSTR 4608
#define MAXMB 72

typedef __attribute__((ext_vector_type(8))) short short8;
typedef __attribute__((ext_vector_type(4))) float f32x4;
typedef __attribute__((ext_vector_type(4))) unsigned short us4;

__device__ __forceinline__ unsigned short f2bf(float f) {
  union { float f; unsigned u; } v; v.f = f;
  return (unsigned short)((v.u + 0x7FFFu + ((v.u >> 16) & 1u)) >> 16);
}
__device__ __forceinline__ float bf2f(unsigned short h) {
  union { unsigned u; float f; } v; v.u = ((unsigned)h) << 16;
  return v.f;
}

#define GLD16(SRC, DST) __builtin_amdgcn_global_load_lds( \
    (__attribute__((address_space(1))) void*)(SRC), \
    (__attribute__((address_space(3))) void*)(DST), 16, 0, 0)

#define DPPF(v, ctrl) __int_as_float(__builtin_amdgcn_update_dpp(0, __float_as_int(v), ctrl, 0xF, 0xF, true))
__device__ __forceinline__ float dppmax16(float v) {
  v = fmaxf(v, DPPF(v, 0xB1));
  v = fmaxf(v, DPPF(v, 0x4E));
  v = fmaxf(v, DPPF(v, 0x124));
  v = fmaxf(v, DPPF(v, 0x128));
  return v;
}
__device__ __forceinline__ float dppsum16(float v) {
  v += DPPF(v, 0xB1);
  v += DPPF(v, 0x4E);
  v += DPPF(v, 0x124);
  v += DPPF(v, 0x128);
  return v;
}

// ---------------- transpose fp32 [R][C] -> bf16 [C][R] (batched) ----------------
__global__ __launch_bounds__(256) void transpose_f32_bf16(
    const float* __restrict__ in, unsigned short* __restrict__ out,
    int R, int C, size_t inBS, size_t outBS) {
  __shared__ float tile[32][33];
  const float* inp = in + (size_t)blockIdx.z * inBS;
  unsigned short* outp = out + (size_t)blockIdx.z * outBS;
  int c0 = blockIdx.x * 32, r0 = blockIdx.y * 32;
  int tx = threadIdx.x & 31, ty = threadIdx.x >> 5;
  #pragma unroll
  for (int i = 0; i < 4; ++i) {
    int rr = ty + i * 8;
    tile[rr][tx] = inp[(size_t)(r0 + rr) * C + c0 + tx];
  }
  __syncthreads();
  #pragma unroll
  for (int i = 0; i < 4; ++i) {
    int rr = ty + i * 8;
    outp[(size_t)(c0 + rr) * R + r0 + tx] = f2bf(tile[tx][rr]);
  }
}

// ---------------- interleaved pair transpose for w1/w3 fusion ----------------
__global__ __launch_bounds__(256) void transpose_pair(
    const float* __restrict__ in1, const float* __restrict__ in3,
    unsigned short* __restrict__ out, int K, int C1, size_t inBS, size_t outBS) {
  __shared__ float tile[32][33];
  int z = blockIdx.z; int bat = z >> 1; int f = (z & 1) * 16;
  const float* src = ((z & 1) ? in3 : in1) + (size_t)bat * inBS;
  unsigned short* o = out + (size_t)bat * outBS;
  int c0 = blockIdx.x * 32, r0 = blockIdx.y * 32;
  int tx = threadIdx.x & 31, ty = threadIdx.x >> 5;
  #pragma unroll
  for (int i = 0; i < 4; ++i) {
    int rr = ty + i * 8;
    tile[rr][tx] = src[(size_t)(r0 + rr) * C1 + c0 + tx];
  }
  __syncthreads();
  #pragma unroll
  for (int i = 0; i < 4; ++i) {
    int cc = ty + i * 8;
    int c = c0 + cc;
    int n = ((c >> 4) << 5) + (c & 15) + f;
    o[(size_t)n * K + r0 + tx] = f2bf(tile[tx][cc]);
  }
}

// ---------------- RMS norm -> bf16 ----------------
template<typename TI>
__global__ __launch_bounds__(256) void rms_to_bf16(
    const TI* __restrict__ src, int stride, int off, const float* __restrict__ w,
    unsigned short* __restrict__ out, int Dd, int outStride) {
  int row = blockIdx.x;
  const TI* xr = src + (size_t)row * stride + off;
  float ss = 0.f;
  for (int i = threadIdx.x; i < Dd; i += 256) {
    float v;
    if constexpr (sizeof(TI) == 2) v = bf2f((unsigned short)xr[i]); else v = (float)xr[i];
    ss += v * v;
  }
  for (int o = 1; o < 64; o <<= 1) ss += __shfl_xor(ss, o);
  __shared__ float red[4];
  if ((threadIdx.x & 63) == 0) red[threadIdx.x >> 6] = ss;
  __syncthreads();
  float tot = red[0] + red[1] + red[2] + red[3];
  float inv = 1.f / sqrtf(tot / Dd + 1e-6f);
  for (int i = threadIdx.x; i < Dd; i += 256) {
    float v;
    if constexpr (sizeof(TI) == 2) v = bf2f((unsigned short)xr[i]); else v = (float)xr[i];
    out[(size_t)row * outStride + i] = f2bf(v * inv * w[i]);
  }
}

// ---------------- fused: q_norm + kv_norm + rope_k from lat ----------------
__global__ __launch_bounds__(256) void lat_post(
    const unsigned short* __restrict__ lat, const float* __restrict__ qw,
    const float* __restrict__ kw, const float* __restrict__ fc, const float* __restrict__ fs,
    unsigned short* __restrict__ qn, unsigned short* __restrict__ kvn,
    unsigned short* __restrict__ kr) {
  int row = blockIdx.x, tid = threadIdx.x;
  int lane = tid & 63, wv = tid >> 6;
  const unsigned short* lr = lat + (size_t)row * 768;
  float s1 = 0.f, s2 = 0.f;
  for (int i = tid; i < QLR_; i += 256) { float v = bf2f(lr[i]); s1 += v * v; }
  { float v = bf2f(lr[QLR_ + tid]); s2 = v * v; }
  for (int o = 1; o < 64; o <<= 1) { s1 += __shfl_xor(s1, o); s2 += __shfl_xor(s2, o); }
  __shared__ float red[8];
  if (lane == 0) { red[wv] = s1; red[4 + wv] = s2; }
  __syncthreads();
  float inv1 = 1.f / sqrtf((red[0] + red[1] + red[2] + red[3]) / QLR_ + 1e-6f);
  float inv2 = 1.f / sqrtf((red[4] + red[5] + red[6] + red[7]) / KVLR_ + 1e-6f);
  for (int i = tid; i < QLR_; i += 256)
    qn[(size_t)row * QLR_ + i] = f2bf(bf2f(lr[i]) * inv1 * qw[i]);
  kvn[(size_t)row * KVLR_ + tid] = f2bf(bf2f(lr[QLR_ + tid]) * inv2 * kw[tid]);
  if (tid < 32) {
    int t = row & (T_ - 1);
    float c = fc[t * 32 + tid], s = fs[t * 32 + tid];
    float x0 = bf2f(lr[640 + 2 * tid]), x1 = bf2f(lr[640 + 2 * tid + 1]);
    kr[(size_t)row * ROPE_ + 2 * tid]     = f2bf(x0 * c - x1 * s);
    kr[(size_t)row * ROPE_ + 2 * tid + 1] = f2bf(x0 * s + x1 * c);
  }
}

// ---------------- bf16 MFMA GEMM: C[M,N] = A[M,K] @ Bt[N,K]^T ----------------
// MODE 0: bf16 out. 1: f32 out = acc + addv.
template<int MODE>
__global__ __launch_bounds__(256) void gemm_bf16(
    const unsigned short* __restrict__ A, const unsigned short* __restrict__ Bt,
    void* __restrict__ Cv, int M, int N, int K,
    const float* __restrict__ addv) {
  __shared__ __align__(16) unsigned short As[128 * 32];
  __shared__ __align__(16) unsigned short Bs[128 * 32];
  const int tid = threadIdx.x;
  const int lane = tid & 63, wave = tid >> 6;
  const int wm = wave >> 1, wn = wave & 1;
  const int bm = blockIdx.y * 128, bn = blockIdx.x * 128;
  const int r = lane & 15, g = lane >> 4;

  f32x4 acc[4][4];
  #pragma unroll
  for (int i = 0; i < 4; ++i)
    #pragma unroll
    for (int j = 0; j < 4; ++j) acc[i][j] = (f32x4)0.f;

  const int rl0 = wave * 16 + (lane >> 2);
  const int rl1 = rl0 + 64;
  const int kc = (lane & 3) * 8;
  char* AsB = (char*)As; char* BsB = (char*)Bs;

  for (int k0 = 0; k0 < K; k0 += 32) {
    GLD16(A + (size_t)(bm + rl0) * K + k0 + kc, AsB + wave * 1024);
    GLD16(A + (size_t)(bm + rl1) * K + k0 + kc, AsB + (wave + 4) * 1024);
    GLD16(Bt + (size_t)(bn + rl0) * K + k0 + kc, BsB + wave * 1024);
    GLD16(Bt + (size_t)(bn + rl1) * K + k0 + kc, BsB + (wave + 4) * 1024);
    __syncthreads();
    short8 af[4], bfr[4];
    #pragma unroll
    for (int mi = 0; mi < 4; ++mi)
      af[mi] = *(const short8*)(As + (wm * 64 + mi * 16 + r) * 32 + g * 8);
    #pragma unroll
    for (int nj = 0; nj < 4; ++nj)
      bfr[nj] = *(const short8*)(Bs + (wn * 64 + nj * 16 + r) * 32 + g * 8);
    #pragma unroll
    for (int mi = 0; mi < 4; ++mi)
      #pragma unroll
      for (int nj = 0; nj < 4; ++nj)
        acc[mi][nj] = __builtin_amdgcn_mfma_f32_16x16x32_bf16(af[mi], bfr[nj], acc[mi][nj], 0, 0, 0);
    __syncthreads();
  }

  const int orow0 = wm * 64 + g * 4;
  const int ocol0 = bn + wn * 64 + r;
  #pragma unroll
  for (int mi = 0; mi < 4; ++mi) {
    #pragma unroll
    for (int reg = 0; reg < 4; ++reg) {
      int mrow = bm + orow0 + mi * 16 + reg;
      size_t bas = (size_t)mrow * N + ocol0;
      if (MODE == 0) {
        unsigned short* C = (unsigned short*)Cv;
        #pragma unroll
        for (int nj = 0; nj < 4; ++nj) C[bas + nj * 16] = f2bf(acc[mi][nj][reg]);
      } else {
        float* C = (float*)Cv;
        #pragma unroll
        for (int nj = 0; nj < 4; ++nj) C[bas + nj * 16] = acc[mi][nj][reg] + addv[bas + nj * 16];
      }
    }
  }
}

// ---------------- merged q_up + kv_up GEMM (one dispatch, 896 blocks) ----------------
__global__ __launch_bounds__(256) void gemm_qkv(
    const unsigned short* __restrict__ qn, const unsigned short* __restrict__ Wqup,
    const unsigned short* __restrict__ kvn, const unsigned short* __restrict__ Wkv,
    unsigned short* __restrict__ qq, unsigned short* __restrict__ kvb,
    unsigned short* __restrict__ vtg) {
  __shared__ __align__(16) unsigned short As[128 * 32];
  __shared__ __align__(16) unsigned short Bs[128 * 32];
  const int tid = threadIdx.x;
  const int lane = tid & 63, wave = tid >> 6;
  const int wm = wave >> 1, wn = wave & 1;
  const bool isQ = blockIdx.x < 12;
  const int bx = isQ ? blockIdx.x : blockIdx.x - 12;
  const unsigned short* A  = isQ ? qn : kvn;
  const unsigned short* Bt = isQ ? Wqup : Wkv;
  const int K = isQ ? QLR_ : KVLR_;
  const int bm = blockIdx.y * 128, bn = bx * 128;
  const int r = lane & 15, g = lane >> 4;

  f32x4 acc[4][4];
  #pragma unroll
  for (int i = 0; i < 4; ++i)
    #pragma unroll
    for (int j = 0; j < 4; ++j) acc[i][j] = (f32x4)0.f;

  const int rl0 = wave * 16 + (lane >> 2);
  const int rl1 = rl0 + 64;
  const int kc = (lane & 3) * 8;
  char* AsB = (char*)As; char* BsB = (char*)Bs;

  for (int k0 = 0; k0 < K; k0 += 32) {
    GLD16(A + (size_t)(bm + rl0) * K + k0 + kc, AsB + wave * 1024);
    GLD16(A + (size_t)(bm + rl1) * K + k0 + kc, AsB + (wave + 4) * 1024);
    GLD16(Bt + (size_t)(bn + rl0) * K + k0 + kc, BsB + wave * 1024);
    GLD16(Bt + (size_t)(bn + rl1) * K + k0 + kc, BsB + (wave + 4) * 1024);
    __syncthreads();
    short8 af[4], bfr[4];
    #pragma unroll
    for (int mi = 0; mi < 4; ++mi)
      af[mi] = *(const short8*)(As + (wm * 64 + mi * 16 + r) * 32 + g * 8);
    #pragma unroll
    for (int nj = 0; nj < 4; ++nj)
      bfr[nj] = *(const short8*)(Bs + (wn * 64 + nj * 16 + r) * 32 + g * 8);
    #pragma unroll
    for (int mi = 0; mi < 4; ++mi)
      #pragma unroll
      for (int nj = 0; nj < 4; ++nj)
        acc[mi][nj] = __builtin_amdgcn_mfma_f32_16x16x32_bf16(af[mi], bfr[nj], acc[mi][nj], 0, 0, 0);
    __syncthreads();
  }

  if (isQ) {
    const int orow0 = wm * 64 + g * 4;
    const int ocol0 = bn + wn * 64 + r;
    #pragma unroll
    for (int mi = 0; mi < 4; ++mi)
      #pragma unroll
      for (int reg = 0; reg < 4; ++reg) {
        int mrow = bm + orow0 + mi * 16 + reg;
        size_t bas = (size_t)mrow * 1536 + ocol0;
        #pragma unroll
        for (int nj = 0; nj < 4; ++nj) qq[bas + nj * 16] = f2bf(acc[mi][nj][reg]);
      }
  } else {
    const int colbase = bn + wn * 64;
    const int b = bm >> 11;
    const int hh = colbase >> 8;
    if ((colbase & 255) < 128) {
      #pragma unroll
      for (int mi = 0; mi < 4; ++mi)
        #pragma unroll
        for (int reg = 0; reg < 4; ++reg) {
          int mrow = bm + wm * 64 + mi * 16 + g * 4 + reg;
          size_t bas = (size_t)mrow * 2048 + colbase + r;
          #pragma unroll
          for (int nj = 0; nj < 4; ++nj) kvb[bas + nj * 16] = f2bf(acc[mi][nj][reg]);
        }
    } else {
      const int tl0 = (bm & 2047) + wm * 64 + g * 4;
      const int d0 = (colbase & 255) - 128 + r;
      const size_t bhbase = (size_t)(b * 8 + hh) * 64;
      #pragma unroll
      for (int mi = 0; mi < 4; ++mi) {
        int t = tl0 + mi * 16;
        size_t tb = (bhbase + (t >> 5)) * 4096 + (t & 31);
        #pragma unroll
        for (int nj = 0; nj < 4; ++nj) {
          int d = d0 + nj * 16;
          us4 pk;
          #pragma unroll
          for (int reg = 0; reg < 4; ++reg) pk[reg] = f2bf(acc[mi][nj][reg]);
          *(us4*)(vtg + tb + (size_t)d * 32) = pk;
        }
      }
    }
  }
}

// ---------------- merged sh13 + moe13 GEMM (silu fused, 1088 blocks) ----------------
__global__ __launch_bounds__(256) void gemm_ffn13(
    const unsigned short* __restrict__ h2b, const unsigned short* __restrict__ Wsh13,
    unsigned short* __restrict__ t1m,
    const unsigned short* __restrict__ Wew13, unsigned short* __restrict__ ehm,
    const int* __restrict__ lists, const int* __restrict__ map, const int* __restrict__ sbase) {
  __shared__ __align__(16) unsigned short As[128 * 32];
  __shared__ __align__(16) unsigned short Bs[128 * 32];
  const int i = blockIdx.x;
  const bool isSh = i < 512;
  const int tid = threadIdx.x, lane = tid & 63, wave = tid >> 6;
  const int wm = wave >> 1, wn = wave & 1;
  const int r = lane & 15, g = lane >> 4;
  const int rl0 = wave * 16 + (lane >> 2), rl1 = rl0 + 64;
  const int kc = (lane & 3) * 8;

  int bn, e = 0, ib = 0, bm = 0;
  const unsigned short* Bt;
  int ar0, ar1;
  const unsigned short* A;
  if (isSh) {
    bn = (i & 15) * 128; bm = (i >> 4) * 128;
    Bt = Wsh13; A = h2b;
    ar0 = bm + rl0; ar1 = bm + rl1;
  } else {
    int j = i - 512;
    bn = (j & 7) * 128;
    int mb = map[j >> 3];
    if (mb < 0) return;
    e = mb >> 16; ib = mb & 0xFFFF;
    Bt = Wew13 + (size_t)e * 1024 * 1024; A = h2b;
    ar0 = lists[e * LSTR + ib * 128 + rl0]; if (ar0 < 0) ar0 = 0;
    ar1 = lists[e * LSTR + ib * 128 + rl1]; if (ar1 < 0) ar1 = 0;
  }

  f32x4 acc[4][4];
  #pragma unroll
  for (int a = 0; a < 4; ++a)
    #pragma unroll
    for (int bj = 0; bj < 4; ++bj) acc[a][bj] = (f32x4)0.f;
  char* AsB = (char*)As; char* BsB = (char*)Bs;

  for (int k0 = 0; k0 < 1024; k0 += 32) {
    GLD16(A + (size_t)ar0 * 1024 + k0 + kc, AsB + wave * 1024);
    GLD16(A + (size_t)ar1 * 1024 + k0 + kc, AsB + (wave + 4) * 1024);
    GLD16(Bt + (size_t)(bn + rl0) * 1024 + k0 + kc, BsB + wave * 1024);
    GLD16(Bt + (size_t)(bn + rl1) * 1024 + k0 + kc, BsB + (wave + 4) * 1024);
    __syncthreads();
    short8 af[4], bfr[4];
    #pragma unroll
    for (int mi = 0; mi < 4; ++mi)
      af[mi] = *(const short8*)(As + (wm * 64 + mi * 16 + r) * 32 + g * 8);
    #pragma unroll
    for (int nj = 0; nj < 4; ++nj)
      bfr[nj] = *(const short8*)(Bs + (wn * 64 + nj * 16 + r) * 32 + g * 8);
    #pragma unroll
    for (int mi = 0; mi < 4; ++mi)
      #pragma unroll
      for (int nj = 0; nj < 4; ++nj)
        acc[mi][nj] = __builtin_amdgcn_mfma_f32_16x16x32_bf16(af[mi], bfr[nj], acc[mi][nj], 0, 0, 0);
    __syncthreads();
  }

  if (isSh) {
    const int hc = ((bn + wn * 64) >> 1) + r;
    #pragma unroll
    for (int mi = 0; mi < 4; ++mi)
      #pragma unroll
      for (int reg = 0; reg < 4; ++reg) {
        int mrow = bm + wm * 64 + mi * 16 + g * 4 + reg;
        #pragma unroll
        for (int p = 0; p < 2; ++p) {
          float a = acc[mi][2 * p][reg], b3 = acc[mi][2 * p + 1][reg];
          t1m[(size_t)mrow * 1024 + hc + p * 16] = f2bf((a / (1.f + __expf(-a))) * b3);
        }
      }
  } else {
    const int sb = sbase[e] + ib * 128;
    const int hc = ((bn + wn * 64) >> 1) + r;
    #pragma unroll
    for (int mi = 0; mi < 4; ++mi)
      #pragma unroll
      for (int reg = 0; reg < 4; ++reg) {
        int srow = sb + wm * 64 + mi * 16 + g * 4 + reg;
        #pragma unroll
        for (int p = 0; p < 2; ++p) {
          float a = acc[mi][2 * p][reg], b3 = acc[mi][2 * p + 1][reg];
          ehm[(size_t)srow * 512 + hc + p * 16] = f2bf((a / (1.f + __expf(-a))) * b3);
        }
      }
  }
}

// ---------------- merged sh2 + moe2 GEMM (atomic accumulate, 832 blocks) ----------------
__global__ __launch_bounds__(256) void gemm_ffn2(
    const unsigned short* __restrict__ t1m, const unsigned short* __restrict__ Wsh2,
    const unsigned short* __restrict__ ehm, const unsigned short* __restrict__ Wew2,
    float* __restrict__ out,
    const int* __restrict__ lists, const int* __restrict__ map, const int* __restrict__ sbase,
    const float* __restrict__ cw) {
  __shared__ __align__(16) unsigned short As[128 * 32];
  __shared__ __align__(16) unsigned short Bs[128 * 32];
  const int i = blockIdx.x;
  const bool isSh = i < 256;
  const int tid = threadIdx.x, lane = tid & 63, wave = tid >> 6;
  const int wm = wave >> 1, wn = wave & 1;
  const int r = lane & 15, g = lane >> 4;
  const int rl0 = wave * 16 + (lane >> 2), rl1 = rl0 + 64;
  const int kc = (lane & 3) * 8;

  int bn, e = 0, ib = 0, bm = 0, K;
  const unsigned short* A;
  const unsigned short* Bt;
  if (isSh) {
    bn = (i & 7) * 128; bm = (i >> 3) * 128;
    A = t1m; Bt = Wsh2; K = 1024;
  } else {
    int j = i - 256;
    bn = (j & 7) * 128;
    int mb = map[j >> 3];
    if (mb < 0) return;
    e = mb >> 16; ib = mb & 0xFFFF;
    bm = sbase[e] + ib * 128;
    A = ehm; Bt = Wew2 + (size_t)e * 512 * 1024; K = 512;
  }

  f32x4 acc[4][4];
  #pragma unroll
  for (int a = 0; a < 4; ++a)
    #pragma unroll
    for (int bj = 0; bj < 4; ++bj) acc[a][bj] = (f32x4)0.f;
  char* AsB = (char*)As; char* BsB = (char*)Bs;

  for (int k0 = 0; k0 < K; k0 += 32) {
    GLD16(A + (size_t)(bm + rl0) * K + k0 + kc, AsB + wave * 1024);
    GLD16(A + (size_t)(bm + rl1) * K + k0 + kc, AsB + (wave + 4) * 1024);
    GLD16(Bt + (size_t)(bn + rl0) * K + k0 + kc, BsB + wave * 1024);
    GLD16(Bt + (size_t)(bn + rl1) * K + k0 + kc, BsB + (wave + 4) * 1024);
    __syncthreads();
    short8 af[4], bfr[4];
    #pragma unroll
    for (int mi = 0; mi < 4; ++mi)
      af[mi] = *(const short8*)(As + (wm * 64 + mi * 16 + r) * 32 + g * 8);
    #pragma unroll
    for (int nj = 0; nj < 4; ++nj)
      bfr[nj] = *(const short8*)(Bs + (wn * 64 + nj * 16 + r) * 32 + g * 8);
    #pragma unroll
    for (int mi = 0; mi < 4; ++mi)
      #pragma unroll
      for (int nj = 0; nj < 4; ++nj)
        acc[mi][nj] = __builtin_amdgcn_mfma_f32_16x16x32_bf16(af[mi], bfr[nj], acc[mi][nj], 0, 0, 0);
    __syncthreads();
  }

  const int ocol0 = bn + wn * 64 + r;
  if (isSh) {
    #pragma unroll
    for (int mi = 0; mi < 4; ++mi)
      #pragma unroll
      for (int reg = 0; reg < 4; ++reg) {
        int mrow = bm + wm * 64 + mi * 16 + g * 4 + reg;
        #pragma unroll
        for (int nj = 0; nj < 4; ++nj)
          atomicAdd(out + (size_t)mrow * 1024 + ocol0 + nj * 16, acc[mi][nj][reg]);
      }
  } else {
    #pragma unroll
    for (int mi = 0; mi < 4; ++mi)
      #pragma unroll
      for (int reg = 0; reg < 4; ++reg) {
        int orow = wm * 64 + mi * 16 + g * 4 + reg;
        int tok = lists[e * LSTR + ib * 128 + orow];
        if (tok >= 0) {
          float wt = cw[(size_t)tok * E_ + e];
          #pragma unroll
          for (int nj = 0; nj < 4; ++nj)
            atomicAdd(out + (size_t)tok * 1024 + ocol0 + nj * 16, acc[mi][nj][reg] * wt);
        }
      }
  }
}

// ---------------- MFMA flash attention: AQ=128, 8 waves, split-K x2 ----------------
#define AQ 128
#define AK 32
#define VP 40
__global__ __launch_bounds__(512) void attn_mfma(
    const unsigned short* __restrict__ q,   // [NTOK][H][192] (rope NOT applied)
    const unsigned short* __restrict__ kv,  // [NTOK][H][256] (nope half valid)
    const unsigned short* __restrict__ kr,  // [NTOK][64]
    const unsigned short* __restrict__ vt,  // [16][64][128][32] tile-contiguous
    const float* __restrict__ fcos, const float* __restrict__ fsin,
    unsigned short* __restrict__ po,        // [16*16*2][128*128] bf16 unnormalized O
    float* __restrict__ pml) {              // [16*16*2][128*2] (m, l)
  __shared__ __align__(16) unsigned short Ks[AK * 192];    // row-major pitch 384B, XOR-swizzled
  __shared__ __align__(16) unsigned short Vl[128 * VP];
  __shared__ __align__(16) unsigned short Ps[8 * 16 * VP];
  const int tid = threadIdx.x, lane = tid & 63, wave = tid >> 6; // wave 0..7
  const int r = lane & 15, g = lane >> 4;
  const int bh = blockIdx.y, b = bh >> 3, h = bh & 7;
  const int qt = gridDim.x - 1 - blockIdx.x;   // LPT
  const int q0 = qt * AQ;
  const int half = blockIdx.z;
  const int hnt = 2 * (qt + 1);                // tiles per half
  const int kb = half * hnt, ke = kb + hnt;
  const size_t bT = (size_t)b * T_;
  const unsigned short* vbase = vt + (size_t)bh * 64 * 4096;
  char* KsB = (char*)Ks;

  // ---- Q into registers with fused RoPE ----
  short8 qf[6];
  const int qrow = q0 + wave * 16 + r;         // sequence position
  {
    const unsigned short* qb = q + ((bT + qrow) * H_ + h) * 192;
    #pragma unroll
    for (int kk = 0; kk < 6; ++kk) qf[kk] = *(const short8*)(qb + kk * 32 + g * 8);
    #pragma unroll
    for (int kk = 4; kk < 6; ++kk) {
      int i0 = (kk - 4) * 16 + g * 4;
      #pragma unroll
      for (int p = 0; p < 4; ++p) {
        float cc = fcos[qrow * 32 + i0 + p], sn = fsin[qrow * 32 + i0 + p];
        float x0 = bf2f((unsigned short)qf[kk][2 * p]), x1 = bf2f((unsigned short)qf[kk][2 * p + 1]);
        qf[kk][2 * p]     = (short)f2bf(x0 * cc - x1 * sn);
        qf[kk][2 * p + 1] = (short)f2bf(x0 * sn + x1 * cc);
      }
    }
  }

  float m_i[4], l_i[4];
  f32x4 o[8];
  #pragma unroll
  for (int i = 0; i < 4; ++i) { m_i[i] = -1e30f; l_i[i] = 0.f; }
  #pragma unroll
  for (int cb = 0; cb < 8; ++cb) o[cb] = (f32x4)0.f;

  const float scale2 = 0.07216878364870322f * 1.44269504088896f; // 1/sqrt(192)*log2e

  // K staging: 768 chunks (512 + 256), V: 512 chunks (one per thread)
  const int kr0r = tid / 24, kr0c = tid % 24;
  const bool k1v = tid < 256;
  const int kr1r = (tid + 512) / 24, kr1c = (tid + 512) % 24;

  short8 kreg0, kreg1, vreg;
  {
    int kk0 = kb * AK;
    kreg0 = (kr0c < 16)
      ? *(const short8*)(kv + ((bT + kk0 + kr0r) * H_ + h) * 256 + kr0c * 8)
      : *(const short8*)(kr + (bT + kk0 + kr0r) * 64 + (kr0c - 16) * 8);
    if (k1v)
      kreg1 = (kr1c < 16)
        ? *(const short8*)(kv + ((bT + kk0 + kr1r) * H_ + h) * 256 + kr1c * 8)
        : *(const short8*)(kr + (bT + kk0 + kr1r) * 64 + (kr1c - 16) * 8);
    vreg = *(const short8*)(vbase + (size_t)kb * 4096 + tid * 8);
  }

  for (int kt = kb; kt < ke; ++kt) {
    __builtin_amdgcn_s_barrier();
    __builtin_amdgcn_sched_barrier(0);
    *(short8*)(KsB + ((kr0r * 384 + kr0c * 16) ^ ((kr0r & 7) << 4))) = kreg0;
    if (k1v)
      *(short8*)(KsB + ((kr1r * 384 + kr1c * 16) ^ ((kr1r & 7) << 4))) = kreg1;
    *(short8*)(Vl + (tid >> 2) * VP + (tid & 3) * 8) = vreg;
    asm volatile("s_waitcnt lgkmcnt(0)" ::: "memory");
    __builtin_amdgcn_s_barrier();
    __builtin_amdgcn_sched_barrier(0);

    if (kt + 1 < ke) {
      int k1 = (kt + 1) * AK;
      kreg0 = (kr0c < 16)
        ? *(const short8*)(kv + ((bT + k1 + kr0r) * H_ + h) * 256 + kr0c * 8)
        : *(const short8*)(kr + (bT + k1 + kr0r) * 64 + (kr0c - 16) * 8);
      if (k1v)
        kreg1 = (kr1c < 16)
          ? *(const short8*)(kv + ((bT + k1 + kr1r) * H_ + h) * 256 + kr1c * 8)
          : *(const short8*)(kr + (bT + k1 + kr1r) * 64 + (kr1c - 16) * 8);
      vreg = *(const short8*)(vbase + (size_t)(kt + 1) * 4096 + tid * 8);
    }

    const int k0 = kt * AK;
    f32x4 sf0 = (f32x4)0.f, sf1 = (f32x4)0.f;
    {
      int ksw = (r & 7) << 4;
      __builtin_amdgcn_s_setprio(1);
      #pragma unroll
      for (int kk = 0; kk < 6; ++kk) {
        short8 b0 = *(const short8*)(KsB + ((r * 384 + kk * 64 + g * 16) ^ ksw));
        short8 b1 = *(const short8*)(KsB + (((16 + r) * 384 + kk * 64 + g * 16) ^ ksw));
        sf0 = __builtin_amdgcn_mfma_f32_16x16x32_bf16(qf[kk], b0, sf0, 0, 0, 0);
        sf1 = __builtin_amdgcn_mfma_f32_16x16x32_bf16(qf[kk], b1, sf1, 0, 0, 0);
      }
      __builtin_amdgcn_s_setprio(0);
    }

    float fac[4];
    bool needs = false;
    const bool bnd = (k0 + AK > q0);   // masks needed only near the diagonal
    #pragma unroll
    for (int reg = 0; reg < 4; ++reg) {
      float s0 = sf0[reg] * scale2;
      float s1 = sf1[reg] * scale2;
      if (bnd) {
        int qp = q0 + wave * 16 + g * 4 + reg;
        if (k0 + r > qp) s0 = -1e30f;
        if (k0 + 16 + r > qp) s1 = -1e30f;
      }
      float mt = dppmax16(fmaxf(s0, s1));
      float fc = 1.f, mn = m_i[reg];
      if (mt > mn + 8.f) {
        mn = mt; fc = exp2f(m_i[reg] - mn); m_i[reg] = mn; needs = true;
      }
      float e0 = exp2f(s0 - mn), e1 = exp2f(s1 - mn);
      float rs = dppsum16(e0 + e1);
      l_i[reg] = l_i[reg] * fc + rs;
      fac[reg] = fc;
      __hip_bfloat162 pk = __float22bfloat162_rn(float2{e0, e1});
      unsigned u = *(unsigned*)&pk;
      int prow = g * 4 + reg;
      Ps[wave * 16 * VP + prow * VP + r] = (unsigned short)u;
      Ps[wave * 16 * VP + prow * VP + 16 + r] = (unsigned short)(u >> 16);
    }
    if (__any(needs)) {
      #pragma unroll
      for (int cb = 0; cb < 8; ++cb)
        #pragma unroll
        for (int reg = 0; reg < 4; ++reg) o[cb][reg] *= fac[reg];
    }
    short8 pa = *(const short8*)(Ps + wave * 16 * VP + r * VP + g * 8);
    __builtin_amdgcn_s_setprio(1);
    #pragma unroll
    for (int cb = 0; cb < 8; ++cb) {
      short8 vb = *(const short8*)(Vl + (cb * 16 + r) * VP + g * 8);
      o[cb] = __builtin_amdgcn_mfma_f32_16x16x32_bf16(pa, vb, o[cb], 0, 0, 0);
    }
    __builtin_amdgcn_s_setprio(0);
  }

  // ---- write partial (unnormalized O bf16, m/l fp32) ----
  const int slab = (bh * 16 + qt) * 2 + half;
  unsigned short* pob = po + (size_t)slab * 16384;
  float* pmlb = pml + (size_t)slab * 256;
  #pragma unroll
  for (int reg = 0; reg < 4; ++reg) {
    int row = wave * 16 + g * 4 + reg;
    if (r == 0) { pmlb[row * 2] = m_i[reg]; pmlb[row * 2 + 1] = l_i[reg]; }
    #pragma unroll
    for (int cb = 0; cb < 8; ++cb)
      pob[row * 128 + cb * 16 + r] = f2bf(o[cb][reg]);
  }
}

// ---------------- split-K combine: merge 2 halves -> y bf16 ----------------
__global__ __launch_bounds__(512) void attn_combine(
    const unsigned short* __restrict__ po, const float* __restrict__ pml,
    unsigned short* __restrict__ y) {
  const int qt = blockIdx.x, bh = blockIdx.y, b = bh >> 3, h = bh & 7;
  const int s0 = (bh * 16 + qt) * 2, s1 = s0 + 1;
  const int row = threadIdx.x >> 2;
  const int qp = threadIdx.x & 3;
  float m0 = pml[(size_t)s0 * 256 + row * 2], l0 = pml[(size_t)s0 * 256 + row * 2 + 1];
  float m1 = pml[(size_t)s1 * 256 + row * 2], l1 = pml[(size_t)s1 * 256 + row * 2 + 1];
  float m = fmaxf(m0, m1);
  float e0 = exp2f(m0 - m), e1 = exp2f(m1 - m);
  float inv = 1.f / (l0 * e0 + l1 * e1);
  e0 *= inv; e1 *= inv;
  const unsigned short* o0 = po + (size_t)s0 * 16384 + row * 128 + qp * 32;
  const unsigned short* o1 = po + (size_t)s1 * 16384 + row * 128 + qp * 32;
  unsigned short* yb = y + ((size_t)(b * T_ + qt * 128 + row)) * 1024 + h * 128 + qp * 32;
  #pragma unroll
  for (int v = 0; v < 4; ++v) {
    short8 a = *(const short8*)(o0 + v * 8);
    short8 c = *(const short8*)(o1 + v * 8);
    short8 w;
    #pragma unroll
    for (int j = 0; j < 8; ++j)
      w[j] = (short)f2bf(bf2f((unsigned short)a[j]) * e0 + bf2f((unsigned short)c[j]) * e1);
    *(short8*)(yb + v * 8) = w;
  }
}

// ---------------- fused rms2 + gate (logits, softmax, top2) ----------------
__global__ __launch_bounds__(256) void rms2_gate(
    const float* __restrict__ xo, const float* __restrict__ rw, const float* __restrict__ gw,
    unsigned short* __restrict__ h2b, float* __restrict__ cw) {
  int row = blockIdx.x, tid = threadIdx.x;
  int lane = tid & 63, wv = tid >> 6;
  const float* xr = xo + (size_t)row * D_;
  float v[4]; float ss = 0.f;
  #pragma unroll
  for (int j = 0; j < 4; ++j) { v[j] = xr[tid + j * 256]; ss += v[j] * v[j]; }
  for (int o = 1; o < 64; o <<= 1) ss += __shfl_xor(ss, o);
  __shared__ float red[4];
  if (lane == 0) red[wv] = ss;
  __syncthreads();
  float inv = 1.f / sqrtf((red[0] + red[1] + red[2] + red[3]) / D_ + 1e-6f);
  float a[E_] = {0, 0, 0, 0, 0, 0, 0, 0};
  #pragma unroll
  for (int j = 0; j < 4; ++j) {
    int i = tid + j * 256;
    float hv = v[j] * inv * rw[i];
    h2b[(size_t)row * D_ + i] = f2bf(hv);
    const float* wr = gw + (size_t)i * E_;
    #pragma unroll
    for (int e = 0; e < E_; ++e) a[e] += hv * wr[e];
  }
  #pragma unroll
  for (int e = 0; e < E_; ++e) {
    float t = a[e];
    for (int o = 1; o < 64; o <<= 1) t += __shfl_xor(t, o);
    a[e] = t;
  }
  __shared__ float ga[4][E_];
  if (lane == 0)
    #pragma unroll
    for (int e = 0; e < E_; ++e) ga[wv][e] = a[e];
  __syncthreads();
  if (tid == 0) {
    float lg[E_];
    #pragma unroll
    for (int e = 0; e < E_; ++e) lg[e] = ga[0][e] + ga[1][e] + ga[2][e] + ga[3][e];
    float mx = lg[0];
    #pragma unroll
    for (int e = 1; e < E_; ++e) mx = fmaxf(mx, lg[e]);
    float sum = 0.f; float p[E_];
    #pragma unroll
    for (int e = 0; e < E_; ++e) { p[e] = __expf(lg[e] - mx); sum += p[e]; }
    float is = 1.f / sum;
    int i1 = 0; float b1 = p[0];
    #pragma unroll
    for (int e = 1; e < E_; ++e) if (p[e] > b1) { b1 = p[e]; i1 = e; }
    int i2 = -1; float b2 = -1.f;
    #pragma unroll
    for (int e = 0; e < E_; ++e) if (e != i1 && p[e] > b2) { b2 = p[e]; i2 = e; }
    #pragma unroll
    for (int e = 0; e < E_; ++e)
      cw[(size_t)row * E_ + e] = (e == i1) ? b1 * is : (e == i2 ? b2 * is : 0.f);
  }
}

// ---------------- MoE token compaction (ballot-based, deterministic) ----------------
__global__ __launch_bounds__(256) void moe_build(const float* __restrict__ cw,
                                                 int* __restrict__ lists, int* __restrict__ counts) {
  int e = blockIdx.x, tid = threadIdx.x;
  int lane = tid & 63, wv = tid >> 6;
  __shared__ int wsum[4];
  __shared__ int base;
  if (tid == 0) base = 0;
  __syncthreads();
  for (int c0 = 0; c0 < NTOK; c0 += 256) {
    int tok = c0 + tid;
    bool f = cw[(size_t)tok * E_ + e] > 0.f;
    unsigned long long m = __ballot(f);
    int pos = __popcll(m & ((1ull << lane) - 1ull));
    if (lane == 0) wsum[wv] = __popcll(m);
    __syncthreads();
    int woff = base;
    #pragma unroll
    for (int w = 0; w < 4; ++w) if (w < wv) woff += wsum[w];
    if (f) lists[e * LSTR + woff + pos] = tok;
    __syncthreads();
    if (tid == 0) base += wsum[0] + wsum[1] + wsum[2] + wsum[3];
    __syncthreads();
  }
  int cnt = base;
  int padded = (cnt + 127) & ~127;
  for (int i2 = cnt + tid; i2 < padded; i2 += 256) lists[e * LSTR + i2] = -1;
  if (tid == 0) { counts[e] = cnt; counts[8 + e] = padded >> 7; }
}

__global__ void moe_finalize(const int* __restrict__ counts, int* __restrict__ map,
                             int* __restrict__ sbase) {
  if (threadIdx.x == 0 && blockIdx.x == 0) {
    int cum = 0;
    for (int e = 0; e < E_; ++e) {
      sbase[e] = cum * 128;
      int nb = counts[8 + e];
      for (int i = 0; i < nb; ++i) map[cum + i] = (e << 16) | i;
      cum += nb;
    }
    for (; cum < MAXMB; ++cum) map[cum] = -1;
  }
}

extern "C" void kernel_launch(void* const* d_in, const int* in_sizes, int n_in,
                              void* d_out, int out_size, void* d_ws, size_t ws_size,
                              hipStream_t stream) {
  const float* x        = (const float*)d_in[0];
  const float* fcos     = (const float*)d_in[1];
  const float* fsin     = (const float*)d_in[2];
  const float* rmsn1_w  = (const float*)d_in[3];
  const float* rmsn2_w  = (const float*)d_in[4];
  const float* latent_w = (const float*)d_in[5];
  const float* q_norm_w = (const float*)d_in[6];
  const float* q_up_w   = (const float*)d_in[7];
  const float* kv_norm_w= (const float*)d_in[8];
  const float* kv_up_w  = (const float*)d_in[9];
  const float* c_proj_w = (const float*)d_in[10];
  const float* gate_w   = (const float*)d_in[11];
  const float* sh_w1    = (const float*)d_in[12];
  const float* sh_w2    = (const float*)d_in[13];
  const float* sh_w3    = (const float*)d_in[14];
  const float* e_w1     = (const float*)d_in[15];
  const float* e_w2     = (const float*)d_in[16];
  const float* e_w3     = (const float*)d_in[17];
  float* out = (float*)d_out;

  char* base = (char*)d_ws;
  size_t off = 0;
  auto take = [&](size_t bytes) { char* p = base + off; off += (bytes + 255) & ~(size_t)255; return p; };
  unsigned short* Wlat  = (unsigned short*)take((size_t)768 * 1024 * 2);
  unsigned short* Wqup  = (unsigned short*)take((size_t)1536 * 384 * 2);
  unsigned short* Wkv   = (unsigned short*)take((size_t)2048 * 256 * 2);
  unsigned short* Wcp   = (unsigned short*)take((size_t)1024 * 1024 * 2);
  unsigned short* Wsh13 = (unsigned short*)take((size_t)2048 * 1024 * 2);
  unsigned short* Wsh2  = (unsigned short*)take((size_t)1024 * 1024 * 2);
  unsigned short* Wew13 = (unsigned short*)take((size_t)8 * 1024 * 1024 * 2);
  unsigned short* Wew2  = (unsigned short*)take((size_t)8 * 1024 * 512 * 2);
  float* cw             = (float*)take((size_t)NTOK * E_ * 4);
  int* lists            = (int*)take((size_t)E_ * LSTR * 4);
  int* counts           = (int*)take(64 * 4);
  int* map              = (int*)take(MAXMB * 4);
  int* sbase            = (int*)take(E_ * 4);
  unsigned short* Vtg   = (unsigned short*)take((size_t)16 * 64 * 4096 * 2);
  unsigned short* kr    = (unsigned short*)take((size_t)NTOK * 64 * 2);
  float* pml            = (float*)take((size_t)512 * 256 * 4);

  size_t actStart = off;
  size_t aoff = actStart;
  auto takeA = [&](size_t bytes) { char* p = base + aoff; aoff += (bytes + 255) & ~(size_t)255; return p; };
  unsigned short* h_bf = (unsigned short*)takeA((size_t)NTOK * 1024 * 2);
  unsigned short* lat  = (unsigned short*)takeA((size_t)NTOK * 768 * 2);
  unsigned short* qn   = (unsigned short*)takeA((size_t)NTOK * 384 * 2);
  unsigned short* kvn  = (unsigned short*)takeA((size_t)NTOK * 256 * 2);
  unsigned short* qq   = (unsigned short*)takeA((size_t)NTOK * 1536 * 2);
  unsigned short* kvb  = (unsigned short*)takeA((size_t)NTOK * 2048 * 2);
  unsigned short* y    = (unsigned short*)takeA((size_t)NTOK * 1024 * 2);

  // split-K partial O (16 MB bf16) aliases h_bf/lat/qn (dead during attention)
  unsigned short* po   = (unsigned short*)(base + actStart);

  size_t coff = actStart;
  auto takeC = [&](size_t bytes) { char* p = base + coff; coff += (bytes + 255) & ~(size_t)255; return p; };
  unsigned short* h2b  = (unsigned short*)takeC((size_t)NTOK * 1024 * 2);
  unsigned short* t1m  = (unsigned short*)takeC((size_t)NTOK * 1024 * 2);
  unsigned short* ehm  = (unsigned short*)takeC((size_t)9216 * 512 * 2);

  dim3 blk(256);

  // --- weight conversion ---
  transpose_f32_bf16<<<dim3(22, 32, 1), blk, 0, stream>>>(latent_w, Wlat, 1024, 704, 0, 0);
  transpose_f32_bf16<<<dim3(48, 12, 1), blk, 0, stream>>>(q_up_w, Wqup, 384, 1536, 0, 0);
  transpose_f32_bf16<<<dim3(64, 8, 1), blk, 0, stream>>>(kv_up_w, Wkv, 256, 2048, 0, 0);
  transpose_f32_bf16<<<dim3(32, 32, 1), blk, 0, stream>>>(c_proj_w, Wcp, 1024, 1024, 0, 0);
  transpose_f32_bf16<<<dim3(32, 32, 1), blk, 0, stream>>>(sh_w2, Wsh2, 1024, 1024, 0, 0);
  transpose_pair<<<dim3(32, 32, 2), blk, 0, stream>>>(sh_w1, sh_w3, Wsh13, 1024, 1024, 0, 0);
  transpose_pair<<<dim3(16, 32, 16), blk, 0, stream>>>(e_w1, e_w3, Wew13, 1024, 512,
      (size_t)1024 * 512, (size_t)1024 * 1024);
  transpose_f32_bf16<<<dim3(32, 16, 8), blk, 0, stream>>>(e_w2, Wew2, 512, 1024,
      (size_t)512 * 1024, (size_t)1024 * 512);

  rms_to_bf16<float><<<NTOK, blk, 0, stream>>>(x, D_, 0, rmsn1_w, h_bf, D_, D_);
  gemm_bf16<0><<<dim3(6, 32), blk, 0, stream>>>(h_bf, Wlat, lat, NTOK, 768, 1024, nullptr);
  lat_post<<<NTOK, blk, 0, stream>>>(lat, q_norm_w, kv_norm_w, fcos, fsin, qn, kvn, kr);
  // merged q_up + kv_up (896 blocks)
  gemm_qkv<<<dim3(28, 32), blk, 0, stream>>>(qn, Wqup, kvn, Wkv, qq, kvb, Vtg);
  attn_mfma<<<dim3(T_ / AQ, B_ * H_, 2), dim3(512), 0, stream>>>(qq, kvb, kr, Vtg, fcos, fsin, po, pml);
  attn_combine<<<dim3(T_ / AQ, B_ * H_), dim3(512), 0, stream>>>(po, pml, y);
  gemm_bf16<1><<<dim3(8, 32), blk, 0, stream>>>(y, Wcp, out, NTOK, 1024, 1024, x);
  rms2_gate<<<NTOK, blk, 0, stream>>>(out, rmsn2_w, gate_w, h2b, cw);
  moe_build<<<E_, blk, 0, stream>>>(cw, lists, counts);
  moe_finalize<<<1, 64, 0, stream>>>(counts, map, sbase);
  // merged sh13 + moe13 (1088 blocks), then merged sh2 + moe2 (832 blocks, atomic)
  gemm_ffn13<<<dim3(1088), blk, 0, stream>>>(h2b, Wsh13, t1m, Wew13, ehm, lists, map, sbase);
  gemm_ffn2<<<dim3(832), blk, 0, stream>>>(t1m, Wsh2, ehm, Wew2, out, lists, map, sbase, cw);
}

// Round 13
// 359.737 us; speedup vs baseline: 1.1581x; 1.0808x over previous
//
#include <hip/hip_runtime.h>
#include <hip/hip_bf16.h>
#include <math.h>

#define D_ 1024
#define H_ 8
#define QLR_ 384
#define KVLR_ 256
#define NOPE_ 128
#define ROPE_ 64
#define VD_ 128
#define E_ 8
#define INTER_ 512
#define B_ 2
#define T_ 2048
#define QKD_ 192
#define NTOK (B_*T_)
#define LSTR 4608
#define MAXMB 72

typedef __attribute__((ext_vector_type(8))) short short8;
typedef __attribute__((ext_vector_type(4))) float f32x4;
typedef __attribute__((ext_vector_type(4))) unsigned short us4;

__device__ __forceinline__ unsigned short f2bf(float f) {
  union { float f; unsigned u; } v; v.f = f;
  return (unsigned short)((v.u + 0x7FFFu + ((v.u >> 16) & 1u)) >> 16);
}
__device__ __forceinline__ float bf2f(unsigned short h) {
  union { unsigned u; float f; } v; v.u = ((unsigned)h) << 16;
  return v.f;
}

#define GLD16(SRC, DST) __builtin_amdgcn_global_load_lds( \
    (__attribute__((address_space(1))) void*)(SRC), \
    (__attribute__((address_space(3))) void*)(DST), 16, 0, 0)

#define DPPF(v, ctrl) __int_as_float(__builtin_amdgcn_update_dpp(0, __float_as_int(v), ctrl, 0xF, 0xF, true))
__device__ __forceinline__ float dppmax16(float v) {
  v = fmaxf(v, DPPF(v, 0xB1));
  v = fmaxf(v, DPPF(v, 0x4E));
  v = fmaxf(v, DPPF(v, 0x124));
  v = fmaxf(v, DPPF(v, 0x128));
  return v;
}
__device__ __forceinline__ float dppsum16(float v) {
  v += DPPF(v, 0xB1);
  v += DPPF(v, 0x4E);
  v += DPPF(v, 0x124);
  v += DPPF(v, 0x128);
  return v;
}

// ---------------- 32x32 transpose helpers (device) ----------------
__device__ __forceinline__ void trans32(const float* __restrict__ src, unsigned short* __restrict__ dst,
                                        int R, int C, int c0, int r0, float (*tile)[33]) {
  int tx = threadIdx.x & 31, ty = threadIdx.x >> 5;
  #pragma unroll
  for (int i = 0; i < 4; ++i) {
    int rr = ty + i * 8;
    tile[rr][tx] = src[(size_t)(r0 + rr) * C + c0 + tx];
  }
  __syncthreads();
  #pragma unroll
  for (int i = 0; i < 4; ++i) {
    int rr = ty + i * 8;
    dst[(size_t)(c0 + rr) * R + r0 + tx] = f2bf(tile[tx][rr]);
  }
}
__device__ __forceinline__ void trans32p(const float* __restrict__ src, unsigned short* __restrict__ dst,
                                         int K, int C1, int c0, int r0, int f, float (*tile)[33]) {
  int tx = threadIdx.x & 31, ty = threadIdx.x >> 5;
  #pragma unroll
  for (int i = 0; i < 4; ++i) {
    int rr = ty + i * 8;
    tile[rr][tx] = src[(size_t)(r0 + rr) * C1 + c0 + tx];
  }
  __syncthreads();
  #pragma unroll
  for (int i = 0; i < 4; ++i) {
    int cc = ty + i * 8;
    int c = c0 + cc;
    int n = ((c >> 4) << 5) + (c & 15) + f;
    dst[(size_t)n * K + r0 + tx] = f2bf(tile[tx][cc]);
  }
}

// ---------------- prep1: rms1 (4096 blocks) + Wlat transpose (704 blocks) ----------------
__global__ __launch_bounds__(256) void prep1(
    const float* __restrict__ x, const float* __restrict__ rw, unsigned short* __restrict__ h_bf,
    const float* __restrict__ latent_w, unsigned short* __restrict__ Wlat) {
  __shared__ float tile[32][33];
  int b = blockIdx.x;
  if (b < NTOK) {
    int tid = threadIdx.x;
    const float* xr = x + (size_t)b * D_;
    float v[4]; float ss = 0.f;
    #pragma unroll
    for (int j = 0; j < 4; ++j) { v[j] = xr[tid + j * 256]; ss += v[j] * v[j]; }
    for (int o = 1; o < 64; o <<= 1) ss += __shfl_xor(ss, o);
    if ((tid & 63) == 0) tile[32][tid >> 6] = ss;   // reuse pad row as scratch
    __syncthreads();
    float inv = 1.f / sqrtf((tile[32][0] + tile[32][1] + tile[32][2] + tile[32][3]) / D_ + 1e-6f);
    #pragma unroll
    for (int j = 0; j < 4; ++j) {
      int i = tid + j * 256;
      h_bf[(size_t)b * D_ + i] = f2bf(v[j] * inv * rw[i]);
    }
    return;
  }
  b -= NTOK;
  trans32(latent_w, Wlat, 1024, 704, (b % 22) * 32, (b / 22) * 32, tile);
}

// ---------------- prep2: lat GEMM (192) + all remaining weight transposes ----------------
__global__ __launch_bounds__(256) void prep2(
    const unsigned short* __restrict__ h_bf, const unsigned short* __restrict__ Wlat,
    unsigned short* __restrict__ lat,
    const float* __restrict__ q_up_w, unsigned short* __restrict__ Wqup,
    const float* __restrict__ kv_up_w, unsigned short* __restrict__ Wkv,
    const float* __restrict__ c_proj_w, unsigned short* __restrict__ Wcp,
    const float* __restrict__ sh_w1, const float* __restrict__ sh_w3, unsigned short* __restrict__ Wsh13,
    const float* __restrict__ sh_w2, unsigned short* __restrict__ Wsh2,
    const float* __restrict__ e_w1, const float* __restrict__ e_w3, unsigned short* __restrict__ Wew13,
    const float* __restrict__ e_w2, unsigned short* __restrict__ Wew2) {
  __shared__ __align__(16) unsigned short As[128 * 32];
  __shared__ __align__(16) unsigned short Bs[128 * 32];
  __shared__ float tile[32][33];
  int b = blockIdx.x;
  if (b < 192) {
    // lat = h_bf @ Wlat^T  (M=4096, N=768, K=1024)
    const int tid = threadIdx.x, lane = tid & 63, wave = tid >> 6;
    const int wm = wave >> 1, wn = wave & 1;
    const int bm = (b / 6) * 128, bn = (b % 6) * 128;
    const int r = lane & 15, g = lane >> 4;
    f32x4 acc[4][4];
    #pragma unroll
    for (int i = 0; i < 4; ++i)
      #pragma unroll
      for (int j = 0; j < 4; ++j) acc[i][j] = (f32x4)0.f;
    const int rl0 = wave * 16 + (lane >> 2), rl1 = rl0 + 64;
    const int kc = (lane & 3) * 8;
    char* AsB = (char*)As; char* BsB = (char*)Bs;
    for (int k0 = 0; k0 < 1024; k0 += 32) {
      GLD16(h_bf + (size_t)(bm + rl0) * 1024 + k0 + kc, AsB + wave * 1024);
      GLD16(h_bf + (size_t)(bm + rl1) * 1024 + k0 + kc, AsB + (wave + 4) * 1024);
      GLD16(Wlat + (size_t)(bn + rl0) * 1024 + k0 + kc, BsB + wave * 1024);
      GLD16(Wlat + (size_t)(bn + rl1) * 1024 + k0 + kc, BsB + (wave + 4) * 1024);
      __syncthreads();
      short8 af[4], bfr[4];
      #pragma unroll
      for (int mi = 0; mi < 4; ++mi)
        af[mi] = *(const short8*)(As + (wm * 64 + mi * 16 + r) * 32 + g * 8);
      #pragma unroll
      for (int nj = 0; nj < 4; ++nj)
        bfr[nj] = *(const short8*)(Bs + (wn * 64 + nj * 16 + r) * 32 + g * 8);
      #pragma unroll
      for (int mi = 0; mi < 4; ++mi)
        #pragma unroll
        for (int nj = 0; nj < 4; ++nj)
          acc[mi][nj] = __builtin_amdgcn_mfma_f32_16x16x32_bf16(af[mi], bfr[nj], acc[mi][nj], 0, 0, 0);
      __syncthreads();
    }
    const int orow0 = wm * 64 + g * 4;
    const int ocol0 = bn + wn * 64 + r;
    #pragma unroll
    for (int mi = 0; mi < 4; ++mi)
      #pragma unroll
      for (int reg = 0; reg < 4; ++reg) {
        int mrow = bm + orow0 + mi * 16 + reg;
        size_t bas = (size_t)mrow * 768 + ocol0;
        #pragma unroll
        for (int nj = 0; nj < 4; ++nj) lat[bas + nj * 16] = f2bf(acc[mi][nj][reg]);
      }
    return;
  }
  b -= 192;
  if (b < 576) { trans32(q_up_w, Wqup, 384, 1536, (b % 48) * 32, (b / 48) * 32, tile); return; }
  b -= 576;
  if (b < 512) { trans32(kv_up_w, Wkv, 256, 2048, (b % 64) * 32, (b / 64) * 32, tile); return; }
  b -= 512;
  if (b < 1024) { trans32(c_proj_w, Wcp, 1024, 1024, (b % 32) * 32, (b / 32) * 32, tile); return; }
  b -= 1024;
  if (b < 1024) { trans32(sh_w2, Wsh2, 1024, 1024, (b % 32) * 32, (b / 32) * 32, tile); return; }
  b -= 1024;
  if (b < 2048) {
    int z = b / 1024, idx = b % 1024;
    trans32p(z ? sh_w3 : sh_w1, Wsh13, 1024, 1024, (idx % 32) * 32, (idx / 32) * 32, z * 16, tile);
    return;
  }
  b -= 2048;
  if (b < 8192) {
    int z = b / 512, idx = b % 512;
    int bat = z >> 1, f = (z & 1) * 16;
    const float* src = ((z & 1) ? e_w3 : e_w1) + (size_t)bat * 1024 * 512;
    trans32p(src, Wew13 + (size_t)bat * 1024 * 1024, 1024, 512, (idx % 16) * 32, (idx / 16) * 32, f, tile);
    return;
  }
  b -= 8192;
  { // e_w2: 8 experts, each 512x1024 -> [1024][512]
    int z = b / 512, idx = b % 512;
    trans32(e_w2 + (size_t)z * 512 * 1024, Wew2 + (size_t)z * 1024 * 512,
            512, 1024, (idx % 32) * 32, (idx / 32) * 32, tile);
  }
}

// ---------------- fused: q_norm + kv_norm + rope_k from lat ----------------
__global__ __launch_bounds__(256) void lat_post(
    const unsigned short* __restrict__ lat, const float* __restrict__ qw,
    const float* __restrict__ kw, const float* __restrict__ fc, const float* __restrict__ fs,
    unsigned short* __restrict__ qn, unsigned short* __restrict__ kvn,
    unsigned short* __restrict__ kr) {
  int row = blockIdx.x, tid = threadIdx.x;
  int lane = tid & 63, wv = tid >> 6;
  const unsigned short* lr = lat + (size_t)row * 768;
  float s1 = 0.f, s2 = 0.f;
  for (int i = tid; i < QLR_; i += 256) { float v = bf2f(lr[i]); s1 += v * v; }
  { float v = bf2f(lr[QLR_ + tid]); s2 = v * v; }
  for (int o = 1; o < 64; o <<= 1) { s1 += __shfl_xor(s1, o); s2 += __shfl_xor(s2, o); }
  __shared__ float red[8];
  if (lane == 0) { red[wv] = s1; red[4 + wv] = s2; }
  __syncthreads();
  float inv1 = 1.f / sqrtf((red[0] + red[1] + red[2] + red[3]) / QLR_ + 1e-6f);
  float inv2 = 1.f / sqrtf((red[4] + red[5] + red[6] + red[7]) / KVLR_ + 1e-6f);
  for (int i = tid; i < QLR_; i += 256)
    qn[(size_t)row * QLR_ + i] = f2bf(bf2f(lr[i]) * inv1 * qw[i]);
  kvn[(size_t)row * KVLR_ + tid] = f2bf(bf2f(lr[QLR_ + tid]) * inv2 * kw[tid]);
  if (tid < 32) {
    int t = row & (T_ - 1);
    float c = fc[t * 32 + tid], s = fs[t * 32 + tid];
    float x0 = bf2f(lr[640 + 2 * tid]), x1 = bf2f(lr[640 + 2 * tid + 1]);
    kr[(size_t)row * ROPE_ + 2 * tid]     = f2bf(x0 * c - x1 * s);
    kr[(size_t)row * ROPE_ + 2 * tid + 1] = f2bf(x0 * s + x1 * c);
  }
}

// ---------------- bf16 MFMA GEMM: C[M,N] = A[M,K] @ Bt[N,K]^T ----------------
// MODE 0: bf16 out. 1: f32 out = acc + addv.
template<int MODE>
__global__ __launch_bounds__(256) void gemm_bf16(
    const unsigned short* __restrict__ A, const unsigned short* __restrict__ Bt,
    void* __restrict__ Cv, int M, int N, int K,
    const float* __restrict__ addv) {
  __shared__ __align__(16) unsigned short As[128 * 32];
  __shared__ __align__(16) unsigned short Bs[128 * 32];
  const int tid = threadIdx.x;
  const int lane = tid & 63, wave = tid >> 6;
  const int wm = wave >> 1, wn = wave & 1;
  const int bm = blockIdx.y * 128, bn = blockIdx.x * 128;
  const int r = lane & 15, g = lane >> 4;

  f32x4 acc[4][4];
  #pragma unroll
  for (int i = 0; i < 4; ++i)
    #pragma unroll
    for (int j = 0; j < 4; ++j) acc[i][j] = (f32x4)0.f;

  const int rl0 = wave * 16 + (lane >> 2);
  const int rl1 = rl0 + 64;
  const int kc = (lane & 3) * 8;
  char* AsB = (char*)As; char* BsB = (char*)Bs;

  for (int k0 = 0; k0 < K; k0 += 32) {
    GLD16(A + (size_t)(bm + rl0) * K + k0 + kc, AsB + wave * 1024);
    GLD16(A + (size_t)(bm + rl1) * K + k0 + kc, AsB + (wave + 4) * 1024);
    GLD16(Bt + (size_t)(bn + rl0) * K + k0 + kc, BsB + wave * 1024);
    GLD16(Bt + (size_t)(bn + rl1) * K + k0 + kc, BsB + (wave + 4) * 1024);
    __syncthreads();
    short8 af[4], bfr[4];
    #pragma unroll
    for (int mi = 0; mi < 4; ++mi)
      af[mi] = *(const short8*)(As + (wm * 64 + mi * 16 + r) * 32 + g * 8);
    #pragma unroll
    for (int nj = 0; nj < 4; ++nj)
      bfr[nj] = *(const short8*)(Bs + (wn * 64 + nj * 16 + r) * 32 + g * 8);
    #pragma unroll
    for (int mi = 0; mi < 4; ++mi)
      #pragma unroll
      for (int nj = 0; nj < 4; ++nj)
        acc[mi][nj] = __builtin_amdgcn_mfma_f32_16x16x32_bf16(af[mi], bfr[nj], acc[mi][nj], 0, 0, 0);
    __syncthreads();
  }

  const int orow0 = wm * 64 + g * 4;
  const int ocol0 = bn + wn * 64 + r;
  #pragma unroll
  for (int mi = 0; mi < 4; ++mi) {
    #pragma unroll
    for (int reg = 0; reg < 4; ++reg) {
      int mrow = bm + orow0 + mi * 16 + reg;
      size_t bas = (size_t)mrow * N + ocol0;
      if (MODE == 0) {
        unsigned short* C = (unsigned short*)Cv;
        #pragma unroll
        for (int nj = 0; nj < 4; ++nj) C[bas + nj * 16] = f2bf(acc[mi][nj][reg]);
      } else {
        float* C = (float*)Cv;
        #pragma unroll
        for (int nj = 0; nj < 4; ++nj) C[bas + nj * 16] = acc[mi][nj][reg] + addv[bas + nj * 16];
      }
    }
  }
}

// ---------------- merged q_up + kv_up GEMM (one dispatch, 896 blocks) ----------------
__global__ __launch_bounds__(256) void gemm_qkv(
    const unsigned short* __restrict__ qn, const unsigned short* __restrict__ Wqup,
    const unsigned short* __restrict__ kvn, const unsigned short* __restrict__ Wkv,
    unsigned short* __restrict__ qq, unsigned short* __restrict__ kvb,
    unsigned short* __restrict__ vtg) {
  __shared__ __align__(16) unsigned short As[128 * 32];
  __shared__ __align__(16) unsigned short Bs[128 * 32];
  const int tid = threadIdx.x;
  const int lane = tid & 63, wave = tid >> 6;
  const int wm = wave >> 1, wn = wave & 1;
  const bool isQ = blockIdx.x < 12;
  const int bx = isQ ? blockIdx.x : blockIdx.x - 12;
  const unsigned short* A  = isQ ? qn : kvn;
  const unsigned short* Bt = isQ ? Wqup : Wkv;
  const int K = isQ ? QLR_ : KVLR_;
  const int bm = blockIdx.y * 128, bn = bx * 128;
  const int r = lane & 15, g = lane >> 4;

  f32x4 acc[4][4];
  #pragma unroll
  for (int i = 0; i < 4; ++i)
    #pragma unroll
    for (int j = 0; j < 4; ++j) acc[i][j] = (f32x4)0.f;

  const int rl0 = wave * 16 + (lane >> 2);
  const int rl1 = rl0 + 64;
  const int kc = (lane & 3) * 8;
  char* AsB = (char*)As; char* BsB = (char*)Bs;

  for (int k0 = 0; k0 < K; k0 += 32) {
    GLD16(A + (size_t)(bm + rl0) * K + k0 + kc, AsB + wave * 1024);
    GLD16(A + (size_t)(bm + rl1) * K + k0 + kc, AsB + (wave + 4) * 1024);
    GLD16(Bt + (size_t)(bn + rl0) * K + k0 + kc, BsB + wave * 1024);
    GLD16(Bt + (size_t)(bn + rl1) * K + k0 + kc, BsB + (wave + 4) * 1024);
    __syncthreads();
    short8 af[4], bfr[4];
    #pragma unroll
    for (int mi = 0; mi < 4; ++mi)
      af[mi] = *(const short8*)(As + (wm * 64 + mi * 16 + r) * 32 + g * 8);
    #pragma unroll
    for (int nj = 0; nj < 4; ++nj)
      bfr[nj] = *(const short8*)(Bs + (wn * 64 + nj * 16 + r) * 32 + g * 8);
    #pragma unroll
    for (int mi = 0; mi < 4; ++mi)
      #pragma unroll
      for (int nj = 0; nj < 4; ++nj)
        acc[mi][nj] = __builtin_amdgcn_mfma_f32_16x16x32_bf16(af[mi], bfr[nj], acc[mi][nj], 0, 0, 0);
    __syncthreads();
  }

  if (isQ) {
    const int orow0 = wm * 64 + g * 4;
    const int ocol0 = bn + wn * 64 + r;
    #pragma unroll
    for (int mi = 0; mi < 4; ++mi)
      #pragma unroll
      for (int reg = 0; reg < 4; ++reg) {
        int mrow = bm + orow0 + mi * 16 + reg;
        size_t bas = (size_t)mrow * 1536 + ocol0;
        #pragma unroll
        for (int nj = 0; nj < 4; ++nj) qq[bas + nj * 16] = f2bf(acc[mi][nj][reg]);
      }
  } else {
    const int colbase = bn + wn * 64;
    const int b = bm >> 11;
    const int hh = colbase >> 8;
    if ((colbase & 255) < 128) {
      #pragma unroll
      for (int mi = 0; mi < 4; ++mi)
        #pragma unroll
        for (int reg = 0; reg < 4; ++reg) {
          int mrow = bm + wm * 64 + mi * 16 + g * 4 + reg;
          size_t bas = (size_t)mrow * 2048 + colbase + r;
          #pragma unroll
          for (int nj = 0; nj < 4; ++nj) kvb[bas + nj * 16] = f2bf(acc[mi][nj][reg]);
        }
    } else {
      const int tl0 = (bm & 2047) + wm * 64 + g * 4;
      const int d0 = (colbase & 255) - 128 + r;
      const size_t bhbase = (size_t)(b * 8 + hh) * 64;
      #pragma unroll
      for (int mi = 0; mi < 4; ++mi) {
        int t = tl0 + mi * 16;
        size_t tb = (bhbase + (t >> 5)) * 4096 + (t & 31);
        #pragma unroll
        for (int nj = 0; nj < 4; ++nj) {
          int d = d0 + nj * 16;
          us4 pk;
          #pragma unroll
          for (int reg = 0; reg < 4; ++reg) pk[reg] = f2bf(acc[mi][nj][reg]);
          *(us4*)(vtg + tb + (size_t)d * 32) = pk;
        }
      }
    }
  }
}

// ---------------- merged sh13 + moe13 GEMM (silu fused, 1088 blocks) ----------------
__global__ __launch_bounds__(256) void gemm_ffn13(
    const unsigned short* __restrict__ h2b, const unsigned short* __restrict__ Wsh13,
    unsigned short* __restrict__ t1m,
    const unsigned short* __restrict__ Wew13, unsigned short* __restrict__ ehm,
    const int* __restrict__ lists, const int* __restrict__ map, const int* __restrict__ sbase) {
  __shared__ __align__(16) unsigned short As[128 * 32];
  __shared__ __align__(16) unsigned short Bs[128 * 32];
  const int i = blockIdx.x;
  const bool isSh = i < 512;
  const int tid = threadIdx.x, lane = tid & 63, wave = tid >> 6;
  const int wm = wave >> 1, wn = wave & 1;
  const int r = lane & 15, g = lane >> 4;
  const int rl0 = wave * 16 + (lane >> 2), rl1 = rl0 + 64;
  const int kc = (lane & 3) * 8;

  int bn, e = 0, ib = 0, bm = 0;
  const unsigned short* Bt;
  int ar0, ar1;
  const unsigned short* A;
  if (isSh) {
    bn = (i & 15) * 128; bm = (i >> 4) * 128;
    Bt = Wsh13; A = h2b;
    ar0 = bm + rl0; ar1 = bm + rl1;
  } else {
    int j = i - 512;
    bn = (j & 7) * 128;
    int mb = map[j >> 3];
    if (mb < 0) return;
    e = mb >> 16; ib = mb & 0xFFFF;
    Bt = Wew13 + (size_t)e * 1024 * 1024; A = h2b;
    ar0 = lists[e * LSTR + ib * 128 + rl0]; if (ar0 < 0) ar0 = 0;
    ar1 = lists[e * LSTR + ib * 128 + rl1]; if (ar1 < 0) ar1 = 0;
  }

  f32x4 acc[4][4];
  #pragma unroll
  for (int a = 0; a < 4; ++a)
    #pragma unroll
    for (int bj = 0; bj < 4; ++bj) acc[a][bj] = (f32x4)0.f;
  char* AsB = (char*)As; char* BsB = (char*)Bs;

  for (int k0 = 0; k0 < 1024; k0 += 32) {
    GLD16(A + (size_t)ar0 * 1024 + k0 + kc, AsB + wave * 1024);
    GLD16(A + (size_t)ar1 * 1024 + k0 + kc, AsB + (wave + 4) * 1024);
    GLD16(Bt + (size_t)(bn + rl0) * 1024 + k0 + kc, BsB + wave * 1024);
    GLD16(Bt + (size_t)(bn + rl1) * 1024 + k0 + kc, BsB + (wave + 4) * 1024);
    __syncthreads();
    short8 af[4], bfr[4];
    #pragma unroll
    for (int mi = 0; mi < 4; ++mi)
      af[mi] = *(const short8*)(As + (wm * 64 + mi * 16 + r) * 32 + g * 8);
    #pragma unroll
    for (int nj = 0; nj < 4; ++nj)
      bfr[nj] = *(const short8*)(Bs + (wn * 64 + nj * 16 + r) * 32 + g * 8);
    #pragma unroll
    for (int mi = 0; mi < 4; ++mi)
      #pragma unroll
      for (int nj = 0; nj < 4; ++nj)
        acc[mi][nj] = __builtin_amdgcn_mfma_f32_16x16x32_bf16(af[mi], bfr[nj], acc[mi][nj], 0, 0, 0);
    __syncthreads();
  }

  if (isSh) {
    const int hc = ((bn + wn * 64) >> 1) + r;
    #pragma unroll
    for (int mi = 0; mi < 4; ++mi)
      #pragma unroll
      for (int reg = 0; reg < 4; ++reg) {
        int mrow = bm + wm * 64 + mi * 16 + g * 4 + reg;
        #pragma unroll
        for (int p = 0; p < 2; ++p) {
          float a = acc[mi][2 * p][reg], b3 = acc[mi][2 * p + 1][reg];
          t1m[(size_t)mrow * 1024 + hc + p * 16] = f2bf((a / (1.f + __expf(-a))) * b3);
        }
      }
  } else {
    const int sb = sbase[e] + ib * 128;
    const int hc = ((bn + wn * 64) >> 1) + r;
    #pragma unroll
    for (int mi = 0; mi < 4; ++mi)
      #pragma unroll
      for (int reg = 0; reg < 4; ++reg) {
        int srow = sb + wm * 64 + mi * 16 + g * 4 + reg;
        #pragma unroll
        for (int p = 0; p < 2; ++p) {
          float a = acc[mi][2 * p][reg], b3 = acc[mi][2 * p + 1][reg];
          ehm[(size_t)srow * 512 + hc + p * 16] = f2bf((a / (1.f + __expf(-a))) * b3);
        }
      }
  }
}

// ---------------- merged sh2 + moe2 GEMM (atomic accumulate, 832 blocks) ----------------
__global__ __launch_bounds__(256) void gemm_ffn2(
    const unsigned short* __restrict__ t1m, const unsigned short* __restrict__ Wsh2,
    const unsigned short* __restrict__ ehm, const unsigned short* __restrict__ Wew2,
    float* __restrict__ out,
    const int* __restrict__ lists, const int* __restrict__ map, const int* __restrict__ sbase,
    const float* __restrict__ cw) {
  __shared__ __align__(16) unsigned short As[128 * 32];
  __shared__ __align__(16) unsigned short Bs[128 * 32];
  const int i = blockIdx.x;
  const bool isSh = i < 256;
  const int tid = threadIdx.x, lane = tid & 63, wave = tid >> 6;
  const int wm = wave >> 1, wn = wave & 1;
  const int r = lane & 15, g = lane >> 4;
  const int rl0 = wave * 16 + (lane >> 2), rl1 = rl0 + 64;
  const int kc = (lane & 3) * 8;

  int bn, e = 0, ib = 0, bm = 0, K;
  const unsigned short* A;
  const unsigned short* Bt;
  if (isSh) {
    bn = (i & 7) * 128; bm = (i >> 3) * 128;
    A = t1m; Bt = Wsh2; K = 1024;
  } else {
    int j = i - 256;
    bn = (j & 7) * 128;
    int mb = map[j >> 3];
    if (mb < 0) return;
    e = mb >> 16; ib = mb & 0xFFFF;
    bm = sbase[e] + ib * 128;
    A = ehm; Bt = Wew2 + (size_t)e * 512 * 1024; K = 512;
  }

  f32x4 acc[4][4];
  #pragma unroll
  for (int a = 0; a < 4; ++a)
    #pragma unroll
    for (int bj = 0; bj < 4; ++bj) acc[a][bj] = (f32x4)0.f;
  char* AsB = (char*)As; char* BsB = (char*)Bs;

  for (int k0 = 0; k0 < K; k0 += 32) {
    GLD16(A + (size_t)(bm + rl0) * K + k0 + kc, AsB + wave * 1024);
    GLD16(A + (size_t)(bm + rl1) * K + k0 + kc, AsB + (wave + 4) * 1024);
    GLD16(Bt + (size_t)(bn + rl0) * K + k0 + kc, BsB + wave * 1024);
    GLD16(Bt + (size_t)(bn + rl1) * K + k0 + kc, BsB + (wave + 4) * 1024);
    __syncthreads();
    short8 af[4], bfr[4];
    #pragma unroll
    for (int mi = 0; mi < 4; ++mi)
      af[mi] = *(const short8*)(As + (wm * 64 + mi * 16 + r) * 32 + g * 8);
    #pragma unroll
    for (int nj = 0; nj < 4; ++nj)
      bfr[nj] = *(const short8*)(Bs + (wn * 64 + nj * 16 + r) * 32 + g * 8);
    #pragma unroll
    for (int mi = 0; mi < 4; ++mi)
      #pragma unroll
      for (int nj = 0; nj < 4; ++nj)
        acc[mi][nj] = __builtin_amdgcn_mfma_f32_16x16x32_bf16(af[mi], bfr[nj], acc[mi][nj], 0, 0, 0);
    __syncthreads();
  }

  const int ocol0 = bn + wn * 64 + r;
  if (isSh) {
    #pragma unroll
    for (int mi = 0; mi < 4; ++mi)
      #pragma unroll
      for (int reg = 0; reg < 4; ++reg) {
        int mrow = bm + wm * 64 + mi * 16 + g * 4 + reg;
        #pragma unroll
        for (int nj = 0; nj < 4; ++nj)
          atomicAdd(out + (size_t)mrow * 1024 + ocol0 + nj * 16, acc[mi][nj][reg]);
      }
  } else {
    #pragma unroll
    for (int mi = 0; mi < 4; ++mi)
      #pragma unroll
      for (int reg = 0; reg < 4; ++reg) {
        int orow = wm * 64 + mi * 16 + g * 4 + reg;
        int tok = lists[e * LSTR + ib * 128 + orow];
        if (tok >= 0) {
          float wt = cw[(size_t)tok * E_ + e];
          #pragma unroll
          for (int nj = 0; nj < 4; ++nj)
            atomicAdd(out + (size_t)tok * 1024 + ocol0 + nj * 16, acc[mi][nj][reg] * wt);
        }
      }
  }
}

// ---------------- MFMA flash attention: AQ=128, 8 waves, split-K x2 ----------------
#define AQ 128
#define AK 32
#define VP 40
__global__ __launch_bounds__(512) void attn_mfma(
    const unsigned short* __restrict__ q,   // [NTOK][H][192] (rope NOT applied)
    const unsigned short* __restrict__ kv,  // [NTOK][H][256] (nope half valid)
    const unsigned short* __restrict__ kr,  // [NTOK][64]
    const unsigned short* __restrict__ vt,  // [16][64][128][32] tile-contiguous
    const float* __restrict__ fcos, const float* __restrict__ fsin,
    unsigned short* __restrict__ po,        // [16*16*2][128*128] bf16 unnormalized O
    float* __restrict__ pml) {              // [16*16*2][128*2] (m, l)
  __shared__ __align__(16) unsigned short Ks[AK * 192];    // row-major pitch 384B, XOR-swizzled
  __shared__ __align__(16) unsigned short Vl[128 * VP];
  __shared__ __align__(16) unsigned short Ps[8 * 16 * VP];
  const int tid = threadIdx.x, lane = tid & 63, wave = tid >> 6; // wave 0..7
  const int r = lane & 15, g = lane >> 4;
  const int bh = blockIdx.y, b = bh >> 3, h = bh & 7;
  const int qt = gridDim.x - 1 - blockIdx.x;   // LPT
  const int q0 = qt * AQ;
  const int half = blockIdx.z;
  const int hnt = 2 * (qt + 1);                // tiles per half
  const int kb = half * hnt, ke = kb + hnt;
  const size_t bT = (size_t)b * T_;
  const unsigned short* vbase = vt + (size_t)bh * 64 * 4096;
  char* KsB = (char*)Ks;

  // ---- Q into registers with fused RoPE ----
  short8 qf[6];
  const int qrow = q0 + wave * 16 + r;         // sequence position
  {
    const unsigned short* qb = q + ((bT + qrow) * H_ + h) * 192;
    #pragma unroll
    for (int kk = 0; kk < 6; ++kk) qf[kk] = *(const short8*)(qb + kk * 32 + g * 8);
    #pragma unroll
    for (int kk = 4; kk < 6; ++kk) {
      int i0 = (kk - 4) * 16 + g * 4;
      #pragma unroll
      for (int p = 0; p < 4; ++p) {
        float cc = fcos[qrow * 32 + i0 + p], sn = fsin[qrow * 32 + i0 + p];
        float x0 = bf2f((unsigned short)qf[kk][2 * p]), x1 = bf2f((unsigned short)qf[kk][2 * p + 1]);
        qf[kk][2 * p]     = (short)f2bf(x0 * cc - x1 * sn);
        qf[kk][2 * p + 1] = (short)f2bf(x0 * sn + x1 * cc);
      }
    }
  }

  float m_i[4], l_i[4];
  f32x4 o[8];
  #pragma unroll
  for (int i = 0; i < 4; ++i) { m_i[i] = -1e30f; l_i[i] = 0.f; }
  #pragma unroll
  for (int cb = 0; cb < 8; ++cb) o[cb] = (f32x4)0.f;

  const float scale2 = 0.07216878364870322f * 1.44269504088896f; // 1/sqrt(192)*log2e

  // K staging: 768 chunks (512 + 256), V: 512 chunks (one per thread)
  const int kr0r = tid / 24, kr0c = tid % 24;
  const bool k1v = tid < 256;
  const int kr1r = (tid + 512) / 24, kr1c = (tid + 512) % 24;

  short8 kreg0, kreg1, vreg;
  {
    int kk0 = kb * AK;
    kreg0 = (kr0c < 16)
      ? *(const short8*)(kv + ((bT + kk0 + kr0r) * H_ + h) * 256 + kr0c * 8)
      : *(const short8*)(kr + (bT + kk0 + kr0r) * 64 + (kr0c - 16) * 8);
    if (k1v)
      kreg1 = (kr1c < 16)
        ? *(const short8*)(kv + ((bT + kk0 + kr1r) * H_ + h) * 256 + kr1c * 8)
        : *(const short8*)(kr + (bT + kk0 + kr1r) * 64 + (kr1c - 16) * 8);
    vreg = *(const short8*)(vbase + (size_t)kb * 4096 + tid * 8);
  }

  for (int kt = kb; kt < ke; ++kt) {
    __builtin_amdgcn_s_barrier();
    __builtin_amdgcn_sched_barrier(0);
    *(short8*)(KsB + ((kr0r * 384 + kr0c * 16) ^ ((kr0r & 7) << 4))) = kreg0;
    if (k1v)
      *(short8*)(KsB + ((kr1r * 384 + kr1c * 16) ^ ((kr1r & 7) << 4))) = kreg1;
    *(short8*)(Vl + (tid >> 2) * VP + (tid & 3) * 8) = vreg;
    asm volatile("s_waitcnt lgkmcnt(0)" ::: "memory");
    __builtin_amdgcn_s_barrier();
    __builtin_amdgcn_sched_barrier(0);

    if (kt + 1 < ke) {
      int k1 = (kt + 1) * AK;
      kreg0 = (kr0c < 16)
        ? *(const short8*)(kv + ((bT + k1 + kr0r) * H_ + h) * 256 + kr0c * 8)
        : *(const short8*)(kr + (bT + k1 + kr0r) * 64 + (kr0c - 16) * 8);
      if (k1v)
        kreg1 = (kr1c < 16)
          ? *(const short8*)(kv + ((bT + k1 + kr1r) * H_ + h) * 256 + kr1c * 8)
          : *(const short8*)(kr + (bT + k1 + kr1r) * 64 + (kr1c - 16) * 8);
      vreg = *(const short8*)(vbase + (size_t)(kt + 1) * 4096 + tid * 8);
    }

    const int k0 = kt * AK;
    f32x4 sf0 = (f32x4)0.f, sf1 = (f32x4)0.f;
    {
      int ksw = (r & 7) << 4;
      __builtin_amdgcn_s_setprio(1);
      #pragma unroll
      for (int kk = 0; kk < 6; ++kk) {
        short8 b0 = *(const short8*)(KsB + ((r * 384 + kk * 64 + g * 16) ^ ksw));
        short8 b1 = *(const short8*)(KsB + (((16 + r) * 384 + kk * 64 + g * 16) ^ ksw));
        sf0 = __builtin_amdgcn_mfma_f32_16x16x32_bf16(qf[kk], b0, sf0, 0, 0, 0);
        sf1 = __builtin_amdgcn_mfma_f32_16x16x32_bf16(qf[kk], b1, sf1, 0, 0, 0);
      }
      __builtin_amdgcn_s_setprio(0);
    }

    float fac[4];
    bool needs = false;
    const bool bnd = (k0 + AK > q0);   // masks needed only near the diagonal
    #pragma unroll
    for (int reg = 0; reg < 4; ++reg) {
      float s0 = sf0[reg] * scale2;
      float s1 = sf1[reg] * scale2;
      if (bnd) {
        int qp = q0 + wave * 16 + g * 4 + reg;
        if (k0 + r > qp) s0 = -1e30f;
        if (k0 + 16 + r > qp) s1 = -1e30f;
      }
      float mt = dppmax16(fmaxf(s0, s1));
      float fc = 1.f, mn = m_i[reg];
      if (mt > mn + 8.f) {
        mn = mt; fc = exp2f(m_i[reg] - mn); m_i[reg] = mn; needs = true;
      }
      float e0 = exp2f(s0 - mn), e1 = exp2f(s1 - mn);
      float rs = dppsum16(e0 + e1);
      l_i[reg] = l_i[reg] * fc + rs;
      fac[reg] = fc;
      __hip_bfloat162 pk = __float22bfloat162_rn(float2{e0, e1});
      unsigned u = *(unsigned*)&pk;
      int prow = g * 4 + reg;
      Ps[wave * 16 * VP + prow * VP + r] = (unsigned short)u;
      Ps[wave * 16 * VP + prow * VP + 16 + r] = (unsigned short)(u >> 16);
    }
    if (__any(needs)) {
      #pragma unroll
      for (int cb = 0; cb < 8; ++cb)
        #pragma unroll
        for (int reg = 0; reg < 4; ++reg) o[cb][reg] *= fac[reg];
    }
    short8 pa = *(const short8*)(Ps + wave * 16 * VP + r * VP + g * 8);
    __builtin_amdgcn_s_setprio(1);
    #pragma unroll
    for (int cb = 0; cb < 8; ++cb) {
      short8 vb = *(const short8*)(Vl + (cb * 16 + r) * VP + g * 8);
      o[cb] = __builtin_amdgcn_mfma_f32_16x16x32_bf16(pa, vb, o[cb], 0, 0, 0);
    }
    __builtin_amdgcn_s_setprio(0);
  }

  // ---- write partial (unnormalized O bf16, m/l fp32) ----
  const int slab = (bh * 16 + qt) * 2 + half;
  unsigned short* pob = po + (size_t)slab * 16384;
  float* pmlb = pml + (size_t)slab * 256;
  #pragma unroll
  for (int reg = 0; reg < 4; ++reg) {
    int row = wave * 16 + g * 4 + reg;
    if (r == 0) { pmlb[row * 2] = m_i[reg]; pmlb[row * 2 + 1] = l_i[reg]; }
    #pragma unroll
    for (int cb = 0; cb < 8; ++cb)
      pob[row * 128 + cb * 16 + r] = f2bf(o[cb][reg]);
  }
}

// ---------------- split-K combine: merge 2 halves -> y bf16 ----------------
__global__ __launch_bounds__(512) void attn_combine(
    const unsigned short* __restrict__ po, const float* __restrict__ pml,
    unsigned short* __restrict__ y) {
  const int qt = blockIdx.x, bh = blockIdx.y, b = bh >> 3, h = bh & 7;
  const int s0 = (bh * 16 + qt) * 2, s1 = s0 + 1;
  const int row = threadIdx.x >> 2;
  const int qp = threadIdx.x & 3;
  float m0 = pml[(size_t)s0 * 256 + row * 2], l0 = pml[(size_t)s0 * 256 + row * 2 + 1];
  float m1 = pml[(size_t)s1 * 256 + row * 2], l1 = pml[(size_t)s1 * 256 + row * 2 + 1];
  float m = fmaxf(m0, m1);
  float e0 = exp2f(m0 - m), e1 = exp2f(m1 - m);
  float inv = 1.f / (l0 * e0 + l1 * e1);
  e0 *= inv; e1 *= inv;
  const unsigned short* o0 = po + (size_t)s0 * 16384 + row * 128 + qp * 32;
  const unsigned short* o1 = po + (size_t)s1 * 16384 + row * 128 + qp * 32;
  unsigned short* yb = y + ((size_t)(b * T_ + qt * 128 + row)) * 1024 + h * 128 + qp * 32;
  #pragma unroll
  for (int v = 0; v < 4; ++v) {
    short8 a = *(const short8*)(o0 + v * 8);
    short8 c = *(const short8*)(o1 + v * 8);
    short8 w;
    #pragma unroll
    for (int j = 0; j < 8; ++j)
      w[j] = (short)f2bf(bf2f((unsigned short)a[j]) * e0 + bf2f((unsigned short)c[j]) * e1);
    *(short8*)(yb + v * 8) = w;
  }
}

// ---------------- fused rms2 + gate (logits, softmax, top2) ----------------
__global__ __launch_bounds__(256) void rms2_gate(
    const float* __restrict__ xo, const float* __restrict__ rw, const float* __restrict__ gw,
    unsigned short* __restrict__ h2b, float* __restrict__ cw) {
  int row = blockIdx.x, tid = threadIdx.x;
  int lane = tid & 63, wv = tid >> 6;
  const float* xr = xo + (size_t)row * D_;
  float v[4]; float ss = 0.f;
  #pragma unroll
  for (int j = 0; j < 4; ++j) { v[j] = xr[tid + j * 256]; ss += v[j] * v[j]; }
  for (int o = 1; o < 64; o <<= 1) ss += __shfl_xor(ss, o);
  __shared__ float red[4];
  if (lane == 0) red[wv] = ss;
  __syncthreads();
  float inv = 1.f / sqrtf((red[0] + red[1] + red[2] + red[3]) / D_ + 1e-6f);
  float a[E_] = {0, 0, 0, 0, 0, 0, 0, 0};
  #pragma unroll
  for (int j = 0; j < 4; ++j) {
    int i = tid + j * 256;
    float hv = v[j] * inv * rw[i];
    h2b[(size_t)row * D_ + i] = f2bf(hv);
    const float* wr = gw + (size_t)i * E_;
    #pragma unroll
    for (int e = 0; e < E_; ++e) a[e] += hv * wr[e];
  }
  #pragma unroll
  for (int e = 0; e < E_; ++e) {
    float t = a[e];
    for (int o = 1; o < 64; o <<= 1) t += __shfl_xor(t, o);
    a[e] = t;
  }
  __shared__ float ga[4][E_];
  if (lane == 0)
    #pragma unroll
    for (int e = 0; e < E_; ++e) ga[wv][e] = a[e];
  __syncthreads();
  if (tid == 0) {
    float lg[E_];
    #pragma unroll
    for (int e = 0; e < E_; ++e) lg[e] = ga[0][e] + ga[1][e] + ga[2][e] + ga[3][e];
    float mx = lg[0];
    #pragma unroll
    for (int e = 1; e < E_; ++e) mx = fmaxf(mx, lg[e]);
    float sum = 0.f; float p[E_];
    #pragma unroll
    for (int e = 0; e < E_; ++e) { p[e] = __expf(lg[e] - mx); sum += p[e]; }
    float is = 1.f / sum;
    int i1 = 0; float b1 = p[0];
    #pragma unroll
    for (int e = 1; e < E_; ++e) if (p[e] > b1) { b1 = p[e]; i1 = e; }
    int i2 = -1; float b2 = -1.f;
    #pragma unroll
    for (int e = 0; e < E_; ++e) if (e != i1 && p[e] > b2) { b2 = p[e]; i2 = e; }
    #pragma unroll
    for (int e = 0; e < E_; ++e)
      cw[(size_t)row * E_ + e] = (e == i1) ? b1 * is : (e == i2 ? b2 * is : 0.f);
  }
}

// ---------------- MoE token compaction (ballot-based, deterministic) ----------------
__global__ __launch_bounds__(256) void moe_build(const float* __restrict__ cw,
                                                 int* __restrict__ lists, int* __restrict__ counts) {
  int e = blockIdx.x, tid = threadIdx.x;
  int lane = tid & 63, wv = tid >> 6;
  __shared__ int wsum[4];
  __shared__ int base;
  if (tid == 0) base = 0;
  __syncthreads();
  for (int c0 = 0; c0 < NTOK; c0 += 256) {
    int tok = c0 + tid;
    bool f = cw[(size_t)tok * E_ + e] > 0.f;
    unsigned long long m = __ballot(f);
    int pos = __popcll(m & ((1ull << lane) - 1ull));
    if (lane == 0) wsum[wv] = __popcll(m);
    __syncthreads();
    int woff = base;
    #pragma unroll
    for (int w = 0; w < 4; ++w) if (w < wv) woff += wsum[w];
    if (f) lists[e * LSTR + woff + pos] = tok;
    __syncthreads();
    if (tid == 0) base += wsum[0] + wsum[1] + wsum[2] + wsum[3];
    __syncthreads();
  }
  int cnt = base;
  int padded = (cnt + 127) & ~127;
  for (int i2 = cnt + tid; i2 < padded; i2 += 256) lists[e * LSTR + i2] = -1;
  if (tid == 0) { counts[e] = cnt; counts[8 + e] = padded >> 7; }
}

__global__ void moe_finalize(const int* __restrict__ counts, int* __restrict__ map,
                             int* __restrict__ sbase) {
  if (threadIdx.x == 0 && blockIdx.x == 0) {
    int cum = 0;
    for (int e = 0; e < E_; ++e) {
      sbase[e] = cum * 128;
      int nb = counts[8 + e];
      for (int i = 0; i < nb; ++i) map[cum + i] = (e << 16) | i;
      cum += nb;
    }
    for (; cum < MAXMB; ++cum) map[cum] = -1;
  }
}

extern "C" void kernel_launch(void* const* d_in, const int* in_sizes, int n_in,
                              void* d_out, int out_size, void* d_ws, size_t ws_size,
                              hipStream_t stream) {
  const float* x        = (const float*)d_in[0];
  const float* fcos     = (const float*)d_in[1];
  const float* fsin     = (const float*)d_in[2];
  const float* rmsn1_w  = (const float*)d_in[3];
  const float* rmsn2_w  = (const float*)d_in[4];
  const float* latent_w = (const float*)d_in[5];
  const float* q_norm_w = (const float*)d_in[6];
  const float* q_up_w   = (const float*)d_in[7];
  const float* kv_norm_w= (const float*)d_in[8];
  const float* kv_up_w  = (const float*)d_in[9];
  const float* c_proj_w = (const float*)d_in[10];
  const float* gate_w   = (const float*)d_in[11];
  const float* sh_w1    = (const float*)d_in[12];
  const float* sh_w2    = (const float*)d_in[13];
  const float* sh_w3    = (const float*)d_in[14];
  const float* e_w1     = (const float*)d_in[15];
  const float* e_w2     = (const float*)d_in[16];
  const float* e_w3     = (const float*)d_in[17];
  float* out = (float*)d_out;

  char* base = (char*)d_ws;
  size_t off = 0;
  auto take = [&](size_t bytes) { char* p = base + off; off += (bytes + 255) & ~(size_t)255; return p; };
  unsigned short* Wlat  = (unsigned short*)take((size_t)768 * 1024 * 2);
  unsigned short* Wqup  = (unsigned short*)take((size_t)1536 * 384 * 2);
  unsigned short* Wkv   = (unsigned short*)take((size_t)2048 * 256 * 2);
  unsigned short* Wcp   = (unsigned short*)take((size_t)1024 * 1024 * 2);
  unsigned short* Wsh13 = (unsigned short*)take((size_t)2048 * 1024 * 2);
  unsigned short* Wsh2  = (unsigned short*)take((size_t)1024 * 1024 * 2);
  unsigned short* Wew13 = (unsigned short*)take((size_t)8 * 1024 * 1024 * 2);
  unsigned short* Wew2  = (unsigned short*)take((size_t)8 * 1024 * 512 * 2);
  float* cw             = (float*)take((size_t)NTOK * E_ * 4);
  int* lists            = (int*)take((size_t)E_ * LSTR * 4);
  int* counts           = (int*)take(64 * 4);
  int* map              = (int*)take(MAXMB * 4);
  int* sbase            = (int*)take(E_ * 4);
  unsigned short* Vtg   = (unsigned short*)take((size_t)16 * 64 * 4096 * 2);
  unsigned short* kr    = (unsigned short*)take((size_t)NTOK * 64 * 2);
  float* pml            = (float*)take((size_t)512 * 256 * 4);

  size_t actStart = off;
  size_t aoff = actStart;
  auto takeA = [&](size_t bytes) { char* p = base + aoff; aoff += (bytes + 255) & ~(size_t)255; return p; };
  unsigned short* h_bf = (unsigned short*)takeA((size_t)NTOK * 1024 * 2);
  unsigned short* lat  = (unsigned short*)takeA((size_t)NTOK * 768 * 2);
  unsigned short* qn   = (unsigned short*)takeA((size_t)NTOK * 384 * 2);
  unsigned short* kvn  = (unsigned short*)takeA((size_t)NTOK * 256 * 2);
  unsigned short* qq   = (unsigned short*)takeA((size_t)NTOK * 1536 * 2);
  unsigned short* kvb  = (unsigned short*)takeA((size_t)NTOK * 2048 * 2);
  unsigned short* y    = (unsigned short*)takeA((size_t)NTOK * 1024 * 2);

  // split-K partial O (16 MB bf16) aliases h_bf/lat/qn (dead during attention)
  unsigned short* po   = (unsigned short*)(base + actStart);

  size_t coff = actStart;
  auto takeC = [&](size_t bytes) { char* p = base + coff; coff += (bytes + 255) & ~(size_t)255; return p; };
  unsigned short* h2b  = (unsigned short*)takeC((size_t)NTOK * 1024 * 2);
  unsigned short* t1m  = (unsigned short*)takeC((size_t)NTOK * 1024 * 2);
  unsigned short* ehm  = (unsigned short*)takeC((size_t)9216 * 512 * 2);

  dim3 blk(256);

  // prep1: rms1 + Wlat transpose (4800 blocks)
  prep1<<<dim3(NTOK + 704), blk, 0, stream>>>(x, rmsn1_w, h_bf, latent_w, Wlat);
  // prep2: lat GEMM (192 blocks, scheduled first) + all remaining weight transposes
  prep2<<<dim3(192 + 576 + 512 + 1024 + 1024 + 2048 + 8192 + 4096), blk, 0, stream>>>(
      h_bf, Wlat, lat, q_up_w, Wqup, kv_up_w, Wkv, c_proj_w, Wcp,
      sh_w1, sh_w3, Wsh13, sh_w2, Wsh2, e_w1, e_w3, Wew13, e_w2, Wew2);
  lat_post<<<NTOK, blk, 0, stream>>>(lat, q_norm_w, kv_norm_w, fcos, fsin, qn, kvn, kr);
  // merged q_up + kv_up (896 blocks)
  gemm_qkv<<<dim3(28, 32), blk, 0, stream>>>(qn, Wqup, kvn, Wkv, qq, kvb, Vtg);
  attn_mfma<<<dim3(T_ / AQ, B_ * H_, 2), dim3(512), 0, stream>>>(qq, kvb, kr, Vtg, fcos, fsin, po, pml);
  attn_combine<<<dim3(T_ / AQ, B_ * H_), dim3(512), 0, stream>>>(po, pml, y);
  gemm_bf16<1><<<dim3(8, 32), blk, 0, stream>>>(y, Wcp, out, NTOK, 1024, 1024, x);
  rms2_gate<<<NTOK, blk, 0, stream>>>(out, rmsn2_w, gate_w, h2b, cw);
  moe_build<<<E_, blk, 0, stream>>>(cw, lists, counts);
  moe_finalize<<<1, 64, 0, stream>>>(counts, map, sbase);
  // merged sh13 + moe13 (1088 blocks), then merged sh2 + moe2 (832 blocks, atomic)
  gemm_ffn13<<<dim3(1088), blk, 0, stream>>>(h2b, Wsh13, t1m, Wew13, ehm, lists, map, sbase);
  gemm_ffn2<<<dim3(832), blk, 0, stream>>>(t1m, Wsh2, ehm, Wew2, out, lists, map, sbase, cw);
}

// Round 14
// 344.928 us; speedup vs baseline: 1.2078x; 1.0429x over previous
//
#include <hip/hip_runtime.h>
#include <hip/hip_bf16.h>
#include <math.h>

#define D_ 1024
#define H_ 8
#define QLR_ 384
#define KVLR_ 256
#define NOPE_ 128
#define ROPE_ 64
#define VD_ 128
#define E_ 8
#define INTER_ 512
#define B_ 2
#define T_ 2048
#define QKD_ 192
#define NTOK (B_*T_)
#define LSTR 4608
#define MAXMB 72

typedef __attribute__((ext_vector_type(8))) short short8;
typedef __attribute__((ext_vector_type(4))) float f32x4;
typedef __attribute__((ext_vector_type(4))) unsigned short us4;

__device__ __forceinline__ unsigned short f2bf(float f) {
  union { float f; unsigned u; } v; v.f = f;
  return (unsigned short)((v.u + 0x7FFFu + ((v.u >> 16) & 1u)) >> 16);
}
__device__ __forceinline__ float bf2f(unsigned short h) {
  union { unsigned u; float f; } v; v.u = ((unsigned)h) << 16;
  return v.f;
}

#define GLD16(SRC, DST) __builtin_amdgcn_global_load_lds( \
    (__attribute__((address_space(1))) void*)(SRC), \
    (__attribute__((address_space(3))) void*)(DST), 16, 0, 0)

#define DPPF(v, ctrl) __int_as_float(__builtin_amdgcn_update_dpp(0, __float_as_int(v), ctrl, 0xF, 0xF, true))
__device__ __forceinline__ float dppmax16(float v) {
  v = fmaxf(v, DPPF(v, 0xB1));
  v = fmaxf(v, DPPF(v, 0x4E));
  v = fmaxf(v, DPPF(v, 0x124));
  v = fmaxf(v, DPPF(v, 0x128));
  return v;
}
__device__ __forceinline__ float dppsum16(float v) {
  v += DPPF(v, 0xB1);
  v += DPPF(v, 0x4E);
  v += DPPF(v, 0x124);
  v += DPPF(v, 0x128);
  return v;
}

// ---------------- 32x32 transpose helpers (device) ----------------
__device__ __forceinline__ void trans32(const float* __restrict__ src, unsigned short* __restrict__ dst,
                                        int R, int C, int c0, int r0, float (*tile)[33]) {
  int tx = threadIdx.x & 31, ty = threadIdx.x >> 5;
  #pragma unroll
  for (int i = 0; i < 4; ++i) {
    int rr = ty + i * 8;
    tile[rr][tx] = src[(size_t)(r0 + rr) * C + c0 + tx];
  }
  __syncthreads();
  #pragma unroll
  for (int i = 0; i < 4; ++i) {
    int rr = ty + i * 8;
    dst[(size_t)(c0 + rr) * R + r0 + tx] = f2bf(tile[tx][rr]);
  }
}
__device__ __forceinline__ void trans32p(const float* __restrict__ src, unsigned short* __restrict__ dst,
                                         int K, int C1, int c0, int r0, int f, float (*tile)[33]) {
  int tx = threadIdx.x & 31, ty = threadIdx.x >> 5;
  #pragma unroll
  for (int i = 0; i < 4; ++i) {
    int rr = ty + i * 8;
    tile[rr][tx] = src[(size_t)(r0 + rr) * C1 + c0 + tx];
  }
  __syncthreads();
  #pragma unroll
  for (int i = 0; i < 4; ++i) {
    int cc = ty + i * 8;
    int c = c0 + cc;
    int n = ((c >> 4) << 5) + (c & 15) + f;
    dst[(size_t)n * K + r0 + tx] = f2bf(tile[tx][cc]);
  }
}

// ---------------- prep1: rms1 (4096 blocks) + Wlat transpose (704 blocks) ----------------
__global__ __launch_bounds__(256) void prep1(
    const float* __restrict__ x, const float* __restrict__ rw, unsigned short* __restrict__ h_bf,
    const float* __restrict__ latent_w, unsigned short* __restrict__ Wlat) {
  __shared__ float tile[32][33];
  int b = blockIdx.x;
  if (b < NTOK) {
    int tid = threadIdx.x;
    const float* xr = x + (size_t)b * D_;
    float v[4]; float ss = 0.f;
    #pragma unroll
    for (int j = 0; j < 4; ++j) { v[j] = xr[tid + j * 256]; ss += v[j] * v[j]; }
    for (int o = 1; o < 64; o <<= 1) ss += __shfl_xor(ss, o);
    if ((tid & 63) == 0) tile[32][tid >> 6] = ss;
    __syncthreads();
    float inv = 1.f / sqrtf((tile[32][0] + tile[32][1] + tile[32][2] + tile[32][3]) / D_ + 1e-6f);
    #pragma unroll
    for (int j = 0; j < 4; ++j) {
      int i = tid + j * 256;
      h_bf[(size_t)b * D_ + i] = f2bf(v[j] * inv * rw[i]);
    }
    return;
  }
  b -= NTOK;
  trans32(latent_w, Wlat, 1024, 704, (b % 22) * 32, (b / 22) * 32, tile);
}

// ---------------- prep2: lat GEMM (192) + all remaining weight transposes ----------------
__global__ __launch_bounds__(256) void prep2(
    const unsigned short* __restrict__ h_bf, const unsigned short* __restrict__ Wlat,
    unsigned short* __restrict__ lat,
    const float* __restrict__ q_up_w, unsigned short* __restrict__ Wqup,
    const float* __restrict__ kv_up_w, unsigned short* __restrict__ Wkv,
    const float* __restrict__ c_proj_w, unsigned short* __restrict__ Wcp,
    const float* __restrict__ sh_w1, const float* __restrict__ sh_w3, unsigned short* __restrict__ Wsh13,
    const float* __restrict__ sh_w2, unsigned short* __restrict__ Wsh2,
    const float* __restrict__ e_w1, const float* __restrict__ e_w3, unsigned short* __restrict__ Wew13,
    const float* __restrict__ e_w2, unsigned short* __restrict__ Wew2) {
  __shared__ __align__(16) unsigned short As[128 * 32];
  __shared__ __align__(16) unsigned short Bs[128 * 32];
  __shared__ float tile[32][33];
  int b = blockIdx.x;
  if (b < 192) {
    const int tid = threadIdx.x, lane = tid & 63, wave = tid >> 6;
    const int wm = wave >> 1, wn = wave & 1;
    const int bm = (b / 6) * 128, bn = (b % 6) * 128;
    const int r = lane & 15, g = lane >> 4;
    f32x4 acc[4][4];
    #pragma unroll
    for (int i = 0; i < 4; ++i)
      #pragma unroll
      for (int j = 0; j < 4; ++j) acc[i][j] = (f32x4)0.f;
    const int rl0 = wave * 16 + (lane >> 2), rl1 = rl0 + 64;
    const int kc = (lane & 3) * 8;
    char* AsB = (char*)As; char* BsB = (char*)Bs;
    for (int k0 = 0; k0 < 1024; k0 += 32) {
      GLD16(h_bf + (size_t)(bm + rl0) * 1024 + k0 + kc, AsB + wave * 1024);
      GLD16(h_bf + (size_t)(bm + rl1) * 1024 + k0 + kc, AsB + (wave + 4) * 1024);
      GLD16(Wlat + (size_t)(bn + rl0) * 1024 + k0 + kc, BsB + wave * 1024);
      GLD16(Wlat + (size_t)(bn + rl1) * 1024 + k0 + kc, BsB + (wave + 4) * 1024);
      __syncthreads();
      short8 af[4], bfr[4];
      #pragma unroll
      for (int mi = 0; mi < 4; ++mi)
        af[mi] = *(const short8*)(As + (wm * 64 + mi * 16 + r) * 32 + g * 8);
      #pragma unroll
      for (int nj = 0; nj < 4; ++nj)
        bfr[nj] = *(const short8*)(Bs + (wn * 64 + nj * 16 + r) * 32 + g * 8);
      #pragma unroll
      for (int mi = 0; mi < 4; ++mi)
        #pragma unroll
        for (int nj = 0; nj < 4; ++nj)
          acc[mi][nj] = __builtin_amdgcn_mfma_f32_16x16x32_bf16(af[mi], bfr[nj], acc[mi][nj], 0, 0, 0);
      __syncthreads();
    }
    const int orow0 = wm * 64 + g * 4;
    const int ocol0 = bn + wn * 64 + r;
    #pragma unroll
    for (int mi = 0; mi < 4; ++mi)
      #pragma unroll
      for (int reg = 0; reg < 4; ++reg) {
        int mrow = bm + orow0 + mi * 16 + reg;
        size_t bas = (size_t)mrow * 768 + ocol0;
        #pragma unroll
        for (int nj = 0; nj < 4; ++nj) lat[bas + nj * 16] = f2bf(acc[mi][nj][reg]);
      }
    return;
  }
  b -= 192;
  if (b < 576) { trans32(q_up_w, Wqup, 384, 1536, (b % 48) * 32, (b / 48) * 32, tile); return; }
  b -= 576;
  if (b < 512) { trans32(kv_up_w, Wkv, 256, 2048, (b % 64) * 32, (b / 64) * 32, tile); return; }
  b -= 512;
  if (b < 1024) { trans32(c_proj_w, Wcp, 1024, 1024, (b % 32) * 32, (b / 32) * 32, tile); return; }
  b -= 1024;
  if (b < 1024) { trans32(sh_w2, Wsh2, 1024, 1024, (b % 32) * 32, (b / 32) * 32, tile); return; }
  b -= 1024;
  if (b < 2048) {
    int z = b / 1024, idx = b % 1024;
    trans32p(z ? sh_w3 : sh_w1, Wsh13, 1024, 1024, (idx % 32) * 32, (idx / 32) * 32, z * 16, tile);
    return;
  }
  b -= 2048;
  if (b < 8192) {
    int z = b / 512, idx = b % 512;
    int bat = z >> 1, f = (z & 1) * 16;
    const float* src = ((z & 1) ? e_w3 : e_w1) + (size_t)bat * 1024 * 512;
    trans32p(src, Wew13 + (size_t)bat * 1024 * 1024, 1024, 512, (idx % 16) * 32, (idx / 16) * 32, f, tile);
    return;
  }
  b -= 8192;
  {
    int z = b / 512, idx = b % 512;
    trans32(e_w2 + (size_t)z * 512 * 1024, Wew2 + (size_t)z * 1024 * 512,
            512, 1024, (idx % 32) * 32, (idx / 32) * 32, tile);
  }
}

// ---------------- fused: q_norm + kv_norm + rope_k from lat ----------------
__global__ __launch_bounds__(256) void lat_post(
    const unsigned short* __restrict__ lat, const float* __restrict__ qw,
    const float* __restrict__ kw, const float* __restrict__ fc, const float* __restrict__ fs,
    unsigned short* __restrict__ qn, unsigned short* __restrict__ kvn,
    unsigned short* __restrict__ kr) {
  int row = blockIdx.x, tid = threadIdx.x;
  int lane = tid & 63, wv = tid >> 6;
  const unsigned short* lr = lat + (size_t)row * 768;
  float s1 = 0.f, s2 = 0.f;
  for (int i = tid; i < QLR_; i += 256) { float v = bf2f(lr[i]); s1 += v * v; }
  { float v = bf2f(lr[QLR_ + tid]); s2 = v * v; }
  for (int o = 1; o < 64; o <<= 1) { s1 += __shfl_xor(s1, o); s2 += __shfl_xor(s2, o); }
  __shared__ float red[8];
  if (lane == 0) { red[wv] = s1; red[4 + wv] = s2; }
  __syncthreads();
  float inv1 = 1.f / sqrtf((red[0] + red[1] + red[2] + red[3]) / QLR_ + 1e-6f);
  float inv2 = 1.f / sqrtf((red[4] + red[5] + red[6] + red[7]) / KVLR_ + 1e-6f);
  for (int i = tid; i < QLR_; i += 256)
    qn[(size_t)row * QLR_ + i] = f2bf(bf2f(lr[i]) * inv1 * qw[i]);
  kvn[(size_t)row * KVLR_ + tid] = f2bf(bf2f(lr[QLR_ + tid]) * inv2 * kw[tid]);
  if (tid < 32) {
    int t = row & (T_ - 1);
    float c = fc[t * 32 + tid], s = fs[t * 32 + tid];
    float x0 = bf2f(lr[640 + 2 * tid]), x1 = bf2f(lr[640 + 2 * tid + 1]);
    kr[(size_t)row * ROPE_ + 2 * tid]     = f2bf(x0 * c - x1 * s);
    kr[(size_t)row * ROPE_ + 2 * tid + 1] = f2bf(x0 * s + x1 * c);
  }
}

// ---------------- bf16 MFMA GEMM: C[M,N] = A[M,K] @ Bt[N,K]^T ----------------
// MODE 0: bf16 out. 1: f32 out = acc + addv.
template<int MODE>
__global__ __launch_bounds__(256) void gemm_bf16(
    const unsigned short* __restrict__ A, const unsigned short* __restrict__ Bt,
    void* __restrict__ Cv, int M, int N, int K,
    const float* __restrict__ addv) {
  __shared__ __align__(16) unsigned short As[128 * 32];
  __shared__ __align__(16) unsigned short Bs[128 * 32];
  const int tid = threadIdx.x;
  const int lane = tid & 63, wave = tid >> 6;
  const int wm = wave >> 1, wn = wave & 1;
  const int bm = blockIdx.y * 128, bn = blockIdx.x * 128;
  const int r = lane & 15, g = lane >> 4;

  f32x4 acc[4][4];
  #pragma unroll
  for (int i = 0; i < 4; ++i)
    #pragma unroll
    for (int j = 0; j < 4; ++j) acc[i][j] = (f32x4)0.f;

  const int rl0 = wave * 16 + (lane >> 2);
  const int rl1 = rl0 + 64;
  const int kc = (lane & 3) * 8;
  char* AsB = (char*)As; char* BsB = (char*)Bs;

  for (int k0 = 0; k0 < K; k0 += 32) {
    GLD16(A + (size_t)(bm + rl0) * K + k0 + kc, AsB + wave * 1024);
    GLD16(A + (size_t)(bm + rl1) * K + k0 + kc, AsB + (wave + 4) * 1024);
    GLD16(Bt + (size_t)(bn + rl0) * K + k0 + kc, BsB + wave * 1024);
    GLD16(Bt + (size_t)(bn + rl1) * K + k0 + kc, BsB + (wave + 4) * 1024);
    __syncthreads();
    short8 af[4], bfr[4];
    #pragma unroll
    for (int mi = 0; mi < 4; ++mi)
      af[mi] = *(const short8*)(As + (wm * 64 + mi * 16 + r) * 32 + g * 8);
    #pragma unroll
    for (int nj = 0; nj < 4; ++nj)
      bfr[nj] = *(const short8*)(Bs + (wn * 64 + nj * 16 + r) * 32 + g * 8);
    #pragma unroll
    for (int mi = 0; mi < 4; ++mi)
      #pragma unroll
      for (int nj = 0; nj < 4; ++nj)
        acc[mi][nj] = __builtin_amdgcn_mfma_f32_16x16x32_bf16(af[mi], bfr[nj], acc[mi][nj], 0, 0, 0);
    __syncthreads();
  }

  const int orow0 = wm * 64 + g * 4;
  const int ocol0 = bn + wn * 64 + r;
  #pragma unroll
  for (int mi = 0; mi < 4; ++mi) {
    #pragma unroll
    for (int reg = 0; reg < 4; ++reg) {
      int mrow = bm + orow0 + mi * 16 + reg;
      size_t bas = (size_t)mrow * N + ocol0;
      if (MODE == 0) {
        unsigned short* C = (unsigned short*)Cv;
        #pragma unroll
        for (int nj = 0; nj < 4; ++nj) C[bas + nj * 16] = f2bf(acc[mi][nj][reg]);
      } else {
        float* C = (float*)Cv;
        #pragma unroll
        for (int nj = 0; nj < 4; ++nj) C[bas + nj * 16] = acc[mi][nj][reg] + addv[bas + nj * 16];
      }
    }
  }
}

// ---------------- merged q_up + kv_up GEMM (one dispatch, 896 blocks) ----------------
// kvb is now nope-only: [tok][h][128]
__global__ __launch_bounds__(256) void gemm_qkv(
    const unsigned short* __restrict__ qn, const unsigned short* __restrict__ Wqup,
    const unsigned short* __restrict__ kvn, const unsigned short* __restrict__ Wkv,
    unsigned short* __restrict__ qq, unsigned short* __restrict__ kvb,
    unsigned short* __restrict__ vtg) {
  __shared__ __align__(16) unsigned short As[128 * 32];
  __shared__ __align__(16) unsigned short Bs[128 * 32];
  const int tid = threadIdx.x;
  const int lane = tid & 63, wave = tid >> 6;
  const int wm = wave >> 1, wn = wave & 1;
  const bool isQ = blockIdx.x < 12;
  const int bx = isQ ? blockIdx.x : blockIdx.x - 12;
  const unsigned short* A  = isQ ? qn : kvn;
  const unsigned short* Bt = isQ ? Wqup : Wkv;
  const int K = isQ ? QLR_ : KVLR_;
  const int bm = blockIdx.y * 128, bn = bx * 128;
  const int r = lane & 15, g = lane >> 4;

  f32x4 acc[4][4];
  #pragma unroll
  for (int i = 0; i < 4; ++i)
    #pragma unroll
    for (int j = 0; j < 4; ++j) acc[i][j] = (f32x4)0.f;

  const int rl0 = wave * 16 + (lane >> 2);
  const int rl1 = rl0 + 64;
  const int kc = (lane & 3) * 8;
  char* AsB = (char*)As; char* BsB = (char*)Bs;

  for (int k0 = 0; k0 < K; k0 += 32) {
    GLD16(A + (size_t)(bm + rl0) * K + k0 + kc, AsB + wave * 1024);
    GLD16(A + (size_t)(bm + rl1) * K + k0 + kc, AsB + (wave + 4) * 1024);
    GLD16(Bt + (size_t)(bn + rl0) * K + k0 + kc, BsB + wave * 1024);
    GLD16(Bt + (size_t)(bn + rl1) * K + k0 + kc, BsB + (wave + 4) * 1024);
    __syncthreads();
    short8 af[4], bfr[4];
    #pragma unroll
    for (int mi = 0; mi < 4; ++mi)
      af[mi] = *(const short8*)(As + (wm * 64 + mi * 16 + r) * 32 + g * 8);
    #pragma unroll
    for (int nj = 0; nj < 4; ++nj)
      bfr[nj] = *(const short8*)(Bs + (wn * 64 + nj * 16 + r) * 32 + g * 8);
    #pragma unroll
    for (int mi = 0; mi < 4; ++mi)
      #pragma unroll
      for (int nj = 0; nj < 4; ++nj)
        acc[mi][nj] = __builtin_amdgcn_mfma_f32_16x16x32_bf16(af[mi], bfr[nj], acc[mi][nj], 0, 0, 0);
    __syncthreads();
  }

  if (isQ) {
    const int orow0 = wm * 64 + g * 4;
    const int ocol0 = bn + wn * 64 + r;
    #pragma unroll
    for (int mi = 0; mi < 4; ++mi)
      #pragma unroll
      for (int reg = 0; reg < 4; ++reg) {
        int mrow = bm + orow0 + mi * 16 + reg;
        size_t bas = (size_t)mrow * 1536 + ocol0;
        #pragma unroll
        for (int nj = 0; nj < 4; ++nj) qq[bas + nj * 16] = f2bf(acc[mi][nj][reg]);
      }
  } else {
    const int colbase = bn + wn * 64;
    const int b = bm >> 11;
    const int hh = colbase >> 8;
    if ((colbase & 255) < 128) {
      #pragma unroll
      for (int mi = 0; mi < 4; ++mi)
        #pragma unroll
        for (int reg = 0; reg < 4; ++reg) {
          int mrow = bm + wm * 64 + mi * 16 + g * 4 + reg;
          size_t bas = (size_t)mrow * 1024 + hh * 128 + (colbase & 255) + r;
          #pragma unroll
          for (int nj = 0; nj < 4; ++nj) kvb[bas + nj * 16] = f2bf(acc[mi][nj][reg]);
        }
    } else {
      const int tl0 = (bm & 2047) + wm * 64 + g * 4;
      const int d0 = (colbase & 255) - 128 + r;
      const size_t bhbase = (size_t)(b * 8 + hh) * 64;
      #pragma unroll
      for (int mi = 0; mi < 4; ++mi) {
        int t = tl0 + mi * 16;
        size_t tb = (bhbase + (t >> 5)) * 4096 + (t & 31);
        #pragma unroll
        for (int nj = 0; nj < 4; ++nj) {
          int d = d0 + nj * 16;
          us4 pk;
          #pragma unroll
          for (int reg = 0; reg < 4; ++reg) pk[reg] = f2bf(acc[mi][nj][reg]);
          *(us4*)(vtg + tb + (size_t)d * 32) = pk;
        }
      }
    }
  }
}

// ---------------- merged sh13 + moe13 GEMM (silu fused, 1088 blocks) ----------------
__global__ __launch_bounds__(256) void gemm_ffn13(
    const unsigned short* __restrict__ h2b, const unsigned short* __restrict__ Wsh13,
    unsigned short* __restrict__ t1m,
    const unsigned short* __restrict__ Wew13, unsigned short* __restrict__ ehm,
    const int* __restrict__ lists, const int* __restrict__ map, const int* __restrict__ sbase) {
  __shared__ __align__(16) unsigned short As[128 * 32];
  __shared__ __align__(16) unsigned short Bs[128 * 32];
  const int i = blockIdx.x;
  const bool isSh = i < 512;
  const int tid = threadIdx.x, lane = tid & 63, wave = tid >> 6;
  const int wm = wave >> 1, wn = wave & 1;
  const int r = lane & 15, g = lane >> 4;
  const int rl0 = wave * 16 + (lane >> 2), rl1 = rl0 + 64;
  const int kc = (lane & 3) * 8;

  int bn, e = 0, ib = 0, bm = 0;
  const unsigned short* Bt;
  int ar0, ar1;
  const unsigned short* A;
  if (isSh) {
    bn = (i & 15) * 128; bm = (i >> 4) * 128;
    Bt = Wsh13; A = h2b;
    ar0 = bm + rl0; ar1 = bm + rl1;
  } else {
    int j = i - 512;
    bn = (j & 7) * 128;
    int mb = map[j >> 3];
    if (mb < 0) return;
    e = mb >> 16; ib = mb & 0xFFFF;
    Bt = Wew13 + (size_t)e * 1024 * 1024; A = h2b;
    ar0 = lists[e * LSTR + ib * 128 + rl0]; if (ar0 < 0) ar0 = 0;
    ar1 = lists[e * LSTR + ib * 128 + rl1]; if (ar1 < 0) ar1 = 0;
  }

  f32x4 acc[4][4];
  #pragma unroll
  for (int a = 0; a < 4; ++a)
    #pragma unroll
    for (int bj = 0; bj < 4; ++bj) acc[a][bj] = (f32x4)0.f;
  char* AsB = (char*)As; char* BsB = (char*)Bs;

  for (int k0 = 0; k0 < 1024; k0 += 32) {
    GLD16(A + (size_t)ar0 * 1024 + k0 + kc, AsB + wave * 1024);
    GLD16(A + (size_t)ar1 * 1024 + k0 + kc, AsB + (wave + 4) * 1024);
    GLD16(Bt + (size_t)(bn + rl0) * 1024 + k0 + kc, BsB + wave * 1024);
    GLD16(Bt + (size_t)(bn + rl1) * 1024 + k0 + kc, BsB + (wave + 4) * 1024);
    __syncthreads();
    short8 af[4], bfr[4];
    #pragma unroll
    for (int mi = 0; mi < 4; ++mi)
      af[mi] = *(const short8*)(As + (wm * 64 + mi * 16 + r) * 32 + g * 8);
    #pragma unroll
    for (int nj = 0; nj < 4; ++nj)
      bfr[nj] = *(const short8*)(Bs + (wn * 64 + nj * 16 + r) * 32 + g * 8);
    #pragma unroll
    for (int mi = 0; mi < 4; ++mi)
      #pragma unroll
      for (int nj = 0; nj < 4; ++nj)
        acc[mi][nj] = __builtin_amdgcn_mfma_f32_16x16x32_bf16(af[mi], bfr[nj], acc[mi][nj], 0, 0, 0);
    __syncthreads();
  }

  if (isSh) {
    const int hc = ((bn + wn * 64) >> 1) + r;
    #pragma unroll
    for (int mi = 0; mi < 4; ++mi)
      #pragma unroll
      for (int reg = 0; reg < 4; ++reg) {
        int mrow = bm + wm * 64 + mi * 16 + g * 4 + reg;
        #pragma unroll
        for (int p = 0; p < 2; ++p) {
          float a = acc[mi][2 * p][reg], b3 = acc[mi][2 * p + 1][reg];
          t1m[(size_t)mrow * 1024 + hc + p * 16] = f2bf((a / (1.f + __expf(-a))) * b3);
        }
      }
  } else {
    const int sb = sbase[e] + ib * 128;
    const int hc = ((bn + wn * 64) >> 1) + r;
    #pragma unroll
    for (int mi = 0; mi < 4; ++mi)
      #pragma unroll
      for (int reg = 0; reg < 4; ++reg) {
        int srow = sb + wm * 64 + mi * 16 + g * 4 + reg;
        #pragma unroll
        for (int p = 0; p < 2; ++p) {
          float a = acc[mi][2 * p][reg], b3 = acc[mi][2 * p + 1][reg];
          ehm[(size_t)srow * 512 + hc + p * 16] = f2bf((a / (1.f + __expf(-a))) * b3);
        }
      }
  }
}

// ---------------- merged sh2 + moe2 GEMM (atomic accumulate, 832 blocks) ----------------
__global__ __launch_bounds__(256) void gemm_ffn2(
    const unsigned short* __restrict__ t1m, const unsigned short* __restrict__ Wsh2,
    const unsigned short* __restrict__ ehm, const unsigned short* __restrict__ Wew2,
    float* __restrict__ out,
    const int* __restrict__ lists, const int* __restrict__ map, const int* __restrict__ sbase,
    const float* __restrict__ cw) {
  __shared__ __align__(16) unsigned short As[128 * 32];
  __shared__ __align__(16) unsigned short Bs[128 * 32];
  const int i = blockIdx.x;
  const bool isSh = i < 256;
  const int tid = threadIdx.x, lane = tid & 63, wave = tid >> 6;
  const int wm = wave >> 1, wn = wave & 1;
  const int r = lane & 15, g = lane >> 4;
  const int rl0 = wave * 16 + (lane >> 2), rl1 = rl0 + 64;
  const int kc = (lane & 3) * 8;

  int bn, e = 0, ib = 0, bm = 0, K;
  const unsigned short* A;
  const unsigned short* Bt;
  if (isSh) {
    bn = (i & 7) * 128; bm = (i >> 3) * 128;
    A = t1m; Bt = Wsh2; K = 1024;
  } else {
    int j = i - 256;
    bn = (j & 7) * 128;
    int mb = map[j >> 3];
    if (mb < 0) return;
    e = mb >> 16; ib = mb & 0xFFFF;
    bm = sbase[e] + ib * 128;
    A = ehm; Bt = Wew2 + (size_t)e * 512 * 1024; K = 512;
  }

  f32x4 acc[4][4];
  #pragma unroll
  for (int a = 0; a < 4; ++a)
    #pragma unroll
    for (int bj = 0; bj < 4; ++bj) acc[a][bj] = (f32x4)0.f;
  char* AsB = (char*)As; char* BsB = (char*)Bs;

  for (int k0 = 0; k0 < K; k0 += 32) {
    GLD16(A + (size_t)(bm + rl0) * K + k0 + kc, AsB + wave * 1024);
    GLD16(A + (size_t)(bm + rl1) * K + k0 + kc, AsB + (wave + 4) * 1024);
    GLD16(Bt + (size_t)(bn + rl0) * K + k0 + kc, BsB + wave * 1024);
    GLD16(Bt + (size_t)(bn + rl1) * K + k0 + kc, BsB + (wave + 4) * 1024);
    __syncthreads();
    short8 af[4], bfr[4];
    #pragma unroll
    for (int mi = 0; mi < 4; ++mi)
      af[mi] = *(const short8*)(As + (wm * 64 + mi * 16 + r) * 32 + g * 8);
    #pragma unroll
    for (int nj = 0; nj < 4; ++nj)
      bfr[nj] = *(const short8*)(Bs + (wn * 64 + nj * 16 + r) * 32 + g * 8);
    #pragma unroll
    for (int mi = 0; mi < 4; ++mi)
      #pragma unroll
      for (int nj = 0; nj < 4; ++nj)
        acc[mi][nj] = __builtin_amdgcn_mfma_f32_16x16x32_bf16(af[mi], bfr[nj], acc[mi][nj], 0, 0, 0);
    __syncthreads();
  }

  const int ocol0 = bn + wn * 64 + r;
  if (isSh) {
    #pragma unroll
    for (int mi = 0; mi < 4; ++mi)
      #pragma unroll
      for (int reg = 0; reg < 4; ++reg) {
        int mrow = bm + wm * 64 + mi * 16 + g * 4 + reg;
        #pragma unroll
        for (int nj = 0; nj < 4; ++nj)
          atomicAdd(out + (size_t)mrow * 1024 + ocol0 + nj * 16, acc[mi][nj][reg]);
      }
  } else {
    #pragma unroll
    for (int mi = 0; mi < 4; ++mi)
      #pragma unroll
      for (int reg = 0; reg < 4; ++reg) {
        int orow = wm * 64 + mi * 16 + g * 4 + reg;
        int tok = lists[e * LSTR + ib * 128 + orow];
        if (tok >= 0) {
          float wt = cw[(size_t)tok * E_ + e];
          #pragma unroll
          for (int nj = 0; nj < 4; ++nj)
            atomicAdd(out + (size_t)tok * 1024 + ocol0 + nj * 16, acc[mi][nj][reg] * wt);
        }
      }
  }
}

// ---------------- MFMA flash attention: AQ=128, 8 waves, uniform chunked split-K ----------------
// chunks of 16 key-tiles (512 keys); per bh: 40 chunks (S table); grid (40, 16)
#define AQ 128
#define AK 32
#define VP 40
__global__ __launch_bounds__(512) void attn_mfma(
    const unsigned short* __restrict__ q,   // [NTOK][H][192] (rope NOT applied)
    const unsigned short* __restrict__ kv,  // [NTOK][H][128] nope-only
    const unsigned short* __restrict__ kr,  // [NTOK][64]
    const unsigned short* __restrict__ vt,  // [16][64][128][32] tile-contiguous
    const float* __restrict__ fcos, const float* __restrict__ fsin,
    unsigned short* __restrict__ po,        // [16*40][128*128] bf16 unnormalized O
    float* __restrict__ pml) {              // [16*40][128*2] (m, l)
  __shared__ __align__(16) unsigned short Ks[AK * 192];
  __shared__ __align__(16) unsigned short Vl[128 * VP];
  __shared__ __align__(16) unsigned short Ps[8 * 16 * VP];
  const int tid = threadIdx.x, lane = tid & 63, wave = tid >> 6;
  const int r = lane & 15, g = lane >> 4;
  const int bh = blockIdx.y, b = bh >> 3, h = bh & 7;
  // chunk decode (LPT: longest qt first)
  const int Stab[17] = {0,1,2,3,4,6,8,10,12,15,18,21,24,28,32,36,40};
  const int cid = 39 - (int)blockIdx.x;
  int qt = 0;
  #pragma unroll
  for (int t = 1; t <= 15; ++t) if (cid >= Stab[t]) qt = t;
  const int chunk = cid - Stab[qt];
  const int q0 = qt * AQ;
  const int ntl = 4 * (qt + 1);
  const int kb = chunk * 16;
  const int ke = (kb + 16 < ntl) ? kb + 16 : ntl;
  const size_t bT = (size_t)b * T_;
  const unsigned short* vbase = vt + (size_t)bh * 64 * 4096;
  char* KsB = (char*)Ks;

  // ---- Q into registers with fused RoPE ----
  short8 qf[6];
  const int qrow = q0 + wave * 16 + r;
  {
    const unsigned short* qb = q + ((bT + qrow) * H_ + h) * 192;
    #pragma unroll
    for (int kk = 0; kk < 6; ++kk) qf[kk] = *(const short8*)(qb + kk * 32 + g * 8);
    #pragma unroll
    for (int kk = 4; kk < 6; ++kk) {
      int i0 = (kk - 4) * 16 + g * 4;
      #pragma unroll
      for (int p = 0; p < 4; ++p) {
        float cc = fcos[qrow * 32 + i0 + p], sn = fsin[qrow * 32 + i0 + p];
        float x0 = bf2f((unsigned short)qf[kk][2 * p]), x1 = bf2f((unsigned short)qf[kk][2 * p + 1]);
        qf[kk][2 * p]     = (short)f2bf(x0 * cc - x1 * sn);
        qf[kk][2 * p + 1] = (short)f2bf(x0 * sn + x1 * cc);
      }
    }
  }

  float m_i[4], l_i[4];
  f32x4 o[8];
  #pragma unroll
  for (int i = 0; i < 4; ++i) { m_i[i] = -1e30f; l_i[i] = 0.f; }
  #pragma unroll
  for (int cb = 0; cb < 8; ++cb) o[cb] = (f32x4)0.f;

  const float scale2 = 0.07216878364870322f * 1.44269504088896f;

  const int kr0r = tid / 24, kr0c = tid % 24;
  const bool k1v = tid < 256;
  const int kr1r = (tid + 512) / 24, kr1c = (tid + 512) % 24;

  short8 kreg0, kreg1, vreg;
  {
    int kk0 = kb * AK;
    kreg0 = (kr0c < 16)
      ? *(const short8*)(kv + ((bT + kk0 + kr0r) * H_ + h) * 128 + kr0c * 8)
      : *(const short8*)(kr + (bT + kk0 + kr0r) * 64 + (kr0c - 16) * 8);
    if (k1v)
      kreg1 = (kr1c < 16)
        ? *(const short8*)(kv + ((bT + kk0 + kr1r) * H_ + h) * 128 + kr1c * 8)
        : *(const short8*)(kr + (bT + kk0 + kr1r) * 64 + (kr1c - 16) * 8);
    vreg = *(const short8*)(vbase + (size_t)kb * 4096 + tid * 8);
  }

  for (int kt = kb; kt < ke; ++kt) {
    __builtin_amdgcn_s_barrier();
    __builtin_amdgcn_sched_barrier(0);
    *(short8*)(KsB + ((kr0r * 384 + kr0c * 16) ^ ((kr0r & 7) << 4))) = kreg0;
    if (k1v)
      *(short8*)(KsB + ((kr1r * 384 + kr1c * 16) ^ ((kr1r & 7) << 4))) = kreg1;
    *(short8*)(Vl + (tid >> 2) * VP + (tid & 3) * 8) = vreg;
    asm volatile("s_waitcnt lgkmcnt(0)" ::: "memory");
    __builtin_amdgcn_s_barrier();
    __builtin_amdgcn_sched_barrier(0);

    if (kt + 1 < ke) {
      int k1 = (kt + 1) * AK;
      kreg0 = (kr0c < 16)
        ? *(const short8*)(kv + ((bT + k1 + kr0r) * H_ + h) * 128 + kr0c * 8)
        : *(const short8*)(kr + (bT + k1 + kr0r) * 64 + (kr0c - 16) * 8);
      if (k1v)
        kreg1 = (kr1c < 16)
          ? *(const short8*)(kv + ((bT + k1 + kr1r) * H_ + h) * 128 + kr1c * 8)
          : *(const short8*)(kr + (bT + k1 + kr1r) * 64 + (kr1c - 16) * 8);
      vreg = *(const short8*)(vbase + (size_t)(kt + 1) * 4096 + tid * 8);
    }

    const int k0 = kt * AK;
    f32x4 sf0 = (f32x4)0.f, sf1 = (f32x4)0.f;
    {
      int ksw = (r & 7) << 4;
      __builtin_amdgcn_s_setprio(1);
      #pragma unroll
      for (int kk = 0; kk < 6; ++kk) {
        short8 b0 = *(const short8*)(KsB + ((r * 384 + kk * 64 + g * 16) ^ ksw));
        short8 b1 = *(const short8*)(KsB + (((16 + r) * 384 + kk * 64 + g * 16) ^ ksw));
        sf0 = __builtin_amdgcn_mfma_f32_16x16x32_bf16(qf[kk], b0, sf0, 0, 0, 0);
        sf1 = __builtin_amdgcn_mfma_f32_16x16x32_bf16(qf[kk], b1, sf1, 0, 0, 0);
      }
      __builtin_amdgcn_s_setprio(0);
    }

    float fac[4];
    bool needs = false;
    const bool bnd = (k0 + AK > q0);
    #pragma unroll
    for (int reg = 0; reg < 4; ++reg) {
      float s0 = sf0[reg] * scale2;
      float s1 = sf1[reg] * scale2;
      if (bnd) {
        int qp = q0 + wave * 16 + g * 4 + reg;
        if (k0 + r > qp) s0 = -1e30f;
        if (k0 + 16 + r > qp) s1 = -1e30f;
      }
      float mt = dppmax16(fmaxf(s0, s1));
      float fc = 1.f, mn = m_i[reg];
      if (mt > mn + 8.f) {
        mn = mt; fc = exp2f(m_i[reg] - mn); m_i[reg] = mn; needs = true;
      }
      float e0 = exp2f(s0 - mn), e1 = exp2f(s1 - mn);
      float rs = dppsum16(e0 + e1);
      l_i[reg] = l_i[reg] * fc + rs;
      fac[reg] = fc;
      __hip_bfloat162 pk = __float22bfloat162_rn(float2{e0, e1});
      unsigned u = *(unsigned*)&pk;
      int prow = g * 4 + reg;
      Ps[wave * 16 * VP + prow * VP + r] = (unsigned short)u;
      Ps[wave * 16 * VP + prow * VP + 16 + r] = (unsigned short)(u >> 16);
    }
    if (__any(needs)) {
      #pragma unroll
      for (int cb = 0; cb < 8; ++cb)
        #pragma unroll
        for (int reg = 0; reg < 4; ++reg) o[cb][reg] *= fac[reg];
    }
    short8 pa = *(const short8*)(Ps + wave * 16 * VP + r * VP + g * 8);
    __builtin_amdgcn_s_setprio(1);
    #pragma unroll
    for (int cb = 0; cb < 8; ++cb) {
      short8 vb = *(const short8*)(Vl + (cb * 16 + r) * VP + g * 8);
      o[cb] = __builtin_amdgcn_mfma_f32_16x16x32_bf16(pa, vb, o[cb], 0, 0, 0);
    }
    __builtin_amdgcn_s_setprio(0);
  }

  // ---- write partial (unnormalized O bf16, m/l fp32); slab = bh*40 + cid ----
  const int slab = bh * 40 + cid;
  unsigned short* pob = po + (size_t)slab * 16384;
  float* pmlb = pml + (size_t)slab * 256;
  #pragma unroll
  for (int reg = 0; reg < 4; ++reg) {
    int row = wave * 16 + g * 4 + reg;
    if (r == 0) { pmlb[row * 2] = m_i[reg]; pmlb[row * 2 + 1] = l_i[reg]; }
    #pragma unroll
    for (int cb = 0; cb < 8; ++cb)
      pob[row * 128 + cb * 16 + r] = f2bf(o[cb][reg]);
  }
}

// ---------------- split-K combine: merge up to 4 chunks -> y bf16 ----------------
__global__ __launch_bounds__(512) void attn_combine(
    const unsigned short* __restrict__ po, const float* __restrict__ pml,
    unsigned short* __restrict__ y) {
  const int qt = blockIdx.x, bh = blockIdx.y, b = bh >> 3, h = bh & 7;
  const int Stab[17] = {0,1,2,3,4,6,8,10,12,15,18,21,24,28,32,36,40};
  const int s0 = bh * 40 + Stab[qt];
  const int nc = Stab[qt + 1] - Stab[qt];
  const int row = threadIdx.x >> 2;
  const int qp = threadIdx.x & 3;
  float mj[4], lj[4];
  float m = -1e30f;
  for (int j = 0; j < nc; ++j) {
    mj[j] = pml[(size_t)(s0 + j) * 256 + row * 2];
    lj[j] = pml[(size_t)(s0 + j) * 256 + row * 2 + 1];
    m = fmaxf(m, mj[j]);
  }
  float lsum = 0.f;
  float ej[4];
  for (int j = 0; j < nc; ++j) {
    ej[j] = exp2f(mj[j] - m);
    lsum += lj[j] * ej[j];
  }
  float inv = 1.f / lsum;
  unsigned short* yb = y + ((size_t)(b * T_ + qt * 128 + row)) * 1024 + h * 128 + qp * 32;
  #pragma unroll
  for (int v = 0; v < 4; ++v) {
    float accv[8];
    #pragma unroll
    for (int jj = 0; jj < 8; ++jj) accv[jj] = 0.f;
    for (int j = 0; j < nc; ++j) {
      const unsigned short* oj = po + (size_t)(s0 + j) * 16384 + row * 128 + qp * 32 + v * 8;
      short8 a = *(const short8*)oj;
      float w = ej[j];
      #pragma unroll
      for (int jj = 0; jj < 8; ++jj) accv[jj] += bf2f((unsigned short)a[jj]) * w;
    }
    short8 wv;
    #pragma unroll
    for (int jj = 0; jj < 8; ++jj) wv[jj] = (short)f2bf(accv[jj] * inv);
    *(short8*)(yb + v * 8) = wv;
  }
}

// ---------------- fused rms2 + gate (logits, softmax, top2) ----------------
__global__ __launch_bounds__(256) void rms2_gate(
    const float* __restrict__ xo, const float* __restrict__ rw, const float* __restrict__ gw,
    unsigned short* __restrict__ h2b, float* __restrict__ cw) {
  int row = blockIdx.x, tid = threadIdx.x;
  int lane = tid & 63, wv = tid >> 6;
  const float* xr = xo + (size_t)row * D_;
  float v[4]; float ss = 0.f;
  #pragma unroll
  for (int j = 0; j < 4; ++j) { v[j] = xr[tid + j * 256]; ss += v[j] * v[j]; }
  for (int o = 1; o < 64; o <<= 1) ss += __shfl_xor(ss, o);
  __shared__ float red[4];
  if (lane == 0) red[wv] = ss;
  __syncthreads();
  float inv = 1.f / sqrtf((red[0] + red[1] + red[2] + red[3]) / D_ + 1e-6f);
  float a[E_] = {0, 0, 0, 0, 0, 0, 0, 0};
  #pragma unroll
  for (int j = 0; j < 4; ++j) {
    int i = tid + j * 256;
    float hv = v[j] * inv * rw[i];
    h2b[(size_t)row * D_ + i] = f2bf(hv);
    const float* wr = gw + (size_t)i * E_;
    #pragma unroll
    for (int e = 0; e < E_; ++e) a[e] += hv * wr[e];
  }
  #pragma unroll
  for (int e = 0; e < E_; ++e) {
    float t = a[e];
    for (int o = 1; o < 64; o <<= 1) t += __shfl_xor(t, o);
    a[e] = t;
  }
  __shared__ float ga[4][E_];
  if (lane == 0)
    #pragma unroll
    for (int e = 0; e < E_; ++e) ga[wv][e] = a[e];
  __syncthreads();
  if (tid == 0) {
    float lg[E_];
    #pragma unroll
    for (int e = 0; e < E_; ++e) lg[e] = ga[0][e] + ga[1][e] + ga[2][e] + ga[3][e];
    float mx = lg[0];
    #pragma unroll
    for (int e = 1; e < E_; ++e) mx = fmaxf(mx, lg[e]);
    float sum = 0.f; float p[E_];
    #pragma unroll
    for (int e = 0; e < E_; ++e) { p[e] = __expf(lg[e] - mx); sum += p[e]; }
    float is = 1.f / sum;
    int i1 = 0; float b1 = p[0];
    #pragma unroll
    for (int e = 1; e < E_; ++e) if (p[e] > b1) { b1 = p[e]; i1 = e; }
    int i2 = -1; float b2 = -1.f;
    #pragma unroll
    for (int e = 0; e < E_; ++e) if (e != i1 && p[e] > b2) { b2 = p[e]; i2 = e; }
    #pragma unroll
    for (int e = 0; e < E_; ++e)
      cw[(size_t)row * E_ + e] = (e == i1) ? b1 * is : (e == i2 ? b2 * is : 0.f);
  }
}

// ---------------- MoE token compaction (ballot-based, deterministic) ----------------
__global__ __launch_bounds__(256) void moe_build(const float* __restrict__ cw,
                                                 int* __restrict__ lists, int* __restrict__ counts) {
  int e = blockIdx.x, tid = threadIdx.x;
  int lane = tid & 63, wv = tid >> 6;
  __shared__ int wsum[4];
  __shared__ int base;
  if (tid == 0) base = 0;
  __syncthreads();
  for (int c0 = 0; c0 < NTOK; c0 += 256) {
    int tok = c0 + tid;
    bool f = cw[(size_t)tok * E_ + e] > 0.f;
    unsigned long long m = __ballot(f);
    int pos = __popcll(m & ((1ull << lane) - 1ull));
    if (lane == 0) wsum[wv] = __popcll(m);
    __syncthreads();
    int woff = base;
    #pragma unroll
    for (int w = 0; w < 4; ++w) if (w < wv) woff += wsum[w];
    if (f) lists[e * LSTR + woff + pos] = tok;
    __syncthreads();
    if (tid == 0) base += wsum[0] + wsum[1] + wsum[2] + wsum[3];
    __syncthreads();
  }
  int cnt = base;
  int padded = (cnt + 127) & ~127;
  for (int i2 = cnt + tid; i2 < padded; i2 += 256) lists[e * LSTR + i2] = -1;
  if (tid == 0) { counts[e] = cnt; counts[8 + e] = padded >> 7; }
}

__global__ void moe_finalize(const int* __restrict__ counts, int* __restrict__ map,
                             int* __restrict__ sbase) {
  if (threadIdx.x == 0 && blockIdx.x == 0) {
    int cum = 0;
    for (int e = 0; e < E_; ++e) {
      sbase[e] = cum * 128;
      int nb = counts[8 + e];
      for (int i = 0; i < nb; ++i) map[cum + i] = (e << 16) | i;
      cum += nb;
    }
    for (; cum < MAXMB; ++cum) map[cum] = -1;
  }
}

extern "C" void kernel_launch(void* const* d_in, const int* in_sizes, int n_in,
                              void* d_out, int out_size, void* d_ws, size_t ws_size,
                              hipStream_t stream) {
  const float* x        = (const float*)d_in[0];
  const float* fcos     = (const float*)d_in[1];
  const float* fsin     = (const float*)d_in[2];
  const float* rmsn1_w  = (const float*)d_in[3];
  const float* rmsn2_w  = (const float*)d_in[4];
  const float* latent_w = (const float*)d_in[5];
  const float* q_norm_w = (const float*)d_in[6];
  const float* q_up_w   = (const float*)d_in[7];
  const float* kv_norm_w= (const float*)d_in[8];
  const float* kv_up_w  = (const float*)d_in[9];
  const float* c_proj_w = (const float*)d_in[10];
  const float* gate_w   = (const float*)d_in[11];
  const float* sh_w1    = (const float*)d_in[12];
  const float* sh_w2    = (const float*)d_in[13];
  const float* sh_w3    = (const float*)d_in[14];
  const float* e_w1     = (const float*)d_in[15];
  const float* e_w2     = (const float*)d_in[16];
  const float* e_w3     = (const float*)d_in[17];
  float* out = (float*)d_out;

  char* base = (char*)d_ws;
  size_t off = 0;
  auto take = [&](size_t bytes) { char* p = base + off; off += (bytes + 255) & ~(size_t)255; return p; };
  unsigned short* Wlat  = (unsigned short*)take((size_t)768 * 1024 * 2);
  unsigned short* Wqup  = (unsigned short*)take((size_t)1536 * 384 * 2);
  unsigned short* Wkv   = (unsigned short*)take((size_t)2048 * 256 * 2);
  unsigned short* Wcp   = (unsigned short*)take((size_t)1024 * 1024 * 2);
  unsigned short* Wsh13 = (unsigned short*)take((size_t)2048 * 1024 * 2);
  unsigned short* Wsh2  = (unsigned short*)take((size_t)1024 * 1024 * 2);
  unsigned short* Wew13 = (unsigned short*)take((size_t)8 * 1024 * 1024 * 2);
  unsigned short* Wew2  = (unsigned short*)take((size_t)8 * 1024 * 512 * 2);
  float* cw             = (float*)take((size_t)NTOK * E_ * 4);
  int* lists            = (int*)take((size_t)E_ * LSTR * 4);
  int* counts           = (int*)take(64 * 4);
  int* map              = (int*)take(MAXMB * 4);
  int* sbase            = (int*)take(E_ * 4);
  unsigned short* Vtg   = (unsigned short*)take((size_t)16 * 64 * 4096 * 2);
  unsigned short* kr    = (unsigned short*)take((size_t)NTOK * 64 * 2);

  size_t actStart = off;
  size_t aoff = actStart;
  auto takeA = [&](size_t bytes) { char* p = base + aoff; aoff += (bytes + 255) & ~(size_t)255; return p; };
  unsigned short* h_bf = (unsigned short*)takeA((size_t)NTOK * 1024 * 2);
  unsigned short* lat  = (unsigned short*)takeA((size_t)NTOK * 768 * 2);
  unsigned short* qn   = (unsigned short*)takeA((size_t)NTOK * 384 * 2);
  unsigned short* kvn  = (unsigned short*)takeA((size_t)NTOK * 256 * 2);
  unsigned short* qq   = (unsigned short*)takeA((size_t)NTOK * 1536 * 2);
  unsigned short* kvb  = (unsigned short*)takeA((size_t)NTOK * 1024 * 2);   // nope-only
  unsigned short* y    = (unsigned short*)takeA((size_t)NTOK * 1024 * 2);
  unsigned short* po   = (unsigned short*)takeA((size_t)640 * 16384 * 2);   // 40 chunks x 16 bh
  float* pml           = (float*)takeA((size_t)640 * 256 * 4);

  size_t coff = actStart;
  auto takeC = [&](size_t bytes) { char* p = base + coff; coff += (bytes + 255) & ~(size_t)255; return p; };
  unsigned short* h2b  = (unsigned short*)takeC((size_t)NTOK * 1024 * 2);
  unsigned short* t1m  = (unsigned short*)takeC((size_t)NTOK * 1024 * 2);
  unsigned short* ehm  = (unsigned short*)takeC((size_t)9216 * 512 * 2);

  dim3 blk(256);

  // prep1: rms1 + Wlat transpose
  prep1<<<dim3(NTOK + 704), blk, 0, stream>>>(x, rmsn1_w, h_bf, latent_w, Wlat);
  // prep2: lat GEMM + all remaining weight transposes
  prep2<<<dim3(192 + 576 + 512 + 1024 + 1024 + 2048 + 8192 + 4096), blk, 0, stream>>>(
      h_bf, Wlat, lat, q_up_w, Wqup, kv_up_w, Wkv, c_proj_w, Wcp,
      sh_w1, sh_w3, Wsh13, sh_w2, Wsh2, e_w1, e_w3, Wew13, e_w2, Wew2);
  lat_post<<<NTOK, blk, 0, stream>>>(lat, q_norm_w, kv_norm_w, fcos, fsin, qn, kvn, kr);
  gemm_qkv<<<dim3(28, 32), blk, 0, stream>>>(qn, Wqup, kvn, Wkv, qq, kvb, Vtg);
  attn_mfma<<<dim3(40, 16), dim3(512), 0, stream>>>(qq, kvb, kr, Vtg, fcos, fsin, po, pml);
  attn_combine<<<dim3(16, 16), dim3(512), 0, stream>>>(po, pml, y);
  gemm_bf16<1><<<dim3(8, 32), blk, 0, stream>>>(y, Wcp, out, NTOK, 1024, 1024, x);
  rms2_gate<<<NTOK, blk, 0, stream>>>(out, rmsn2_w, gate_w, h2b, cw);
  moe_build<<<E_, blk, 0, stream>>>(cw, lists, counts);
  moe_finalize<<<1, 64, 0, stream>>>(counts, map, sbase);
  gemm_ffn13<<<dim3(1088), blk, 0, stream>>>(h2b, Wsh13, t1m, Wew13, ehm, lists, map, sbase);
  gemm_ffn2<<<dim3(832), blk, 0, stream>>>(t1m, Wsh2, ehm, Wew2, out, lists, map, sbase, cw);
}